// Round 2
// baseline (2408.876 us; speedup 1.0000x reference)
//
#include <hip/hip_runtime.h>
#include <hip/hip_bf16.h>
#include <cstdint>
#include <cstddef>

#define DCH 128
#define NHEADS 2
#define NEG_SLOPE 0.2f

// ---------------------------------------------------------------- utilities
__device__ __forceinline__ void atomicMaxF(float* addr, float val) {
    // float atomic-max via integer compare trick (init must be -inf)
    if (val >= 0.f) atomicMax((int*)addr, __float_as_int(val));
    else            atomicMin((unsigned int*)addr, __float_as_uint(val));
}

__device__ __forceinline__ float bf2f(unsigned short u) {
    union { unsigned int i; float f; } v; v.i = ((unsigned int)u) << 16; return v.f;
}

// typed 4-wide / 2-wide loads returning float
__device__ __forceinline__ float4 ld4(const float* p) { return *(const float4*)p; }
__device__ __forceinline__ float4 ld4(const __hip_bfloat16* p) {
    ushort4 u = *(const ushort4*)p;
    return make_float4(bf2f(u.x), bf2f(u.y), bf2f(u.z), bf2f(u.w));
}
__device__ __forceinline__ float2 ld2(const float* p) { return *(const float2*)p; }
__device__ __forceinline__ float2 ld2(const __hip_bfloat16* p) {
    ushort2 u = *(const ushort2*)p;
    return make_float2(bf2f(u.x), bf2f(u.y));
}
__device__ __forceinline__ void st1(float* p, float v) { *p = v; }
__device__ __forceinline__ void st1(__hip_bfloat16* p, float v) { *p = __float2bfloat16(v); }

// ------------------------------------------------------------ init m=-inf z=0
__global__ void init_mz(float* __restrict__ m, float* __restrict__ z, int n2) {
    int i = blockIdx.x * blockDim.x + threadIdx.x;
    if (i < n2) { m[i] = -INFINITY; z[i] = 0.f; }
}

// --------------------------------------------------- fused LN+ReLU + 3 GEMMs
// Conceptual C[N,640]: cols 0..255 -> xl = h@Wl+bl, 256..511 -> xr = h@Wr+br,
// 512..639 -> d_out = x + h@res_W + bias. h = relu(LN(x)) computed on the fly
// during A staging (no hbuf). Tile 64x64, K=128 one-shot, 4x4 micro-tile.
template <typename ST>
__launch_bounds__(256, 2)
__global__ void gemm_ln(const float* __restrict__ x,
                        const float* __restrict__ gamma, const float* __restrict__ beta,
                        const float* __restrict__ Wl, const float* __restrict__ bl,
                        const float* __restrict__ Wr, const float* __restrict__ br,
                        const float* __restrict__ resW, const float* __restrict__ bias,
                        ST* __restrict__ xl, ST* __restrict__ xr,
                        float* __restrict__ out, int n) {
    __shared__ float As[64][128];   // [row][k], k XOR-swizzled by ((row>>2)&3)<<3
    __shared__ float Bs[128][64];   // [k][col]

    int cb = blockIdx.x % 10;
    int rb = blockIdx.x / 10;
    int row0 = rb * 64;

    const float* B; const float* bvec;
    int ldB, col0; bool isRes = false;
    if (cb < 4)      { B = Wl;   ldB = 256; col0 = cb * 64;       bvec = bl;   }
    else if (cb < 8) { B = Wr;   ldB = 256; col0 = (cb - 4) * 64; bvec = br;   }
    else             { B = resW; ldB = 128; col0 = (cb - 8) * 64; bvec = bias; isRes = true; }
    ST* dstS = (cb < 4) ? xl : xr;

    int tid = threadIdx.x;

    // stage A tile: load x rows, LayerNorm+ReLU fused (32 threads = one row,
    // half-wave shuffle reduction), store swizzled.
    {
        int r  = tid >> 5;            // 0..7
        int k4 = (tid & 31) * 4;      // 0,4,...,124
        float4 g4  = *(const float4*)(gamma + k4);
        float4 be4 = *(const float4*)(beta + k4);
#pragma unroll
        for (int i = 0; i < 8; ++i) {
            int row = r + i * 8;
            int grow = row0 + row;
            float4 a = (grow < n) ? *(const float4*)(x + (size_t)grow * DCH + k4)
                                  : make_float4(0.f, 0.f, 0.f, 0.f);
            float s  = a.x + a.y + a.z + a.w;
            float sq = a.x * a.x + a.y * a.y + a.z * a.z + a.w * a.w;
#pragma unroll
            for (int msk = 16; msk; msk >>= 1) {
                s  += __shfl_xor(s, msk);
                sq += __shfl_xor(sq, msk);
            }
            float mu = s * (1.f / DCH);
            float rs = rsqrtf(sq * (1.f / DCH) - mu * mu + 1e-5f);
            a.x = fmaxf((a.x - mu) * rs * g4.x + be4.x, 0.f);
            a.y = fmaxf((a.y - mu) * rs * g4.y + be4.y, 0.f);
            a.z = fmaxf((a.z - mu) * rs * g4.z + be4.z, 0.f);
            a.w = fmaxf((a.w - mu) * rs * g4.w + be4.w, 0.f);
            int k4s = k4 ^ (((row >> 2) & 3) << 3);
            *(float4*)&As[row][k4s] = a;
        }
    }
    // stage B tile (128 k x 64 cols)
    {
        int c4 = (tid & 15) * 4;
        int k  = tid >> 4;            // 0..15
#pragma unroll
        for (int i = 0; i < 8; ++i) {
            int kk = k + i * 16;
            *(float4*)&Bs[kk][c4] = *(const float4*)(B + (size_t)kk * ldB + col0 + c4);
        }
    }
    __syncthreads();

    int tx = tid & 15, ty = tid >> 4;  // 16 x 16
    int sw = (ty & 3) << 3;
    float acc[4][4] = {};
#pragma unroll 8
    for (int k = 0; k < 128; ++k) {
        float4 b = *(const float4*)&Bs[k][tx * 4];
        int ks = k ^ sw;
        float a0 = As[ty * 4 + 0][ks];
        float a1 = As[ty * 4 + 1][ks];
        float a2 = As[ty * 4 + 2][ks];
        float a3 = As[ty * 4 + 3][ks];
        acc[0][0] = fmaf(a0, b.x, acc[0][0]); acc[0][1] = fmaf(a0, b.y, acc[0][1]);
        acc[0][2] = fmaf(a0, b.z, acc[0][2]); acc[0][3] = fmaf(a0, b.w, acc[0][3]);
        acc[1][0] = fmaf(a1, b.x, acc[1][0]); acc[1][1] = fmaf(a1, b.y, acc[1][1]);
        acc[1][2] = fmaf(a1, b.z, acc[1][2]); acc[1][3] = fmaf(a1, b.w, acc[1][3]);
        acc[2][0] = fmaf(a2, b.x, acc[2][0]); acc[2][1] = fmaf(a2, b.y, acc[2][1]);
        acc[2][2] = fmaf(a2, b.z, acc[2][2]); acc[2][3] = fmaf(a2, b.w, acc[2][3]);
        acc[3][0] = fmaf(a3, b.x, acc[3][0]); acc[3][1] = fmaf(a3, b.y, acc[3][1]);
        acc[3][2] = fmaf(a3, b.z, acc[3][2]); acc[3][3] = fmaf(a3, b.w, acc[3][3]);
    }

#pragma unroll
    for (int i = 0; i < 4; ++i) {
        int row = row0 + ty * 4 + i;
        if (row < n) {
#pragma unroll
            for (int j = 0; j < 4; ++j) {
                int col = col0 + tx * 4 + j;
                float v = acc[i][j] + bvec[col];
                if (isRes) {
                    out[(size_t)row * DCH + col] = v + x[(size_t)row * DCH + col];
                } else {
                    st1(&dstS[(size_t)row * 256 + col], v);
                }
            }
        }
    }
}

// -------------------------------------- pass A: per-edge raw alpha + seg max
template <typename ST>
__launch_bounds__(256)
__global__ void edge_alpha(const int* __restrict__ src, const int* __restrict__ dst,
                           const ST* __restrict__ xl, const ST* __restrict__ xr,
                           const float* __restrict__ att,
                           float* __restrict__ alpha, float* __restrict__ mbuf, int E) {
    int lane = threadIdx.x & 63;
    int wid  = (blockIdx.x * blockDim.x + threadIdx.x) >> 6;
    int nw   = (gridDim.x * blockDim.x) >> 6;
    float4 av = *(const float4*)(att + lane * 4);  // flat[256]: lanes 0..31 head0
    for (int e = wid; e < E; e += nw) {
        int s = src[e], t = dst[e];
        float4 l4 = ld4(xl + (size_t)s * 256 + lane * 4);
        float4 r4 = ld4(xr + (size_t)t * 256 + lane * 4);
        float vx = l4.x + r4.x; vx = vx > 0.f ? vx : NEG_SLOPE * vx;
        float vy = l4.y + r4.y; vy = vy > 0.f ? vy : NEG_SLOPE * vy;
        float vz = l4.z + r4.z; vz = vz > 0.f ? vz : NEG_SLOPE * vz;
        float vw = l4.w + r4.w; vw = vw > 0.f ? vw : NEG_SLOPE * vw;
        float p = vx * av.x + vy * av.y + vz * av.z + vw * av.w;
#pragma unroll
        for (int msk = 16; msk; msk >>= 1) p += __shfl_xor(p, msk);
        if (lane == 0 || lane == 32) {
            int hh = lane >> 5;
            alpha[(size_t)e * NHEADS + hh] = p;
            atomicMaxF(&mbuf[t * NHEADS + hh], p);
        }
    }
}

// -------------------------------------- pass B: a = exp(alpha - m), z += a
__global__ void softmax_z(const int* __restrict__ dst, const float* __restrict__ mbuf,
                          float* __restrict__ alpha, float* __restrict__ zbuf, int E) {
    int total = E * NHEADS;
    for (int i = blockIdx.x * blockDim.x + threadIdx.x; i < total;
         i += gridDim.x * blockDim.x) {
        int e = i >> 1, hh = i & 1;
        int t = dst[e];
        float a = __expf(alpha[i] - mbuf[t * NHEADS + hh]);
        alpha[i] = a;
        unsafeAtomicAdd(&zbuf[t * NHEADS + hh], a);
    }
}

// ------------------- pass C: out[dst] += sum_h xl[src,h]*alpha_h/(z+eps)/H
template <typename ST>
__launch_bounds__(256)
__global__ void scatter_edges(const int* __restrict__ src, const int* __restrict__ dst,
                              const ST* __restrict__ xl, const float* __restrict__ alpha,
                              const float* __restrict__ zbuf, float* __restrict__ out, int E) {
    int lane = threadIdx.x & 63;
    int wid  = (blockIdx.x * blockDim.x + threadIdx.x) >> 6;
    int nw   = (gridDim.x * blockDim.x) >> 6;
    for (int e = wid; e < E; e += nw) {
        int s = src[e], t = dst[e];
        float w0 = alpha[(size_t)e * 2 + 0] / (zbuf[t * 2 + 0] + 1e-16f) * 0.5f;
        float w1 = alpha[(size_t)e * 2 + 1] / (zbuf[t * 2 + 1] + 1e-16f) * 0.5f;
        float2 a = ld2(xl + (size_t)s * 256 + 2 * lane);        // head0, d = 2*lane
        float2 b = ld2(xl + (size_t)s * 256 + 128 + 2 * lane);  // head1, d = 2*lane
        float cx = a.x * w0 + b.x * w1;
        float cy = a.y * w0 + b.y * w1;
        float* o = out + (size_t)t * DCH + 2 * lane;
        unsafeAtomicAdd(o,     cx);
        unsafeAtomicAdd(o + 1, cy);
    }
}

// --------------------------------------------------------------------- launch
extern "C" void kernel_launch(void* const* d_in, const int* in_sizes, int n_in,
                              void* d_out, int out_size, void* d_ws, size_t ws_size,
                              hipStream_t stream) {
    const float* x     = (const float*)d_in[0];
    const int*   ei    = (const int*)d_in[1];
    const float* gamma = (const float*)d_in[2];
    const float* beta  = (const float*)d_in[3];
    const float* Wl    = (const float*)d_in[4];
    const float* bl    = (const float*)d_in[5];
    const float* Wr    = (const float*)d_in[6];
    const float* br    = (const float*)d_in[7];
    const float* att   = (const float*)d_in[8];
    const float* resW  = (const float*)d_in[9];
    const float* bias  = (const float*)d_in[10];
    float* out = (float*)d_out;

    int n = in_sizes[0] / DCH;
    int E = in_sizes[1] / 2;
    const int* src = ei;
    const int* dstIdx = ei + E;

    char* ws = (char*)d_ws;
    size_t off = 0;
    auto alloc = [&](size_t bytes) -> void* {
        void* p = ws + off;
        off = (off + bytes + 255) & ~(size_t)255;
        return p;
    };

    // plan selection: f32 xl/xr needs ~219.2 MB of d_ws, bf16 plan ~116.8 MB.
    size_t smallBytes = (size_t)E * NHEADS * 4 + 2 * (size_t)n * NHEADS * 4 + 4096;
    size_t needF32 = 2 * (size_t)n * NHEADS * DCH * 4 + smallBytes;
    bool useF32 = ws_size >= needF32;

    int rb = (n + 63) / 64;
    if (useF32) {
        float* xl    = (float*)alloc((size_t)n * NHEADS * DCH * 4);  // 102.4 MB
        float* xr    = (float*)alloc((size_t)n * NHEADS * DCH * 4);  // 102.4 MB
        float* alpha = (float*)alloc((size_t)E * NHEADS * 4);        // 12.8 MB
        float* mbuf  = (float*)alloc((size_t)n * NHEADS * 4);        // 0.8 MB
        float* zbuf  = (float*)alloc((size_t)n * NHEADS * 4);        // 0.8 MB
        init_mz<<<(n * NHEADS + 255) / 256, 256, 0, stream>>>(mbuf, zbuf, n * NHEADS);
        gemm_ln<float><<<rb * 10, 256, 0, stream>>>(x, gamma, beta, Wl, bl, Wr, br,
                                                    resW, bias, xl, xr, out, n);
        edge_alpha<float><<<4096, 256, 0, stream>>>(src, dstIdx, xl, xr, att, alpha, mbuf, E);
        softmax_z<<<4096, 256, 0, stream>>>(dstIdx, mbuf, alpha, zbuf, E);
        scatter_edges<float><<<4096, 256, 0, stream>>>(src, dstIdx, xl, alpha, zbuf, out, E);
    } else {
        __hip_bfloat16* xl = (__hip_bfloat16*)alloc((size_t)n * NHEADS * DCH * 2);  // 51.2 MB
        __hip_bfloat16* xr = (__hip_bfloat16*)alloc((size_t)n * NHEADS * DCH * 2);  // 51.2 MB
        float* alpha = (float*)alloc((size_t)E * NHEADS * 4);
        float* mbuf  = (float*)alloc((size_t)n * NHEADS * 4);
        float* zbuf  = (float*)alloc((size_t)n * NHEADS * 4);
        init_mz<<<(n * NHEADS + 255) / 256, 256, 0, stream>>>(mbuf, zbuf, n * NHEADS);
        gemm_ln<__hip_bfloat16><<<rb * 10, 256, 0, stream>>>(x, gamma, beta, Wl, bl, Wr, br,
                                                             resW, bias, xl, xr, out, n);
        edge_alpha<__hip_bfloat16><<<4096, 256, 0, stream>>>(src, dstIdx, xl, xr, att,
                                                             alpha, mbuf, E);
        softmax_z<<<4096, 256, 0, stream>>>(dstIdx, mbuf, alpha, zbuf, E);
        scatter_edges<__hip_bfloat16><<<4096, 256, 0, stream>>>(src, dstIdx, xl, alpha,
                                                                zbuf, out, E);
    }
}

// Round 3
// 1216.262 us; speedup vs baseline: 1.9806x; 1.9806x over previous
//
#include <hip/hip_runtime.h>
#include <hip/hip_bf16.h>
#include <cstdint>
#include <cstddef>

#define DCH 128
#define NHEADS 2
#define NEG_SLOPE 0.2f

// ---------------------------------------------------------------- utilities
__device__ __forceinline__ float bf2f(unsigned short u) {
    union { unsigned int i; float f; } v; v.i = ((unsigned int)u) << 16; return v.f;
}
__device__ __forceinline__ float4 ld4(const float* p) { return *(const float4*)p; }
__device__ __forceinline__ float4 ld4(const __hip_bfloat16* p) {
    ushort4 u = *(const ushort4*)p;
    return make_float4(bf2f(u.x), bf2f(u.y), bf2f(u.z), bf2f(u.w));
}
__device__ __forceinline__ void st1(float* p, float v) { *p = v; }
__device__ __forceinline__ void st1(__hip_bfloat16* p, float v) { *p = __float2bfloat16(v); }

// --------------------------------------------------- fused LN+ReLU + 3 GEMMs
// Conceptual C[N,640]: cols 0..255 -> xl = h@Wl+bl, 256..511 -> xr = h@Wr+br,
// 512..639 -> d_out = x + h@res_W + bias. h = relu(LN(x)) computed on the fly
// during A staging. Tile 64x64, K=128 one-shot, 4x4 micro-tile per thread.
template <typename ST>
__launch_bounds__(256, 2)
__global__ void gemm_ln(const float* __restrict__ x,
                        const float* __restrict__ gamma, const float* __restrict__ beta,
                        const float* __restrict__ Wl, const float* __restrict__ bl,
                        const float* __restrict__ Wr, const float* __restrict__ br,
                        const float* __restrict__ resW, const float* __restrict__ bias,
                        ST* __restrict__ xl, ST* __restrict__ xr,
                        float* __restrict__ out, int n) {
    __shared__ float As[64][128];   // [row][k], k XOR-swizzled by ((row>>2)&3)<<3
    __shared__ float Bs[128][64];   // [k][col]

    int cb = blockIdx.x % 10;
    int rb = blockIdx.x / 10;
    int row0 = rb * 64;

    const float* B; const float* bvec;
    int ldB, col0; bool isRes = false;
    if (cb < 4)      { B = Wl;   ldB = 256; col0 = cb * 64;       bvec = bl;   }
    else if (cb < 8) { B = Wr;   ldB = 256; col0 = (cb - 4) * 64; bvec = br;   }
    else             { B = resW; ldB = 128; col0 = (cb - 8) * 64; bvec = bias; isRes = true; }
    ST* dstS = (cb < 4) ? xl : xr;

    int tid = threadIdx.x;

    // stage A tile: load x rows, LayerNorm+ReLU fused (32 threads = one row)
    {
        int r  = tid >> 5;            // 0..7
        int k4 = (tid & 31) * 4;      // 0,4,...,124
        float4 g4  = *(const float4*)(gamma + k4);
        float4 be4 = *(const float4*)(beta + k4);
#pragma unroll
        for (int i = 0; i < 8; ++i) {
            int row = r + i * 8;
            int grow = row0 + row;
            float4 a = (grow < n) ? *(const float4*)(x + (size_t)grow * DCH + k4)
                                  : make_float4(0.f, 0.f, 0.f, 0.f);
            float s  = a.x + a.y + a.z + a.w;
            float sq = a.x * a.x + a.y * a.y + a.z * a.z + a.w * a.w;
#pragma unroll
            for (int msk = 16; msk; msk >>= 1) {
                s  += __shfl_xor(s, msk);
                sq += __shfl_xor(sq, msk);
            }
            float mu = s * (1.f / DCH);
            float rs = rsqrtf(sq * (1.f / DCH) - mu * mu + 1e-5f);
            a.x = fmaxf((a.x - mu) * rs * g4.x + be4.x, 0.f);
            a.y = fmaxf((a.y - mu) * rs * g4.y + be4.y, 0.f);
            a.z = fmaxf((a.z - mu) * rs * g4.z + be4.z, 0.f);
            a.w = fmaxf((a.w - mu) * rs * g4.w + be4.w, 0.f);
            int k4s = k4 ^ (((row >> 2) & 3) << 3);
            *(float4*)&As[row][k4s] = a;
        }
    }
    // stage B tile (128 k x 64 cols)
    {
        int c4 = (tid & 15) * 4;
        int k  = tid >> 4;            // 0..15
#pragma unroll
        for (int i = 0; i < 8; ++i) {
            int kk = k + i * 16;
            *(float4*)&Bs[kk][c4] = *(const float4*)(B + (size_t)kk * ldB + col0 + c4);
        }
    }
    __syncthreads();

    int tx = tid & 15, ty = tid >> 4;  // 16 x 16
    int sw = (ty & 3) << 3;
    float acc[4][4] = {};
#pragma unroll 8
    for (int k = 0; k < 128; ++k) {
        float4 b = *(const float4*)&Bs[k][tx * 4];
        int ks = k ^ sw;
        float a0 = As[ty * 4 + 0][ks];
        float a1 = As[ty * 4 + 1][ks];
        float a2 = As[ty * 4 + 2][ks];
        float a3 = As[ty * 4 + 3][ks];
        acc[0][0] = fmaf(a0, b.x, acc[0][0]); acc[0][1] = fmaf(a0, b.y, acc[0][1]);
        acc[0][2] = fmaf(a0, b.z, acc[0][2]); acc[0][3] = fmaf(a0, b.w, acc[0][3]);
        acc[1][0] = fmaf(a1, b.x, acc[1][0]); acc[1][1] = fmaf(a1, b.y, acc[1][1]);
        acc[1][2] = fmaf(a1, b.z, acc[1][2]); acc[1][3] = fmaf(a1, b.w, acc[1][3]);
        acc[2][0] = fmaf(a2, b.x, acc[2][0]); acc[2][1] = fmaf(a2, b.y, acc[2][1]);
        acc[2][2] = fmaf(a2, b.z, acc[2][2]); acc[2][3] = fmaf(a2, b.w, acc[2][3]);
        acc[3][0] = fmaf(a3, b.x, acc[3][0]); acc[3][1] = fmaf(a3, b.y, acc[3][1]);
        acc[3][2] = fmaf(a3, b.z, acc[3][2]); acc[3][3] = fmaf(a3, b.w, acc[3][3]);
    }

#pragma unroll
    for (int i = 0; i < 4; ++i) {
        int row = row0 + ty * 4 + i;
        if (row < n) {
#pragma unroll
            for (int j = 0; j < 4; ++j) {
                int col = col0 + tx * 4 + j;
                float v = acc[i][j] + bvec[col];
                if (isRes) {
                    out[(size_t)row * DCH + col] = v + x[(size_t)row * DCH + col];
                } else {
                    st1(&dstS[(size_t)row * 256 + col], v);
                }
            }
        }
    }
}

// --------------------------------------------------------------- CSR build
__global__ void zero2(int* __restrict__ a, int* __restrict__ b, int n) {
    int i = blockIdx.x * blockDim.x + threadIdx.x;
    if (i < n) { a[i] = 0; b[i] = 0; }
}

__global__ void hist_dst(const int* __restrict__ dst, int* __restrict__ cnt, int E) {
    for (int i = blockIdx.x * blockDim.x + threadIdx.x; i < E;
         i += gridDim.x * blockDim.x)
        atomicAdd(&cnt[dst[i]], 1);
}

// per-block exclusive scan (256 elems/block) + block sums
__global__ void scan_block(const int* __restrict__ cnt, int* __restrict__ offs,
                           int* __restrict__ bsum, int n) {
    __shared__ int sm[256];
    int t = threadIdx.x;
    int i = blockIdx.x * 256 + t;
    int v = (i < n) ? cnt[i] : 0;
    sm[t] = v;
    __syncthreads();
#pragma unroll
    for (int d = 1; d < 256; d <<= 1) {
        int add = (t >= d) ? sm[t - d] : 0;
        __syncthreads();
        sm[t] += add;
        __syncthreads();
    }
    if (i < n) offs[i] = sm[t] - v;          // exclusive within block
    if (t == 255) bsum[blockIdx.x] = sm[t];  // block total
}

__global__ void scan_bsum(int* __restrict__ bsum, int nb) {
    if (blockIdx.x == 0 && threadIdx.x == 0) {
        int acc = 0;
        for (int i = 0; i < nb; ++i) { int v = bsum[i]; bsum[i] = acc; acc += v; }
    }
}

__global__ void scan_add(int* __restrict__ offs, const int* __restrict__ bsum,
                         int n, int E) {
    int i = blockIdx.x * 256 + threadIdx.x;
    if (i < n) offs[i] += bsum[blockIdx.x];
    if (i == 0) offs[n] = E;
}

__global__ void fill_csr(const int* __restrict__ src, const int* __restrict__ dst,
                         const int* __restrict__ offs, int* __restrict__ fillc,
                         int* __restrict__ sbuf, int E) {
    for (int i = blockIdx.x * blockDim.x + threadIdx.x; i < E;
         i += gridDim.x * blockDim.x) {
        int t = dst[i];
        int pos = offs[t] + atomicAdd(&fillc[t], 1);
        sbuf[pos] = src[i];
    }
}

// --------------------------------- fused attention + softmax + aggregation
// One wave owns one dst node t: xr[t] in registers; pass 1 = online (m,z)
// over the bucket; pass 2 = recompute logits (xl re-reads are L2/L3-hot),
// weight, accumulate; head-mean via shfl_xor(32); non-atomic RMW on out[t].
template <typename ST>
__launch_bounds__(256)
__global__ void gat_aggregate(const int* __restrict__ offs, const int* __restrict__ sbuf,
                              const ST* __restrict__ xl, const ST* __restrict__ xr,
                              const float* __restrict__ att,
                              float* __restrict__ out, int n) {
    int lane = threadIdx.x & 63;
    int wid  = (blockIdx.x * blockDim.x + threadIdx.x) >> 6;
    int nw   = (gridDim.x * blockDim.x) >> 6;
    float4 av = *(const float4*)(att + lane * 4);  // flat[256]: lanes 0..31 head0

    for (int t = wid; t < n; t += nw) {
        int beg = offs[t];
        int end = offs[t + 1];
        if (beg == end) continue;
        float4 r4 = ld4(xr + (size_t)t * 256 + lane * 4);

        // pass 1: online segment max + partition function
        float m0 = -INFINITY, m1 = -INFINITY, z0 = 0.f, z1 = 0.f;
        for (int j = beg; j < end; ++j) {
            int s = sbuf[j];
            float4 l4 = ld4(xl + (size_t)s * 256 + lane * 4);
            float vx = l4.x + r4.x; vx = vx > 0.f ? vx : NEG_SLOPE * vx;
            float vy = l4.y + r4.y; vy = vy > 0.f ? vy : NEG_SLOPE * vy;
            float vz = l4.z + r4.z; vz = vz > 0.f ? vz : NEG_SLOPE * vz;
            float vw = l4.w + r4.w; vw = vw > 0.f ? vw : NEG_SLOPE * vw;
            float p = vx * av.x + vy * av.y + vz * av.z + vw * av.w;
#pragma unroll
            for (int msk = 16; msk; msk >>= 1) p += __shfl_xor(p, msk);
            float p0 = __shfl(p, 0), p1 = __shfl(p, 32);
            float mn0 = fmaxf(m0, p0);
            z0 = z0 * __expf(m0 - mn0) + __expf(p0 - mn0); m0 = mn0;
            float mn1 = fmaxf(m1, p1);
            z1 = z1 * __expf(m1 - mn1) + __expf(p1 - mn1); m1 = mn1;
        }
        float inv0 = 0.5f / (z0 + 1e-16f);
        float inv1 = 0.5f / (z1 + 1e-16f);

        // pass 2: recompute logits, weight, accumulate
        float4 acc = make_float4(0.f, 0.f, 0.f, 0.f);
        for (int j = beg; j < end; ++j) {
            int s = sbuf[j];
            float4 l4 = ld4(xl + (size_t)s * 256 + lane * 4);
            float vx = l4.x + r4.x; vx = vx > 0.f ? vx : NEG_SLOPE * vx;
            float vy = l4.y + r4.y; vy = vy > 0.f ? vy : NEG_SLOPE * vy;
            float vz = l4.z + r4.z; vz = vz > 0.f ? vz : NEG_SLOPE * vz;
            float vw = l4.w + r4.w; vw = vw > 0.f ? vw : NEG_SLOPE * vw;
            float p = vx * av.x + vy * av.y + vz * av.z + vw * av.w;
#pragma unroll
            for (int msk = 16; msk; msk >>= 1) p += __shfl_xor(p, msk);
            float p0 = __shfl(p, 0), p1 = __shfl(p, 32);
            float w = (lane < 32) ? __expf(p0 - m0) * inv0 : __expf(p1 - m1) * inv1;
            acc.x = fmaf(l4.x, w, acc.x);
            acc.y = fmaf(l4.y, w, acc.y);
            acc.z = fmaf(l4.z, w, acc.z);
            acc.w = fmaf(l4.w, w, acc.w);
        }
        // head mean: lane L (<32) += lane L+32 (same channels, head 1)
        acc.x += __shfl_xor(acc.x, 32);
        acc.y += __shfl_xor(acc.y, 32);
        acc.z += __shfl_xor(acc.z, 32);
        acc.w += __shfl_xor(acc.w, 32);
        if (lane < 32) {
            float4* o = (float4*)(out + (size_t)t * DCH + lane * 4);
            float4 cur = *o;
            cur.x += acc.x; cur.y += acc.y; cur.z += acc.z; cur.w += acc.w;
            *o = cur;
        }
    }
}

// --------------------------------------------------------------------- launch
extern "C" void kernel_launch(void* const* d_in, const int* in_sizes, int n_in,
                              void* d_out, int out_size, void* d_ws, size_t ws_size,
                              hipStream_t stream) {
    const float* x     = (const float*)d_in[0];
    const int*   ei    = (const int*)d_in[1];
    const float* gamma = (const float*)d_in[2];
    const float* beta  = (const float*)d_in[3];
    const float* Wl    = (const float*)d_in[4];
    const float* bl    = (const float*)d_in[5];
    const float* Wr    = (const float*)d_in[6];
    const float* br    = (const float*)d_in[7];
    const float* att   = (const float*)d_in[8];
    const float* resW  = (const float*)d_in[9];
    const float* bias  = (const float*)d_in[10];
    float* out = (float*)d_out;

    int n = in_sizes[0] / DCH;
    int E = in_sizes[1] / 2;
    const int* src = ei;
    const int* dstIdx = ei + E;

    char* ws = (char*)d_ws;
    size_t off = 0;
    auto alloc = [&](size_t bytes) -> void* {
        void* p = ws + off;
        off = (off + bytes + 255) & ~(size_t)255;
        return p;
    };

    int nb = (n + 255) / 256;

    // shared small buffers
    // f32 plan needs ~212.5 MB; bf16 fallback ~110 MB.
    size_t smallBytes = (size_t)(3 * n + nb + 64) * 4 + (size_t)E * 4 + 8192;
    size_t needF32 = 2 * (size_t)n * NHEADS * DCH * 4 + smallBytes;
    bool useF32 = ws_size >= needF32;

    void* xlRaw; void* xrRaw;
    if (useF32) {
        xlRaw = alloc((size_t)n * NHEADS * DCH * 4);  // 102.4 MB
        xrRaw = alloc((size_t)n * NHEADS * DCH * 4);  // 102.4 MB
    } else {
        xlRaw = alloc((size_t)n * NHEADS * DCH * 2);  // 51.2 MB
        xrRaw = alloc((size_t)n * NHEADS * DCH * 2);  // 51.2 MB
    }
    int* cnt   = (int*)alloc((size_t)n * 4);
    int* offs  = (int*)alloc((size_t)(n + 1) * 4);
    int* bsum  = (int*)alloc((size_t)nb * 4);
    int* fillc = (int*)alloc((size_t)n * 4);
    int* sbuf  = (int*)alloc((size_t)E * 4);          // 6.4 MB

    int rb = (n + 63) / 64;

    zero2<<<(n + 255) / 256, 256, 0, stream>>>(cnt, fillc, n);
    hist_dst<<<2048, 256, 0, stream>>>(dstIdx, cnt, E);
    scan_block<<<nb, 256, 0, stream>>>(cnt, offs, bsum, n);
    scan_bsum<<<1, 64, 0, stream>>>(bsum, nb);
    scan_add<<<nb, 256, 0, stream>>>(offs, bsum, n, E);
    fill_csr<<<2048, 256, 0, stream>>>(src, dstIdx, offs, fillc, sbuf, E);

    if (useF32) {
        float* xl = (float*)xlRaw; float* xr = (float*)xrRaw;
        gemm_ln<float><<<rb * 10, 256, 0, stream>>>(x, gamma, beta, Wl, bl, Wr, br,
                                                    resW, bias, xl, xr, out, n);
        gat_aggregate<float><<<2048, 256, 0, stream>>>(offs, sbuf, xl, xr, att, out, n);
    } else {
        __hip_bfloat16* xl = (__hip_bfloat16*)xlRaw;
        __hip_bfloat16* xr = (__hip_bfloat16*)xrRaw;
        gemm_ln<__hip_bfloat16><<<rb * 10, 256, 0, stream>>>(x, gamma, beta, Wl, bl, Wr, br,
                                                             resW, bias, xl, xr, out, n);
        gat_aggregate<__hip_bfloat16><<<2048, 256, 0, stream>>>(offs, sbuf, xl, xr, att, out, n);
    }
}

// Round 4
// 735.515 us; speedup vs baseline: 3.2751x; 1.6536x over previous
//
#include <hip/hip_runtime.h>
#include <hip/hip_bf16.h>
#include <cstdint>
#include <cstddef>

#define DCH 128
#define NHEADS 2
#define NEG_SLOPE 0.2f

typedef __attribute__((ext_vector_type(8))) short short8v;
typedef __attribute__((ext_vector_type(4))) float f32x4;

// ---------------------------------------------------------------- utilities
__device__ __forceinline__ float bf2f(unsigned short u) {
    union { unsigned int i; float f; } v; v.i = ((unsigned int)u) << 16; return v.f;
}
__device__ __forceinline__ unsigned short f2bf(float f) {
    union { float f; unsigned int i; } v; v.f = f;
    unsigned int r = v.i + 0x7fffu + ((v.i >> 16) & 1u);   // RNE
    return (unsigned short)(r >> 16);
}
__device__ __forceinline__ float4 ld4(const __hip_bfloat16* p) {
    ushort4 u = *(const ushort4*)p;
    return make_float4(bf2f(u.x), bf2f(u.y), bf2f(u.z), bf2f(u.w));
}

// ------------------------------------------- weights -> bf16 fragment order
// Fragment f = ct*4+ks (ct in [0,40), ks in [0,4)); lane needs
// B[k = ks*32 + (lane>>4)*8 + j][col = ct*16 + (lane&15)], j=0..7, stored at
// wfrag[(f*64+lane)*8 + j]. Global cols: [0,256)=Wl, [256,512)=Wr, [512,640)=resW.
__global__ void prep_wfrag(const float* __restrict__ Wl, const float* __restrict__ Wr,
                           const float* __restrict__ resW, unsigned short* __restrict__ wfrag) {
    int gid  = blockIdx.x * 256 + threadIdx.x;   // 10240 threads
    int lane = gid & 63;
    int f    = gid >> 6;                          // 0..159
    int ks   = f & 3;
    int ct   = f >> 2;
    int col  = ct * 16 + (lane & 15);
    int k0   = ks * 32 + (lane >> 4) * 8;
    const float* W; int ldB, c;
    if (col < 256)      { W = Wl;   ldB = 256; c = col; }
    else if (col < 512) { W = Wr;   ldB = 256; c = col - 256; }
    else                { W = resW; ldB = 128; c = col - 512; }
    unsigned short tmp[8];
#pragma unroll
    for (int j = 0; j < 8; ++j) tmp[j] = f2bf(W[(size_t)(k0 + j) * ldB + c]);
    ushort4* dst = (ushort4*)(wfrag + (size_t)gid * 8);
    dst[0] = make_ushort4(tmp[0], tmp[1], tmp[2], tmp[3]);
    dst[1] = make_ushort4(tmp[4], tmp[5], tmp[6], tmp[7]);
}

// ------------------------------- fused LN+ReLU + MFMA GEMM (64 rows x 640 cols)
// A = relu(LN(x)) staged bf16 in LDS, XOR-swizzled (byte ^= (row&7)<<4).
// Wave w computes rows [w*16, w*16+16) x all 40 col-tiles; 4 mfma per tile.
// cols 0..255 -> xl (bf16), 256..511 -> xr (bf16), 512..639 -> out = x+h@resW+bias.
__launch_bounds__(256)
__global__ void gemm_mfma(const float* __restrict__ x,
                          const float* __restrict__ gamma, const float* __restrict__ beta,
                          const unsigned short* __restrict__ wfrag,
                          const float* __restrict__ bl, const float* __restrict__ br,
                          const float* __restrict__ bias,
                          unsigned short* __restrict__ xl, unsigned short* __restrict__ xr,
                          float* __restrict__ out, int n) {
    __shared__ __align__(16) unsigned short As[64 * 128];  // bf16 bits, swizzled
    int row0 = blockIdx.x * 64;
    int tid  = threadIdx.x;

    // ---- stage A with fused LayerNorm+ReLU (32 threads per row)
    {
        int r  = tid >> 5;            // 0..7
        int k4 = (tid & 31) * 4;      // 0,4,...,124
        float4 g4  = *(const float4*)(gamma + k4);
        float4 be4 = *(const float4*)(beta + k4);
#pragma unroll
        for (int i = 0; i < 8; ++i) {
            int row  = r + i * 8;
            int grow = row0 + row;
            float4 a = (grow < n) ? *(const float4*)(x + (size_t)grow * DCH + k4)
                                  : make_float4(0.f, 0.f, 0.f, 0.f);
            float s  = a.x + a.y + a.z + a.w;
            float sq = a.x * a.x + a.y * a.y + a.z * a.z + a.w * a.w;
#pragma unroll
            for (int msk = 16; msk; msk >>= 1) {
                s  += __shfl_xor(s, msk);
                sq += __shfl_xor(sq, msk);
            }
            float mu = s * (1.f / DCH);
            float rs = rsqrtf(sq * (1.f / DCH) - mu * mu + 1e-5f);
            ushort4 u;
            u.x = f2bf(fmaxf((a.x - mu) * rs * g4.x + be4.x, 0.f));
            u.y = f2bf(fmaxf((a.y - mu) * rs * g4.y + be4.y, 0.f));
            u.z = f2bf(fmaxf((a.z - mu) * rs * g4.z + be4.z, 0.f));
            u.w = f2bf(fmaxf((a.w - mu) * rs * g4.w + be4.w, 0.f));
            int byteoff = row * 256 + ((k4 * 2) ^ ((row & 7) << 4));
            *(ushort4*)((char*)As + byteoff) = u;
        }
    }
    __syncthreads();

    int wv = tid >> 6, lane = tid & 63;
    int arow = wv * 16 + (lane & 15);

    // A fragments for this wave's 16 rows, all 4 K-slices (reused over 40 tiles)
    short8v afrag[4];
#pragma unroll
    for (int ks = 0; ks < 4; ++ks) {
        int kbyte = (ks * 64 + (lane >> 4) * 16) ^ ((arow & 7) << 4);
        afrag[ks] = *(const short8v*)((const char*)As + arow * 256 + kbyte);
    }

    int rbase = row0 + wv * 16 + ((lane >> 4) << 2);  // output rows rbase..rbase+3
    const float* xrow = x + (size_t)row0 * DCH;

#pragma unroll 2
    for (int ct = 0; ct < 40; ++ct) {
        const unsigned short* bp = wfrag + ((size_t)(ct * 4) * 64 + lane) * 8;
        short8v b0 = *(const short8v*)(bp);
        short8v b1 = *(const short8v*)(bp + 64 * 8);
        short8v b2 = *(const short8v*)(bp + 128 * 8);
        short8v b3 = *(const short8v*)(bp + 192 * 8);
        f32x4 acc = {0.f, 0.f, 0.f, 0.f};
        acc = __builtin_amdgcn_mfma_f32_16x16x32_bf16(afrag[0], b0, acc, 0, 0, 0);
        acc = __builtin_amdgcn_mfma_f32_16x16x32_bf16(afrag[1], b1, acc, 0, 0, 0);
        acc = __builtin_amdgcn_mfma_f32_16x16x32_bf16(afrag[2], b2, acc, 0, 0, 0);
        acc = __builtin_amdgcn_mfma_f32_16x16x32_bf16(afrag[3], b3, acc, 0, 0, 0);

        int gc = ct * 16 + (lane & 15);
        if (gc < 512) {
            unsigned short* dst; int c; const float* bv;
            if (gc < 256) { dst = xl; c = gc;       bv = bl; }
            else          { dst = xr; c = gc - 256; bv = br; }
            float bb = bv[c];
#pragma unroll
            for (int i = 0; i < 4; ++i) {
                int row = rbase + i;
                if (row < n) dst[(size_t)row * 256 + c] = f2bf(acc[i] + bb);
            }
        } else {
            int c = gc - 512;
            float bb = bias[c];
#pragma unroll
            for (int i = 0; i < 4; ++i) {
                int row = rbase + i;
                if (row < n)
                    out[(size_t)row * DCH + c] = acc[i] + bb + x[(size_t)row * DCH + c];
            }
        }
    }
    (void)xrow;
}

// --------------------------------------------------------------- CSR build
__global__ void zero2(int* __restrict__ a, int* __restrict__ b, int n) {
    int i = blockIdx.x * blockDim.x + threadIdx.x;
    if (i < n) { a[i] = 0; b[i] = 0; }
}

__global__ void hist_dst(const int* __restrict__ dst, int* __restrict__ cnt, int E) {
    for (int i = blockIdx.x * blockDim.x + threadIdx.x; i < E;
         i += gridDim.x * blockDim.x)
        atomicAdd(&cnt[dst[i]], 1);
}

__global__ void scan_block(const int* __restrict__ cnt, int* __restrict__ offs,
                           int* __restrict__ bsum, int n) {
    __shared__ int sm[256];
    int t = threadIdx.x;
    int i = blockIdx.x * 256 + t;
    int v = (i < n) ? cnt[i] : 0;
    sm[t] = v;
    __syncthreads();
#pragma unroll
    for (int d = 1; d < 256; d <<= 1) {
        int add = (t >= d) ? sm[t - d] : 0;
        __syncthreads();
        sm[t] += add;
        __syncthreads();
    }
    if (i < n) offs[i] = sm[t] - v;
    if (t == 255) bsum[blockIdx.x] = sm[t];
}

__global__ void scan_bsum(int* __restrict__ bsum, int nb) {
    if (blockIdx.x == 0 && threadIdx.x == 0) {
        int acc = 0;
        for (int i = 0; i < nb; ++i) { int v = bsum[i]; bsum[i] = acc; acc += v; }
    }
}

__global__ void scan_add(int* __restrict__ offs, const int* __restrict__ bsum,
                         int n, int E) {
    int i = blockIdx.x * 256 + threadIdx.x;
    if (i < n) offs[i] += bsum[blockIdx.x];
    if (i == 0) offs[n] = E;
}

__global__ void fill_csr(const int* __restrict__ src, const int* __restrict__ dst,
                         const int* __restrict__ offs, int* __restrict__ fillc,
                         int* __restrict__ sbuf, int E) {
    for (int i = blockIdx.x * blockDim.x + threadIdx.x; i < E;
         i += gridDim.x * blockDim.x) {
        int t = dst[i];
        int pos = offs[t] + atomicAdd(&fillc[t], 1);
        sbuf[pos] = src[i];
    }
}

// --------------------------------- fused attention + softmax + aggregation
// One wave per dst node t; xr[t] in registers; pass 1 online (m,z); pass 2
// recompute + weighted accumulate; head-mean via shfl_xor(32); plain RMW.
__launch_bounds__(256)
__global__ void gat_aggregate(const int* __restrict__ offs, const int* __restrict__ sbuf,
                              const __hip_bfloat16* __restrict__ xl,
                              const __hip_bfloat16* __restrict__ xr,
                              const float* __restrict__ att,
                              float* __restrict__ out, int n) {
    int lane = threadIdx.x & 63;
    int wid  = (blockIdx.x * blockDim.x + threadIdx.x) >> 6;
    int nw   = (gridDim.x * blockDim.x) >> 6;
    float4 av = *(const float4*)(att + lane * 4);  // flat[256]: lanes 0..31 head0

    for (int t = wid; t < n; t += nw) {
        int beg = offs[t];
        int end = offs[t + 1];
        if (beg == end) continue;
        float4 r4 = ld4(xr + (size_t)t * 256 + lane * 4);

        float m0 = -INFINITY, m1 = -INFINITY, z0 = 0.f, z1 = 0.f;
        for (int j = beg; j < end; ++j) {
            int s = sbuf[j];
            float4 l4 = ld4(xl + (size_t)s * 256 + lane * 4);
            float vx = l4.x + r4.x; vx = vx > 0.f ? vx : NEG_SLOPE * vx;
            float vy = l4.y + r4.y; vy = vy > 0.f ? vy : NEG_SLOPE * vy;
            float vz = l4.z + r4.z; vz = vz > 0.f ? vz : NEG_SLOPE * vz;
            float vw = l4.w + r4.w; vw = vw > 0.f ? vw : NEG_SLOPE * vw;
            float p = vx * av.x + vy * av.y + vz * av.z + vw * av.w;
#pragma unroll
            for (int msk = 16; msk; msk >>= 1) p += __shfl_xor(p, msk);
            float p0 = __shfl(p, 0), p1 = __shfl(p, 32);
            float mn0 = fmaxf(m0, p0);
            z0 = z0 * __expf(m0 - mn0) + __expf(p0 - mn0); m0 = mn0;
            float mn1 = fmaxf(m1, p1);
            z1 = z1 * __expf(m1 - mn1) + __expf(p1 - mn1); m1 = mn1;
        }
        float inv0 = 0.5f / (z0 + 1e-16f);
        float inv1 = 0.5f / (z1 + 1e-16f);

        float4 acc = make_float4(0.f, 0.f, 0.f, 0.f);
        for (int j = beg; j < end; ++j) {
            int s = sbuf[j];
            float4 l4 = ld4(xl + (size_t)s * 256 + lane * 4);
            float vx = l4.x + r4.x; vx = vx > 0.f ? vx : NEG_SLOPE * vx;
            float vy = l4.y + r4.y; vy = vy > 0.f ? vy : NEG_SLOPE * vy;
            float vz = l4.z + r4.z; vz = vz > 0.f ? vz : NEG_SLOPE * vz;
            float vw = l4.w + r4.w; vw = vw > 0.f ? vw : NEG_SLOPE * vw;
            float p = vx * av.x + vy * av.y + vz * av.z + vw * av.w;
#pragma unroll
            for (int msk = 16; msk; msk >>= 1) p += __shfl_xor(p, msk);
            float p0 = __shfl(p, 0), p1 = __shfl(p, 32);
            float w = (lane < 32) ? __expf(p0 - m0) * inv0 : __expf(p1 - m1) * inv1;
            acc.x = fmaf(l4.x, w, acc.x);
            acc.y = fmaf(l4.y, w, acc.y);
            acc.z = fmaf(l4.z, w, acc.z);
            acc.w = fmaf(l4.w, w, acc.w);
        }
        acc.x += __shfl_xor(acc.x, 32);
        acc.y += __shfl_xor(acc.y, 32);
        acc.z += __shfl_xor(acc.z, 32);
        acc.w += __shfl_xor(acc.w, 32);
        if (lane < 32) {
            float4* o = (float4*)(out + (size_t)t * DCH + lane * 4);
            float4 cur = *o;
            cur.x += acc.x; cur.y += acc.y; cur.z += acc.z; cur.w += acc.w;
            *o = cur;
        }
    }
}

// --------------------------------------------------------------------- launch
extern "C" void kernel_launch(void* const* d_in, const int* in_sizes, int n_in,
                              void* d_out, int out_size, void* d_ws, size_t ws_size,
                              hipStream_t stream) {
    const float* x     = (const float*)d_in[0];
    const int*   ei    = (const int*)d_in[1];
    const float* gamma = (const float*)d_in[2];
    const float* beta  = (const float*)d_in[3];
    const float* Wl    = (const float*)d_in[4];
    const float* bl    = (const float*)d_in[5];
    const float* Wr    = (const float*)d_in[6];
    const float* br    = (const float*)d_in[7];
    const float* att   = (const float*)d_in[8];
    const float* resW  = (const float*)d_in[9];
    const float* bias  = (const float*)d_in[10];
    float* out = (float*)d_out;

    int n = in_sizes[0] / DCH;
    int E = in_sizes[1] / 2;
    const int* src = ei;
    const int* dstIdx = ei + E;

    char* ws = (char*)d_ws;
    size_t off = 0;
    auto alloc = [&](size_t bytes) -> void* {
        void* p = ws + off;
        off = (off + bytes + 255) & ~(size_t)255;
        return p;
    };

    int nb = (n + 255) / 256;

    unsigned short* xl = (unsigned short*)alloc((size_t)n * 256 * 2);  // 51.2 MB
    unsigned short* xr = (unsigned short*)alloc((size_t)n * 256 * 2);  // 51.2 MB
    unsigned short* wfrag = (unsigned short*)alloc(160 * 64 * 8 * 2);  // 160 KB
    int* cnt   = (int*)alloc((size_t)n * 4);
    int* offs  = (int*)alloc((size_t)(n + 1) * 4);
    int* bsum  = (int*)alloc((size_t)nb * 4);
    int* fillc = (int*)alloc((size_t)n * 4);
    int* sbuf  = (int*)alloc((size_t)E * 4);                           // 6.4 MB

    prep_wfrag<<<40, 256, 0, stream>>>(Wl, Wr, resW, wfrag);
    zero2<<<(n + 255) / 256, 256, 0, stream>>>(cnt, fillc, n);
    hist_dst<<<2048, 256, 0, stream>>>(dstIdx, cnt, E);
    scan_block<<<nb, 256, 0, stream>>>(cnt, offs, bsum, n);
    scan_bsum<<<1, 64, 0, stream>>>(bsum, nb);
    scan_add<<<nb, 256, 0, stream>>>(offs, bsum, n, E);
    fill_csr<<<2048, 256, 0, stream>>>(src, dstIdx, offs, fillc, sbuf, E);

    int nrb = (n + 63) / 64;
    gemm_mfma<<<nrb, 256, 0, stream>>>(x, gamma, beta, wfrag, bl, br, bias,
                                       xl, xr, out, n);
    gat_aggregate<<<2048, 256, 0, stream>>>(offs, sbuf, (const __hip_bfloat16*)xl,
                                            (const __hip_bfloat16*)xr, att, out, n);
}

// Round 5
// 466.052 us; speedup vs baseline: 5.1687x; 1.5782x over previous
//
#include <hip/hip_runtime.h>
#include <hip/hip_bf16.h>
#include <cstdint>
#include <cstddef>

#define DCH 128
#define NHEADS 2
#define NEG_SLOPE 0.2f

typedef __attribute__((ext_vector_type(8))) short short8v;
typedef __attribute__((ext_vector_type(4))) float f32x4;

// ---------------------------------------------------------------- utilities
__device__ __forceinline__ float bf2f(unsigned short u) {
    union { unsigned int i; float f; } v; v.i = ((unsigned int)u) << 16; return v.f;
}
__device__ __forceinline__ unsigned short f2bf(float f) {
    union { float f; unsigned int i; } v; v.f = f;
    unsigned int r = v.i + 0x7fffu + ((v.i >> 16) & 1u);   // RNE
    return (unsigned short)(r >> 16);
}
__device__ __forceinline__ float4 ld4(const __hip_bfloat16* p) {
    ushort4 u = *(const ushort4*)p;
    return make_float4(bf2f(u.x), bf2f(u.y), bf2f(u.z), bf2f(u.w));
}

// ------------------------------------------- weights -> bf16 fragment order
// Fragment f = ct*4+ks (ct in [0,40), ks in [0,4)); lane needs
// B[k = ks*32 + (lane>>4)*8 + j][col = ct*16 + (lane&15)], j=0..7, stored at
// wfrag[(f*64+lane)*8 + j]. Global cols: [0,256)=Wl, [256,512)=Wr, [512,640)=resW.
__global__ void prep_wfrag(const float* __restrict__ Wl, const float* __restrict__ Wr,
                           const float* __restrict__ resW, unsigned short* __restrict__ wfrag) {
    int gid  = blockIdx.x * 256 + threadIdx.x;   // 10240 threads
    int lane = gid & 63;
    int f    = gid >> 6;                          // 0..159
    int ks   = f & 3;
    int ct   = f >> 2;
    int col  = ct * 16 + (lane & 15);
    int k0   = ks * 32 + (lane >> 4) * 8;
    const float* W; int ldB, c;
    if (col < 256)      { W = Wl;   ldB = 256; c = col; }
    else if (col < 512) { W = Wr;   ldB = 256; c = col - 256; }
    else                { W = resW; ldB = 128; c = col - 512; }
    unsigned short tmp[8];
#pragma unroll
    for (int j = 0; j < 8; ++j) tmp[j] = f2bf(W[(size_t)(k0 + j) * ldB + c]);
    ushort4* dst = (ushort4*)(wfrag + (size_t)gid * 8);
    dst[0] = make_ushort4(tmp[0], tmp[1], tmp[2], tmp[3]);
    dst[1] = make_ushort4(tmp[4], tmp[5], tmp[6], tmp[7]);
}

// ------------------------------- fused LN+ReLU + MFMA GEMM (64 rows x 640 cols)
// A = relu(LN(x)) staged bf16 in LDS, XOR-swizzled (byte ^= (row&7)<<4).
// Wave w computes rows [w*16, w*16+16) x all 40 col-tiles; 4 mfma per tile.
// cols 0..255 -> xl (bf16), 256..511 -> xr (bf16), 512..639 -> out = x+h@resW+bias.
__launch_bounds__(256)
__global__ void gemm_mfma(const float* __restrict__ x,
                          const float* __restrict__ gamma, const float* __restrict__ beta,
                          const unsigned short* __restrict__ wfrag,
                          const float* __restrict__ bl, const float* __restrict__ br,
                          const float* __restrict__ bias,
                          unsigned short* __restrict__ xl, unsigned short* __restrict__ xr,
                          float* __restrict__ out, int n) {
    __shared__ __align__(16) unsigned short As[64 * 128];  // bf16 bits, swizzled
    int row0 = blockIdx.x * 64;
    int tid  = threadIdx.x;

    // ---- stage A with fused LayerNorm+ReLU (32 threads per row)
    {
        int r  = tid >> 5;            // 0..7
        int k4 = (tid & 31) * 4;      // 0,4,...,124
        float4 g4  = *(const float4*)(gamma + k4);
        float4 be4 = *(const float4*)(beta + k4);
#pragma unroll
        for (int i = 0; i < 8; ++i) {
            int row  = r + i * 8;
            int grow = row0 + row;
            float4 a = (grow < n) ? *(const float4*)(x + (size_t)grow * DCH + k4)
                                  : make_float4(0.f, 0.f, 0.f, 0.f);
            float s  = a.x + a.y + a.z + a.w;
            float sq = a.x * a.x + a.y * a.y + a.z * a.z + a.w * a.w;
#pragma unroll
            for (int msk = 16; msk; msk >>= 1) {
                s  += __shfl_xor(s, msk);
                sq += __shfl_xor(sq, msk);
            }
            float mu = s * (1.f / DCH);
            float rs = rsqrtf(sq * (1.f / DCH) - mu * mu + 1e-5f);
            ushort4 u;
            u.x = f2bf(fmaxf((a.x - mu) * rs * g4.x + be4.x, 0.f));
            u.y = f2bf(fmaxf((a.y - mu) * rs * g4.y + be4.y, 0.f));
            u.z = f2bf(fmaxf((a.z - mu) * rs * g4.z + be4.z, 0.f));
            u.w = f2bf(fmaxf((a.w - mu) * rs * g4.w + be4.w, 0.f));
            int byteoff = row * 256 + ((k4 * 2) ^ ((row & 7) << 4));
            *(ushort4*)((char*)As + byteoff) = u;
        }
    }
    __syncthreads();

    int wv = tid >> 6, lane = tid & 63;
    int arow = wv * 16 + (lane & 15);

    // A fragments for this wave's 16 rows, all 4 K-slices (reused over 40 tiles)
    short8v afrag[4];
#pragma unroll
    for (int ks = 0; ks < 4; ++ks) {
        int kbyte = (ks * 64 + (lane >> 4) * 16) ^ ((arow & 7) << 4);
        afrag[ks] = *(const short8v*)((const char*)As + arow * 256 + kbyte);
    }

    int rbase = row0 + wv * 16 + ((lane >> 4) << 2);  // output rows rbase..rbase+3

#pragma unroll 2
    for (int ct = 0; ct < 40; ++ct) {
        const unsigned short* bp = wfrag + ((size_t)(ct * 4) * 64 + lane) * 8;
        short8v b0 = *(const short8v*)(bp);
        short8v b1 = *(const short8v*)(bp + 64 * 8);
        short8v b2 = *(const short8v*)(bp + 128 * 8);
        short8v b3 = *(const short8v*)(bp + 192 * 8);
        f32x4 acc = {0.f, 0.f, 0.f, 0.f};
        acc = __builtin_amdgcn_mfma_f32_16x16x32_bf16(afrag[0], b0, acc, 0, 0, 0);
        acc = __builtin_amdgcn_mfma_f32_16x16x32_bf16(afrag[1], b1, acc, 0, 0, 0);
        acc = __builtin_amdgcn_mfma_f32_16x16x32_bf16(afrag[2], b2, acc, 0, 0, 0);
        acc = __builtin_amdgcn_mfma_f32_16x16x32_bf16(afrag[3], b3, acc, 0, 0, 0);

        int gc = ct * 16 + (lane & 15);
        if (gc < 512) {
            unsigned short* dst; int c; const float* bv;
            if (gc < 256) { dst = xl; c = gc;       bv = bl; }
            else          { dst = xr; c = gc - 256; bv = br; }
            float bb = bv[c];
#pragma unroll
            for (int i = 0; i < 4; ++i) {
                int row = rbase + i;
                if (row < n) dst[(size_t)row * 256 + c] = f2bf(acc[i] + bb);
            }
        } else {
            int c = gc - 512;
            float bb = bias[c];
#pragma unroll
            for (int i = 0; i < 4; ++i) {
                int row = rbase + i;
                if (row < n)
                    out[(size_t)row * DCH + c] = acc[i] + bb + x[(size_t)row * DCH + c];
            }
        }
    }
}

// --------------------------------------------------------------- CSR build
__global__ void zero2(int* __restrict__ a, int* __restrict__ b, int n) {
    int i = blockIdx.x * blockDim.x + threadIdx.x;
    if (i < n) { a[i] = 0; b[i] = 0; }
}

__global__ void hist_dst(const int* __restrict__ dst, int* __restrict__ cnt, int E) {
    for (int i = blockIdx.x * blockDim.x + threadIdx.x; i < E;
         i += gridDim.x * blockDim.x)
        atomicAdd(&cnt[dst[i]], 1);
}

__global__ void scan_block(const int* __restrict__ cnt, int* __restrict__ offs,
                           int* __restrict__ bsum, int n) {
    __shared__ int sm[256];
    int t = threadIdx.x;
    int i = blockIdx.x * 256 + t;
    int v = (i < n) ? cnt[i] : 0;
    sm[t] = v;
    __syncthreads();
#pragma unroll
    for (int d = 1; d < 256; d <<= 1) {
        int add = (t >= d) ? sm[t - d] : 0;
        __syncthreads();
        sm[t] += add;
        __syncthreads();
    }
    if (i < n) offs[i] = sm[t] - v;
    if (t == 255) bsum[blockIdx.x] = sm[t];
}

__global__ void scan_bsum(int* __restrict__ bsum, int nb) {
    if (blockIdx.x == 0 && threadIdx.x == 0) {
        int acc = 0;
        for (int i = 0; i < nb; ++i) { int v = bsum[i]; bsum[i] = acc; acc += v; }
    }
}

__global__ void scan_add(int* __restrict__ offs, const int* __restrict__ bsum,
                         int n, int E) {
    int i = blockIdx.x * 256 + threadIdx.x;
    if (i < n) offs[i] += bsum[blockIdx.x];
    if (i == 0) offs[n] = E;
}

__global__ void fill_csr(const int* __restrict__ src, const int* __restrict__ dst,
                         const int* __restrict__ offs, int* __restrict__ fillc,
                         int* __restrict__ sbuf, int E) {
    for (int i = blockIdx.x * blockDim.x + threadIdx.x; i < E;
         i += gridDim.x * blockDim.x) {
        int t = dst[i];
        int pos = offs[t] + atomicAdd(&fillc[t], 1);
        sbuf[pos] = src[i];
    }
}

// --------------- single-pass fused attention + softmax + aggregation
// One wave per dst node t. After the 5-level shfl_xor butterfly every lane of
// each 32-half holds its head's full logit, so each half-wave keeps a
// lane-local online (m, z) and accumulates acc = acc*sc + w*xl in the same
// pass (defer-max: rescale only when p - m > 8; out = sum(w*xl)/sum(w) is
// m-invariant). Head-mean via shfl_xor(32); non-atomic RMW on out[t].
__launch_bounds__(256)
__global__ void gat_aggregate(const int* __restrict__ offs, const int* __restrict__ sbuf,
                              const __hip_bfloat16* __restrict__ xl,
                              const __hip_bfloat16* __restrict__ xr,
                              const float* __restrict__ att,
                              float* __restrict__ out, int n) {
    int lane = threadIdx.x & 63;
    int wid  = __builtin_amdgcn_readfirstlane((blockIdx.x * blockDim.x + threadIdx.x) >> 6);
    int nw   = (gridDim.x * blockDim.x) >> 6;
    float4 av = *(const float4*)(att + lane * 4);  // flat[256]: lanes 0..31 head0

    for (int t = wid; t < n; t += nw) {
        int beg = offs[t];
        int end = offs[t + 1];
        if (beg == end) continue;
        float4 r4 = ld4(xr + (size_t)t * 256 + lane * 4);

        float m = -INFINITY, z = 0.f;            // per-lane: own head's state
        float4 acc = make_float4(0.f, 0.f, 0.f, 0.f);
        for (int j = beg; j < end; ++j) {
            int s = sbuf[j];
            float4 l4 = ld4(xl + (size_t)s * 256 + lane * 4);
            float vx = l4.x + r4.x; vx = fmaxf(vx, NEG_SLOPE * vx);
            float vy = l4.y + r4.y; vy = fmaxf(vy, NEG_SLOPE * vy);
            float vz = l4.z + r4.z; vz = fmaxf(vz, NEG_SLOPE * vz);
            float vw = l4.w + r4.w; vw = fmaxf(vw, NEG_SLOPE * vw);
            float p = vx * av.x + vy * av.y + vz * av.z + vw * av.w;
#pragma unroll
            for (int msk = 16; msk; msk >>= 1) p += __shfl_xor(p, msk);
            // p now holds this half's head logit on every lane of the half
            float d = p - m;
            if (__any(d > 8.f)) {                // rare: raise the reference max
                float mn = fmaxf(m, p);
                float sc = __expf(m - mn);       // 0 on first edge (m=-inf)
                z *= sc;
                acc.x *= sc; acc.y *= sc; acc.z *= sc; acc.w *= sc;
                m = mn;
                d = p - m;
            }
            float w = __expf(d);                 // bounded by e^8
            z += w;
            acc.x = fmaf(l4.x, w, acc.x);
            acc.y = fmaf(l4.y, w, acc.y);
            acc.z = fmaf(l4.z, w, acc.z);
            acc.w = fmaf(l4.w, w, acc.w);
        }
        float inv = 0.5f / (z + 1e-16f);         // z uniform within each half
        acc.x *= inv; acc.y *= inv; acc.z *= inv; acc.w *= inv;
        // head mean: lane L (<32) += lane L+32 (same channels, head 1)
        acc.x += __shfl_xor(acc.x, 32);
        acc.y += __shfl_xor(acc.y, 32);
        acc.z += __shfl_xor(acc.z, 32);
        acc.w += __shfl_xor(acc.w, 32);
        if (lane < 32) {
            float4* o = (float4*)(out + (size_t)t * DCH + lane * 4);
            float4 cur = *o;
            cur.x += acc.x; cur.y += acc.y; cur.z += acc.z; cur.w += acc.w;
            *o = cur;
        }
    }
}

// --------------------------------------------------------------------- launch
extern "C" void kernel_launch(void* const* d_in, const int* in_sizes, int n_in,
                              void* d_out, int out_size, void* d_ws, size_t ws_size,
                              hipStream_t stream) {
    const float* x     = (const float*)d_in[0];
    const int*   ei    = (const int*)d_in[1];
    const float* gamma = (const float*)d_in[2];
    const float* beta  = (const float*)d_in[3];
    const float* Wl    = (const float*)d_in[4];
    const float* bl    = (const float*)d_in[5];
    const float* Wr    = (const float*)d_in[6];
    const float* br    = (const float*)d_in[7];
    const float* att   = (const float*)d_in[8];
    const float* resW  = (const float*)d_in[9];
    const float* bias  = (const float*)d_in[10];
    float* out = (float*)d_out;

    int n = in_sizes[0] / DCH;
    int E = in_sizes[1] / 2;
    const int* src = ei;
    const int* dstIdx = ei + E;

    char* ws = (char*)d_ws;
    size_t off = 0;
    auto alloc = [&](size_t bytes) -> void* {
        void* p = ws + off;
        off = (off + bytes + 255) & ~(size_t)255;
        return p;
    };

    int nb = (n + 255) / 256;

    unsigned short* xl = (unsigned short*)alloc((size_t)n * 256 * 2);  // 51.2 MB
    unsigned short* xr = (unsigned short*)alloc((size_t)n * 256 * 2);  // 51.2 MB
    unsigned short* wfrag = (unsigned short*)alloc(160 * 64 * 8 * 2);  // 160 KB
    int* cnt   = (int*)alloc((size_t)n * 4);
    int* offs  = (int*)alloc((size_t)(n + 1) * 4);
    int* bsum  = (int*)alloc((size_t)nb * 4);
    int* fillc = (int*)alloc((size_t)n * 4);
    int* sbuf  = (int*)alloc((size_t)E * 4);                           // 6.4 MB

    prep_wfrag<<<40, 256, 0, stream>>>(Wl, Wr, resW, wfrag);
    zero2<<<(n + 255) / 256, 256, 0, stream>>>(cnt, fillc, n);
    hist_dst<<<2048, 256, 0, stream>>>(dstIdx, cnt, E);
    scan_block<<<nb, 256, 0, stream>>>(cnt, offs, bsum, n);
    scan_bsum<<<1, 64, 0, stream>>>(bsum, nb);
    scan_add<<<nb, 256, 0, stream>>>(offs, bsum, n, E);
    fill_csr<<<2048, 256, 0, stream>>>(src, dstIdx, offs, fillc, sbuf, E);

    int nrb = (n + 63) / 64;
    gemm_mfma<<<nrb, 256, 0, stream>>>(x, gamma, beta, wfrag, bl, br, bias,
                                       xl, xr, out, n);
    gat_aggregate<<<2048, 256, 0, stream>>>(offs, sbuf, (const __hip_bfloat16*)xl,
                                            (const __hip_bfloat16*)xr, att, out, n);
}

// Round 6
// 444.881 us; speedup vs baseline: 5.4147x; 1.0476x over previous
//
#include <hip/hip_runtime.h>
#include <hip/hip_bf16.h>
#include <cstdint>
#include <cstddef>

#define DCH 128
#define NHEADS 2
#define NEG_SLOPE 0.2f

typedef __attribute__((ext_vector_type(8))) short short8v;
typedef __attribute__((ext_vector_type(4))) float f32x4;

// ---------------------------------------------------------------- utilities
__device__ __forceinline__ float bf2f(unsigned short u) {
    union { unsigned int i; float f; } v; v.i = ((unsigned int)u) << 16; return v.f;
}
__device__ __forceinline__ unsigned short f2bf(float f) {
    union { float f; unsigned int i; } v; v.f = f;
    unsigned int r = v.i + 0x7fffu + ((v.i >> 16) & 1u);   // RNE
    return (unsigned short)(r >> 16);
}
__device__ __forceinline__ float4 ld4(const __hip_bfloat16* p) {
    ushort4 u = *(const ushort4*)p;
    return make_float4(bf2f(u.x), bf2f(u.y), bf2f(u.z), bf2f(u.w));
}

// ------------------------------------------- weights -> bf16 fragment order
// Fragment f = ct*4+ks (ct in [0,40), ks in [0,4)); lane needs
// B[k = ks*32 + (lane>>4)*8 + j][col = ct*16 + (lane&15)], j=0..7, stored at
// wfrag[(f*64+lane)*8 + j]. Global cols: [0,256)=Wl, [256,512)=Wr, [512,640)=resW.
__global__ void prep_wfrag(const float* __restrict__ Wl, const float* __restrict__ Wr,
                           const float* __restrict__ resW, unsigned short* __restrict__ wfrag) {
    int gid  = blockIdx.x * 256 + threadIdx.x;   // 10240 threads
    int lane = gid & 63;
    int f    = gid >> 6;                          // 0..159
    int ks   = f & 3;
    int ct   = f >> 2;
    int col  = ct * 16 + (lane & 15);
    int k0   = ks * 32 + (lane >> 4) * 8;
    const float* W; int ldB, c;
    if (col < 256)      { W = Wl;   ldB = 256; c = col; }
    else if (col < 512) { W = Wr;   ldB = 256; c = col - 256; }
    else                { W = resW; ldB = 128; c = col - 512; }
    unsigned short tmp[8];
#pragma unroll
    for (int j = 0; j < 8; ++j) tmp[j] = f2bf(W[(size_t)(k0 + j) * ldB + c]);
    ushort4* dst = (ushort4*)(wfrag + (size_t)gid * 8);
    dst[0] = make_ushort4(tmp[0], tmp[1], tmp[2], tmp[3]);
    dst[1] = make_ushort4(tmp[4], tmp[5], tmp[6], tmp[7]);
}

// ---------------- fused LN+ReLU + MFMA GEMM (128 rows x 640 cols per block)
// A = relu(LN(x)) staged bf16 in LDS, XOR-swizzled (byte ^= (row&7)<<4).
// 4 waves; wave w owns rows [w*32, w*32+32) as two 16-row groups -> each
// B-fragment load feeds 2 MFMA chains (2x reuse vs R5). 8 mfma per ct.
__launch_bounds__(256)
__global__ void gemm_mfma(const float* __restrict__ x,
                          const float* __restrict__ gamma, const float* __restrict__ beta,
                          const unsigned short* __restrict__ wfrag,
                          const float* __restrict__ bl, const float* __restrict__ br,
                          const float* __restrict__ bias,
                          unsigned short* __restrict__ xl, unsigned short* __restrict__ xr,
                          float* __restrict__ out, int n) {
    __shared__ __align__(16) unsigned short As[128 * 128];  // 32 KB, swizzled
    int row0 = blockIdx.x * 128;
    int tid  = threadIdx.x;

    // ---- stage A with fused LayerNorm+ReLU (32 threads per row, 16 passes)
    {
        int r  = tid >> 5;            // 0..7
        int k4 = (tid & 31) * 4;      // 0,4,...,124
        float4 g4  = *(const float4*)(gamma + k4);
        float4 be4 = *(const float4*)(beta + k4);
#pragma unroll
        for (int i = 0; i < 16; ++i) {
            int row  = r + i * 8;
            int grow = row0 + row;
            float4 a = (grow < n) ? *(const float4*)(x + (size_t)grow * DCH + k4)
                                  : make_float4(0.f, 0.f, 0.f, 0.f);
            float s  = a.x + a.y + a.z + a.w;
            float sq = a.x * a.x + a.y * a.y + a.z * a.z + a.w * a.w;
#pragma unroll
            for (int msk = 16; msk; msk >>= 1) {
                s  += __shfl_xor(s, msk);
                sq += __shfl_xor(sq, msk);
            }
            float mu = s * (1.f / DCH);
            float rs = rsqrtf(sq * (1.f / DCH) - mu * mu + 1e-5f);
            ushort4 u;
            u.x = f2bf(fmaxf((a.x - mu) * rs * g4.x + be4.x, 0.f));
            u.y = f2bf(fmaxf((a.y - mu) * rs * g4.y + be4.y, 0.f));
            u.z = f2bf(fmaxf((a.z - mu) * rs * g4.z + be4.z, 0.f));
            u.w = f2bf(fmaxf((a.w - mu) * rs * g4.w + be4.w, 0.f));
            int byteoff = row * 256 + ((k4 * 2) ^ ((row & 7) << 4));
            *(ushort4*)((char*)As + byteoff) = u;
        }
    }
    __syncthreads();

    int wv = tid >> 6, lane = tid & 63;

    // A fragments: 2 row-groups x 4 K-slices, reused across 40 col-tiles
    short8v afrag[2][4];
#pragma unroll
    for (int g = 0; g < 2; ++g) {
        int arow = wv * 32 + g * 16 + (lane & 15);
#pragma unroll
        for (int ks = 0; ks < 4; ++ks) {
            int kbyte = (ks * 64 + (lane >> 4) * 16) ^ ((arow & 7) << 4);
            afrag[g][ks] = *(const short8v*)((const char*)As + arow * 256 + kbyte);
        }
    }

    int rb0 = row0 + wv * 32 + ((lane >> 4) << 2);  // group0 rows rb0..rb0+3
    int gcl = lane & 15;

#pragma unroll 2
    for (int ct = 0; ct < 40; ++ct) {
        const unsigned short* bp = wfrag + ((size_t)(ct * 4) * 64 + lane) * 8;
        short8v b0 = *(const short8v*)(bp);
        short8v b1 = *(const short8v*)(bp + 64 * 8);
        short8v b2 = *(const short8v*)(bp + 128 * 8);
        short8v b3 = *(const short8v*)(bp + 192 * 8);
        f32x4 acc0 = {0.f, 0.f, 0.f, 0.f};
        f32x4 acc1 = {0.f, 0.f, 0.f, 0.f};
        acc0 = __builtin_amdgcn_mfma_f32_16x16x32_bf16(afrag[0][0], b0, acc0, 0, 0, 0);
        acc1 = __builtin_amdgcn_mfma_f32_16x16x32_bf16(afrag[1][0], b0, acc1, 0, 0, 0);
        acc0 = __builtin_amdgcn_mfma_f32_16x16x32_bf16(afrag[0][1], b1, acc0, 0, 0, 0);
        acc1 = __builtin_amdgcn_mfma_f32_16x16x32_bf16(afrag[1][1], b1, acc1, 0, 0, 0);
        acc0 = __builtin_amdgcn_mfma_f32_16x16x32_bf16(afrag[0][2], b2, acc0, 0, 0, 0);
        acc1 = __builtin_amdgcn_mfma_f32_16x16x32_bf16(afrag[1][2], b2, acc1, 0, 0, 0);
        acc0 = __builtin_amdgcn_mfma_f32_16x16x32_bf16(afrag[0][3], b3, acc0, 0, 0, 0);
        acc1 = __builtin_amdgcn_mfma_f32_16x16x32_bf16(afrag[1][3], b3, acc1, 0, 0, 0);

        int gc = ct * 16 + gcl;
#pragma unroll
        for (int g = 0; g < 2; ++g) {
            const f32x4& acc = g ? acc1 : acc0;
            int rbase = rb0 + g * 16;
            if (gc < 512) {
                unsigned short* dst; int c; const float* bv;
                if (gc < 256) { dst = xl; c = gc;       bv = bl; }
                else          { dst = xr; c = gc - 256; bv = br; }
                float bb = bv[c];
#pragma unroll
                for (int i = 0; i < 4; ++i) {
                    int row = rbase + i;
                    if (row < n) dst[(size_t)row * 256 + c] = f2bf(acc[i] + bb);
                }
            } else {
                int c = gc - 512;
                float bb = bias[c];
#pragma unroll
                for (int i = 0; i < 4; ++i) {
                    int row = rbase + i;
                    if (row < n)
                        out[(size_t)row * DCH + c] = acc[i] + bb + x[(size_t)row * DCH + c];
                }
            }
        }
    }
}

// --------------------------------------------------------------- CSR build
__global__ void zero1(int* __restrict__ a, int n) {
    int i = blockIdx.x * blockDim.x + threadIdx.x;
    if (i < n) a[i] = 0;
}

__global__ void hist_dst(const int* __restrict__ dst, int* __restrict__ cnt, int E) {
    for (int i = blockIdx.x * blockDim.x + threadIdx.x; i < E;
         i += gridDim.x * blockDim.x)
        atomicAdd(&cnt[dst[i]], 1);
}

__global__ void scan_block(const int* __restrict__ cnt, int* __restrict__ offs,
                           int* __restrict__ bsum, int n) {
    __shared__ int sm[256];
    int t = threadIdx.x;
    int i = blockIdx.x * 256 + t;
    int v = (i < n) ? cnt[i] : 0;
    sm[t] = v;
    __syncthreads();
#pragma unroll
    for (int d = 1; d < 256; d <<= 1) {
        int add = (t >= d) ? sm[t - d] : 0;
        __syncthreads();
        sm[t] += add;
        __syncthreads();
    }
    if (i < n) offs[i] = sm[t] - v;
    if (t == 255) bsum[blockIdx.x] = sm[t];
}

// parallel exclusive scan of block sums (single block; nb <= 512 fast path)
__global__ void scan_bsum_par(int* __restrict__ bsum, int nb) {
    __shared__ int sm[512];
    int t = threadIdx.x;
    if (nb <= 512) {
        int v = (t < nb) ? bsum[t] : 0;
        sm[t] = v;
        __syncthreads();
#pragma unroll
        for (int d = 1; d < 512; d <<= 1) {
            int add = (t >= d) ? sm[t - d] : 0;
            __syncthreads();
            sm[t] += add;
            __syncthreads();
        }
        if (t < nb) bsum[t] = sm[t] - v;
    } else if (t == 0) {                       // generic fallback
        int acc = 0;
        for (int i = 0; i < nb; ++i) { int v = bsum[i]; bsum[i] = acc; acc += v; }
    }
}

// add block offsets; also pre-init fillc = offs so fill_csr skips one read
__global__ void scan_add(int* __restrict__ offs, int* __restrict__ fillc,
                         const int* __restrict__ bsum, int n, int E) {
    int i = blockIdx.x * 256 + threadIdx.x;
    if (i < n) {
        int v = offs[i] + bsum[blockIdx.x];
        offs[i]  = v;
        fillc[i] = v;
    }
    if (i == 0) offs[n] = E;
}

__global__ void fill_csr(const int* __restrict__ src, const int* __restrict__ dst,
                         int* __restrict__ fillc, int* __restrict__ sbuf, int E) {
    for (int i = blockIdx.x * blockDim.x + threadIdx.x; i < E;
         i += gridDim.x * blockDim.x) {
        int pos = atomicAdd(&fillc[dst[i]], 1);
        sbuf[pos] = src[i];
    }
}

// --------------- single-pass fused attention + softmax + aggregation
// One wave per dst node t; lane-local per-head online (m,z); defer-max
// (rescale only when p-m > 8; out = sum(w*xl)/sum(w) is m-invariant).
// 2-way edge unroll: two gathers in flight, butterflies interleaved.
__launch_bounds__(256)
__global__ void gat_aggregate(const int* __restrict__ offs, const int* __restrict__ sbuf,
                              const __hip_bfloat16* __restrict__ xl,
                              const __hip_bfloat16* __restrict__ xr,
                              const float* __restrict__ att,
                              float* __restrict__ out, int n) {
    int lane = threadIdx.x & 63;
    int wid  = __builtin_amdgcn_readfirstlane((blockIdx.x * blockDim.x + threadIdx.x) >> 6);
    int nw   = (gridDim.x * blockDim.x) >> 6;
    float4 av = *(const float4*)(att + lane * 4);  // flat[256]: lanes 0..31 head0

    for (int t = wid; t < n; t += nw) {
        int beg = offs[t];
        int end = offs[t + 1];
        if (beg == end) continue;
        float4 r4 = ld4(xr + (size_t)t * 256 + lane * 4);

        float m = -INFINITY, z = 0.f;            // per-lane: own head's state
        float4 acc = make_float4(0.f, 0.f, 0.f, 0.f);
        int j = beg;
        for (; j + 2 <= end; j += 2) {
            int s0 = sbuf[j], s1 = sbuf[j + 1];
            float4 l0 = ld4(xl + (size_t)s0 * 256 + lane * 4);
            float4 l1 = ld4(xl + (size_t)s1 * 256 + lane * 4);
            float ax = l0.x + r4.x; ax = fmaxf(ax, NEG_SLOPE * ax);
            float ay = l0.y + r4.y; ay = fmaxf(ay, NEG_SLOPE * ay);
            float az = l0.z + r4.z; az = fmaxf(az, NEG_SLOPE * az);
            float aw = l0.w + r4.w; aw = fmaxf(aw, NEG_SLOPE * aw);
            float p0 = ax * av.x + ay * av.y + az * av.z + aw * av.w;
            float bx = l1.x + r4.x; bx = fmaxf(bx, NEG_SLOPE * bx);
            float by = l1.y + r4.y; by = fmaxf(by, NEG_SLOPE * by);
            float bz = l1.z + r4.z; bz = fmaxf(bz, NEG_SLOPE * bz);
            float bw = l1.w + r4.w; bw = fmaxf(bw, NEG_SLOPE * bw);
            float p1 = bx * av.x + by * av.y + bz * av.z + bw * av.w;
#pragma unroll
            for (int msk = 16; msk; msk >>= 1) {
                p0 += __shfl_xor(p0, msk);
                p1 += __shfl_xor(p1, msk);
            }
            float pm = fmaxf(p0, p1);
            if (__any(pm - m > 8.f)) {
                float mn = fmaxf(m, pm);
                float sc = __expf(m - mn);       // 0 on first edge (m=-inf)
                z *= sc;
                acc.x *= sc; acc.y *= sc; acc.z *= sc; acc.w *= sc;
                m = mn;
            }
            float w0 = __expf(p0 - m);
            float w1 = __expf(p1 - m);
            z += w0 + w1;
            acc.x = fmaf(l0.x, w0, acc.x); acc.x = fmaf(l1.x, w1, acc.x);
            acc.y = fmaf(l0.y, w0, acc.y); acc.y = fmaf(l1.y, w1, acc.y);
            acc.z = fmaf(l0.z, w0, acc.z); acc.z = fmaf(l1.z, w1, acc.z);
            acc.w = fmaf(l0.w, w0, acc.w); acc.w = fmaf(l1.w, w1, acc.w);
        }
        if (j < end) {                           // tail edge
            int s = sbuf[j];
            float4 l4 = ld4(xl + (size_t)s * 256 + lane * 4);
            float vx = l4.x + r4.x; vx = fmaxf(vx, NEG_SLOPE * vx);
            float vy = l4.y + r4.y; vy = fmaxf(vy, NEG_SLOPE * vy);
            float vz = l4.z + r4.z; vz = fmaxf(vz, NEG_SLOPE * vz);
            float vw = l4.w + r4.w; vw = fmaxf(vw, NEG_SLOPE * vw);
            float p = vx * av.x + vy * av.y + vz * av.z + vw * av.w;
#pragma unroll
            for (int msk = 16; msk; msk >>= 1) p += __shfl_xor(p, msk);
            if (__any(p - m > 8.f)) {
                float mn = fmaxf(m, p);
                float sc = __expf(m - mn);
                z *= sc;
                acc.x *= sc; acc.y *= sc; acc.z *= sc; acc.w *= sc;
                m = mn;
            }
            float w = __expf(p - m);
            z += w;
            acc.x = fmaf(l4.x, w, acc.x);
            acc.y = fmaf(l4.y, w, acc.y);
            acc.z = fmaf(l4.z, w, acc.z);
            acc.w = fmaf(l4.w, w, acc.w);
        }
        float inv = 0.5f / (z + 1e-16f);         // z uniform within each half
        acc.x *= inv; acc.y *= inv; acc.z *= inv; acc.w *= inv;
        // head mean: lane L (<32) += lane L+32 (same channels, head 1)
        acc.x += __shfl_xor(acc.x, 32);
        acc.y += __shfl_xor(acc.y, 32);
        acc.z += __shfl_xor(acc.z, 32);
        acc.w += __shfl_xor(acc.w, 32);
        if (lane < 32) {
            float4* o = (float4*)(out + (size_t)t * DCH + lane * 4);
            float4 cur = *o;
            cur.x += acc.x; cur.y += acc.y; cur.z += acc.z; cur.w += acc.w;
            *o = cur;
        }
    }
}

// --------------------------------------------------------------------- launch
extern "C" void kernel_launch(void* const* d_in, const int* in_sizes, int n_in,
                              void* d_out, int out_size, void* d_ws, size_t ws_size,
                              hipStream_t stream) {
    const float* x     = (const float*)d_in[0];
    const int*   ei    = (const int*)d_in[1];
    const float* gamma = (const float*)d_in[2];
    const float* beta  = (const float*)d_in[3];
    const float* Wl    = (const float*)d_in[4];
    const float* bl    = (const float*)d_in[5];
    const float* Wr    = (const float*)d_in[6];
    const float* br    = (const float*)d_in[7];
    const float* att   = (const float*)d_in[8];
    const float* resW  = (const float*)d_in[9];
    const float* bias  = (const float*)d_in[10];
    float* out = (float*)d_out;

    int n = in_sizes[0] / DCH;
    int E = in_sizes[1] / 2;
    const int* src = ei;
    const int* dstIdx = ei + E;

    char* ws = (char*)d_ws;
    size_t off = 0;
    auto alloc = [&](size_t bytes) -> void* {
        void* p = ws + off;
        off = (off + bytes + 255) & ~(size_t)255;
        return p;
    };

    int nb = (n + 255) / 256;

    unsigned short* xl = (unsigned short*)alloc((size_t)n * 256 * 2);  // 51.2 MB
    unsigned short* xr = (unsigned short*)alloc((size_t)n * 256 * 2);  // 51.2 MB
    unsigned short* wfrag = (unsigned short*)alloc(160 * 64 * 8 * 2);  // 160 KB
    int* cnt   = (int*)alloc((size_t)n * 4);
    int* offs  = (int*)alloc((size_t)(n + 1) * 4);
    int* bsum  = (int*)alloc((size_t)nb * 4);
    int* fillc = (int*)alloc((size_t)n * 4);
    int* sbuf  = (int*)alloc((size_t)E * 4);                           // 6.4 MB

    prep_wfrag<<<40, 256, 0, stream>>>(Wl, Wr, resW, wfrag);
    zero1<<<(n + 255) / 256, 256, 0, stream>>>(cnt, n);
    hist_dst<<<2048, 256, 0, stream>>>(dstIdx, cnt, E);
    scan_block<<<nb, 256, 0, stream>>>(cnt, offs, bsum, n);
    scan_bsum_par<<<1, 512, 0, stream>>>(bsum, nb);
    scan_add<<<nb, 256, 0, stream>>>(offs, fillc, bsum, n, E);
    fill_csr<<<2048, 256, 0, stream>>>(src, dstIdx, fillc, sbuf, E);

    int nrb = (n + 127) / 128;
    gemm_mfma<<<nrb, 256, 0, stream>>>(x, gamma, beta, wfrag, bl, br, bias,
                                       xl, xr, out, n);
    gat_aggregate<<<2048, 256, 0, stream>>>(offs, sbuf, (const __hip_bfloat16*)xl,
                                            (const __hip_bfloat16*)xr, att, out, n);
}

// Round 7
// 441.509 us; speedup vs baseline: 5.4560x; 1.0076x over previous
//
#include <hip/hip_runtime.h>
#include <hip/hip_bf16.h>
#include <cstdint>
#include <cstddef>

#define DCH 128
#define NHEADS 2
#define NEG_SLOPE 0.2f

typedef __attribute__((ext_vector_type(8))) short short8v;
typedef __attribute__((ext_vector_type(4))) float f32x4;
typedef _Float16 h2 __attribute__((ext_vector_type(2)));
typedef _Float16 h4 __attribute__((ext_vector_type(4)));

// ---------------------------------------------------------------- utilities
__device__ __forceinline__ unsigned short f2bf(float f) {
    union { float f; unsigned int i; } v; v.f = f;
    unsigned int r = v.i + 0x7fffu + ((v.i >> 16) & 1u);   // RNE
    return (unsigned short)(r >> 16);
}
__device__ __forceinline__ unsigned short f2h_bits(float f) {
    _Float16 h = (_Float16)f;
    union { _Float16 h; unsigned short u; } v; v.h = h; return v.u;
}

__device__ __forceinline__ h2 lrelu2(h2 v, h2 ns) {
    h2 f = v * ns;
#if __has_builtin(__builtin_elementwise_max)
    return __builtin_elementwise_max(v, f);
#else
    h2 r; r[0] = v[0] > f[0] ? v[0] : f[0]; r[1] = v[1] > f[1] ? v[1] : f[1];
    return r;
#endif
}
__device__ __forceinline__ float dot4h(h2 a0, h2 a1, h2 b0, h2 b1) {
#if __has_builtin(__builtin_amdgcn_fdot2)
    return __builtin_amdgcn_fdot2(a0, b0, __builtin_amdgcn_fdot2(a1, b1, 0.f, false), false);
#else
    return (float)a0[0]*(float)b0[0] + (float)a0[1]*(float)b0[1]
         + (float)a1[0]*(float)b1[0] + (float)a1[1]*(float)b1[1];
#endif
}

// ------------------------------- merged: weights->bf16 fragments + zero cnt
// blocks [0,40): wfrag; blocks [40, ...): cnt[i] = 0.
// Fragment f = ct*4+ks; lane needs B[k = ks*32 + (lane>>4)*8 + j][col = ct*16
// + (lane&15)], stored at wfrag[(f*64+lane)*8 + j].
__global__ void prep_and_zero(const float* __restrict__ Wl, const float* __restrict__ Wr,
                              const float* __restrict__ resW,
                              unsigned short* __restrict__ wfrag,
                              int* __restrict__ cnt, int n) {
    if (blockIdx.x >= 40) {
        int i = (blockIdx.x - 40) * 256 + threadIdx.x;
        if (i < n) cnt[i] = 0;
        return;
    }
    int gid  = blockIdx.x * 256 + threadIdx.x;   // 10240 threads
    int lane = gid & 63;
    int f    = gid >> 6;                          // 0..159
    int ks   = f & 3;
    int ct   = f >> 2;
    int col  = ct * 16 + (lane & 15);
    int k0   = ks * 32 + (lane >> 4) * 8;
    const float* W; int ldB, c;
    if (col < 256)      { W = Wl;   ldB = 256; c = col; }
    else if (col < 512) { W = Wr;   ldB = 256; c = col - 256; }
    else                { W = resW; ldB = 128; c = col - 512; }
    unsigned short tmp[8];
#pragma unroll
    for (int j = 0; j < 8; ++j) tmp[j] = f2bf(W[(size_t)(k0 + j) * ldB + c]);
    ushort4* dst = (ushort4*)(wfrag + (size_t)gid * 8);
    dst[0] = make_ushort4(tmp[0], tmp[1], tmp[2], tmp[3]);
    dst[1] = make_ushort4(tmp[4], tmp[5], tmp[6], tmp[7]);
}

// ---------------- fused LN+ReLU + MFMA GEMM (128 rows x 640 cols per block)
// A = relu(LN(x)) staged bf16 in LDS, XOR-swizzled (byte ^= (row&7)<<4).
// 4 waves; wave w owns rows [w*32, w*32+32) as two 16-row groups; 8 mfma/ct.
// cols 0..255 -> xl (f16), 256..511 -> xr (f16), 512..639 -> out=x+h@resW+bias.
__launch_bounds__(256)
__global__ void gemm_mfma(const float* __restrict__ x,
                          const float* __restrict__ gamma, const float* __restrict__ beta,
                          const unsigned short* __restrict__ wfrag,
                          const float* __restrict__ bl, const float* __restrict__ br,
                          const float* __restrict__ bias,
                          unsigned short* __restrict__ xl, unsigned short* __restrict__ xr,
                          float* __restrict__ out, int n) {
    __shared__ __align__(16) unsigned short As[128 * 128];  // 32 KB, swizzled
    int row0 = blockIdx.x * 128;
    int tid  = threadIdx.x;

    // ---- stage A with fused LayerNorm+ReLU (32 threads per row, 16 passes)
    {
        int r  = tid >> 5;            // 0..7
        int k4 = (tid & 31) * 4;      // 0,4,...,124
        float4 g4  = *(const float4*)(gamma + k4);
        float4 be4 = *(const float4*)(beta + k4);
#pragma unroll
        for (int i = 0; i < 16; ++i) {
            int row  = r + i * 8;
            int grow = row0 + row;
            float4 a = (grow < n) ? *(const float4*)(x + (size_t)grow * DCH + k4)
                                  : make_float4(0.f, 0.f, 0.f, 0.f);
            float s  = a.x + a.y + a.z + a.w;
            float sq = a.x * a.x + a.y * a.y + a.z * a.z + a.w * a.w;
#pragma unroll
            for (int msk = 16; msk; msk >>= 1) {
                s  += __shfl_xor(s, msk);
                sq += __shfl_xor(sq, msk);
            }
            float mu = s * (1.f / DCH);
            float rs = rsqrtf(sq * (1.f / DCH) - mu * mu + 1e-5f);
            ushort4 u;
            u.x = f2bf(fmaxf((a.x - mu) * rs * g4.x + be4.x, 0.f));
            u.y = f2bf(fmaxf((a.y - mu) * rs * g4.y + be4.y, 0.f));
            u.z = f2bf(fmaxf((a.z - mu) * rs * g4.z + be4.z, 0.f));
            u.w = f2bf(fmaxf((a.w - mu) * rs * g4.w + be4.w, 0.f));
            int byteoff = row * 256 + ((k4 * 2) ^ ((row & 7) << 4));
            *(ushort4*)((char*)As + byteoff) = u;
        }
    }
    __syncthreads();

    int wv = tid >> 6, lane = tid & 63;

    // A fragments: 2 row-groups x 4 K-slices, reused across 40 col-tiles
    short8v afrag[2][4];
#pragma unroll
    for (int g = 0; g < 2; ++g) {
        int arow = wv * 32 + g * 16 + (lane & 15);
#pragma unroll
        for (int ks = 0; ks < 4; ++ks) {
            int kbyte = (ks * 64 + (lane >> 4) * 16) ^ ((arow & 7) << 4);
            afrag[g][ks] = *(const short8v*)((const char*)As + arow * 256 + kbyte);
        }
    }

    int rb0 = row0 + wv * 32 + ((lane >> 4) << 2);  // group0 rows rb0..rb0+3
    int gcl = lane & 15;

#pragma unroll 2
    for (int ct = 0; ct < 40; ++ct) {
        const unsigned short* bp = wfrag + ((size_t)(ct * 4) * 64 + lane) * 8;
        short8v b0 = *(const short8v*)(bp);
        short8v b1 = *(const short8v*)(bp + 64 * 8);
        short8v b2 = *(const short8v*)(bp + 128 * 8);
        short8v b3 = *(const short8v*)(bp + 192 * 8);
        f32x4 acc0 = {0.f, 0.f, 0.f, 0.f};
        f32x4 acc1 = {0.f, 0.f, 0.f, 0.f};
        acc0 = __builtin_amdgcn_mfma_f32_16x16x32_bf16(afrag[0][0], b0, acc0, 0, 0, 0);
        acc1 = __builtin_amdgcn_mfma_f32_16x16x32_bf16(afrag[1][0], b0, acc1, 0, 0, 0);
        acc0 = __builtin_amdgcn_mfma_f32_16x16x32_bf16(afrag[0][1], b1, acc0, 0, 0, 0);
        acc1 = __builtin_amdgcn_mfma_f32_16x16x32_bf16(afrag[1][1], b1, acc1, 0, 0, 0);
        acc0 = __builtin_amdgcn_mfma_f32_16x16x32_bf16(afrag[0][2], b2, acc0, 0, 0, 0);
        acc1 = __builtin_amdgcn_mfma_f32_16x16x32_bf16(afrag[1][2], b2, acc1, 0, 0, 0);
        acc0 = __builtin_amdgcn_mfma_f32_16x16x32_bf16(afrag[0][3], b3, acc0, 0, 0, 0);
        acc1 = __builtin_amdgcn_mfma_f32_16x16x32_bf16(afrag[1][3], b3, acc1, 0, 0, 0);

        int gc = ct * 16 + gcl;
#pragma unroll
        for (int g = 0; g < 2; ++g) {
            const f32x4& acc = g ? acc1 : acc0;
            int rbase = rb0 + g * 16;
            if (gc < 512) {
                unsigned short* dst; int c; const float* bv;
                if (gc < 256) { dst = xl; c = gc;       bv = bl; }
                else          { dst = xr; c = gc - 256; bv = br; }
                float bb = bv[c];
#pragma unroll
                for (int i = 0; i < 4; ++i) {
                    int row = rbase + i;
                    if (row < n) dst[(size_t)row * 256 + c] = f2h_bits(acc[i] + bb);
                }
            } else {
                int c = gc - 512;
                float bb = bias[c];
#pragma unroll
                for (int i = 0; i < 4; ++i) {
                    int row = rbase + i;
                    if (row < n)
                        out[(size_t)row * DCH + c] = acc[i] + bb + x[(size_t)row * DCH + c];
                }
            }
        }
    }
}

// --------------------------------------------------------------- CSR build
__global__ void hist_dst(const int* __restrict__ dst, int* __restrict__ cnt, int E) {
    for (int i = blockIdx.x * blockDim.x + threadIdx.x; i < E;
         i += gridDim.x * blockDim.x)
        atomicAdd(&cnt[dst[i]], 1);
}

__global__ void scan_block(const int* __restrict__ cnt, int* __restrict__ offs,
                           int* __restrict__ bsum, int n) {
    __shared__ int sm[256];
    int t = threadIdx.x;
    int i = blockIdx.x * 256 + t;
    int v = (i < n) ? cnt[i] : 0;
    sm[t] = v;
    __syncthreads();
#pragma unroll
    for (int d = 1; d < 256; d <<= 1) {
        int add = (t >= d) ? sm[t - d] : 0;
        __syncthreads();
        sm[t] += add;
        __syncthreads();
    }
    if (i < n) offs[i] = sm[t] - v;
    if (t == 255) bsum[blockIdx.x] = sm[t];
}

// parallel exclusive scan of block sums (single block; nb <= 512 fast path)
__global__ void scan_bsum_par(int* __restrict__ bsum, int nb) {
    __shared__ int sm[512];
    int t = threadIdx.x;
    if (nb <= 512) {
        int v = (t < nb) ? bsum[t] : 0;
        sm[t] = v;
        __syncthreads();
#pragma unroll
        for (int d = 1; d < 512; d <<= 1) {
            int add = (t >= d) ? sm[t - d] : 0;
            __syncthreads();
            sm[t] += add;
            __syncthreads();
        }
        if (t < nb) bsum[t] = sm[t] - v;
    } else if (t == 0) {
        int acc = 0;
        for (int i = 0; i < nb; ++i) { int v = bsum[i]; bsum[i] = acc; acc += v; }
    }
}

// add block offsets; also pre-init fillc = offs so fill_csr skips one read
__global__ void scan_add(int* __restrict__ offs, int* __restrict__ fillc,
                         const int* __restrict__ bsum, int n, int E) {
    int i = blockIdx.x * 256 + threadIdx.x;
    if (i < n) {
        int v = offs[i] + bsum[blockIdx.x];
        offs[i]  = v;
        fillc[i] = v;
    }
    if (i == 0) offs[n] = E;
}

__global__ void fill_csr(const int* __restrict__ src, const int* __restrict__ dst,
                         int* __restrict__ fillc, int* __restrict__ sbuf, int E) {
    for (int i = blockIdx.x * blockDim.x + threadIdx.x; i < E;
         i += gridDim.x * blockDim.x) {
        int pos = atomicAdd(&fillc[dst[i]], 1);
        sbuf[pos] = src[i];
    }
}

// --------------- single-pass fused attention + softmax + aggregation (f16)
// One wave per dst node t. Packed-f16 leaky-relu (pk_add/pk_mul/pk_max) and
// v_dot2_f32_f16 attention dot; att pre-scaled by log2(e) so the softmax
// uses raw v_exp_f32 (exp2). Lane-local per-head online (m,z) with defer-max
// (rescale only when p-m > 11.5 in log2 domain); 4-way edge unroll.
__launch_bounds__(256)
__global__ void gat_aggregate(const int* __restrict__ offs, const int* __restrict__ sbuf,
                              const unsigned short* __restrict__ xl_,
                              const unsigned short* __restrict__ xr_,
                              const float* __restrict__ att,
                              float* __restrict__ out, int n) {
    const _Float16* xl = (const _Float16*)xl_;
    const _Float16* xr = (const _Float16*)xr_;
    int lane = threadIdx.x & 63;
    int wid  = __builtin_amdgcn_readfirstlane((blockIdx.x * blockDim.x + threadIdx.x) >> 6);
    int nw   = (gridDim.x * blockDim.x) >> 6;

    const float LOG2E = 1.4426950408889634f;
    float4 af = *(const float4*)(att + lane * 4);   // flat[256]: lanes 0..31 head0
    h2 av0 = {(_Float16)(af.x * LOG2E), (_Float16)(af.y * LOG2E)};
    h2 av1 = {(_Float16)(af.z * LOG2E), (_Float16)(af.w * LOG2E)};
    h2 ns  = {(_Float16)NEG_SLOPE, (_Float16)NEG_SLOPE};

    for (int t = wid; t < n; t += nw) {
        int beg = offs[t];
        int end = offs[t + 1];
        if (beg == end) continue;
        h4 r4 = *(const h4*)(xr + (size_t)t * 256 + lane * 4);
        h2 r0 = __builtin_shufflevector(r4, r4, 0, 1);
        h2 r1 = __builtin_shufflevector(r4, r4, 2, 3);

        float m = -INFINITY, z = 0.f;            // per-lane: own head's state
        float4 acc = make_float4(0.f, 0.f, 0.f, 0.f);
        int j = beg;
        for (; j + 4 <= end; j += 4) {
            int s0 = sbuf[j], s1 = sbuf[j + 1], s2 = sbuf[j + 2], s3 = sbuf[j + 3];
            h4 l0 = *(const h4*)(xl + (size_t)s0 * 256 + lane * 4);
            h4 l1 = *(const h4*)(xl + (size_t)s1 * 256 + lane * 4);
            h4 l2 = *(const h4*)(xl + (size_t)s2 * 256 + lane * 4);
            h4 l3 = *(const h4*)(xl + (size_t)s3 * 256 + lane * 4);
            float p0 = dot4h(lrelu2(__builtin_shufflevector(l0, l0, 0, 1) + r0, ns),
                             lrelu2(__builtin_shufflevector(l0, l0, 2, 3) + r1, ns), av0, av1);
            float p1 = dot4h(lrelu2(__builtin_shufflevector(l1, l1, 0, 1) + r0, ns),
                             lrelu2(__builtin_shufflevector(l1, l1, 2, 3) + r1, ns), av0, av1);
            float p2 = dot4h(lrelu2(__builtin_shufflevector(l2, l2, 0, 1) + r0, ns),
                             lrelu2(__builtin_shufflevector(l2, l2, 2, 3) + r1, ns), av0, av1);
            float p3 = dot4h(lrelu2(__builtin_shufflevector(l3, l3, 0, 1) + r0, ns),
                             lrelu2(__builtin_shufflevector(l3, l3, 2, 3) + r1, ns), av0, av1);
#pragma unroll
            for (int msk = 16; msk; msk >>= 1) {
                p0 += __shfl_xor(p0, msk);
                p1 += __shfl_xor(p1, msk);
                p2 += __shfl_xor(p2, msk);
                p3 += __shfl_xor(p3, msk);
            }
            float pm = fmaxf(fmaxf(p0, p1), fmaxf(p2, p3));
            if (__any(pm - m > 11.5f)) {         // 8/ln2: raise reference max
                float mn = fmaxf(m, pm);
                float sc = __builtin_amdgcn_exp2f(m - mn);   // 0 on first group
                z *= sc;
                acc.x *= sc; acc.y *= sc; acc.z *= sc; acc.w *= sc;
                m = mn;
            }
            float w0 = __builtin_amdgcn_exp2f(p0 - m);
            float w1 = __builtin_amdgcn_exp2f(p1 - m);
            float w2 = __builtin_amdgcn_exp2f(p2 - m);
            float w3 = __builtin_amdgcn_exp2f(p3 - m);
            z += (w0 + w1) + (w2 + w3);
            acc.x = fmaf((float)l0[0], w0, acc.x); acc.y = fmaf((float)l0[1], w0, acc.y);
            acc.z = fmaf((float)l0[2], w0, acc.z); acc.w = fmaf((float)l0[3], w0, acc.w);
            acc.x = fmaf((float)l1[0], w1, acc.x); acc.y = fmaf((float)l1[1], w1, acc.y);
            acc.z = fmaf((float)l1[2], w1, acc.z); acc.w = fmaf((float)l1[3], w1, acc.w);
            acc.x = fmaf((float)l2[0], w2, acc.x); acc.y = fmaf((float)l2[1], w2, acc.y);
            acc.z = fmaf((float)l2[2], w2, acc.z); acc.w = fmaf((float)l2[3], w2, acc.w);
            acc.x = fmaf((float)l3[0], w3, acc.x); acc.y = fmaf((float)l3[1], w3, acc.y);
            acc.z = fmaf((float)l3[2], w3, acc.z); acc.w = fmaf((float)l3[3], w3, acc.w);
        }
        for (; j < end; ++j) {                   // tail (0..3 edges)
            int s = sbuf[j];
            h4 l0 = *(const h4*)(xl + (size_t)s * 256 + lane * 4);
            float p = dot4h(lrelu2(__builtin_shufflevector(l0, l0, 0, 1) + r0, ns),
                            lrelu2(__builtin_shufflevector(l0, l0, 2, 3) + r1, ns), av0, av1);
#pragma unroll
            for (int msk = 16; msk; msk >>= 1) p += __shfl_xor(p, msk);
            if (__any(p - m > 11.5f)) {
                float mn = fmaxf(m, p);
                float sc = __builtin_amdgcn_exp2f(m - mn);
                z *= sc;
                acc.x *= sc; acc.y *= sc; acc.z *= sc; acc.w *= sc;
                m = mn;
            }
            float w = __builtin_amdgcn_exp2f(p - m);
            z += w;
            acc.x = fmaf((float)l0[0], w, acc.x); acc.y = fmaf((float)l0[1], w, acc.y);
            acc.z = fmaf((float)l0[2], w, acc.z); acc.w = fmaf((float)l0[3], w, acc.w);
        }
        float inv = 0.5f / (z + 1e-16f);         // z uniform within each half
        acc.x *= inv; acc.y *= inv; acc.z *= inv; acc.w *= inv;
        // head mean: lane L (<32) += lane L+32 (same channels, head 1)
        acc.x += __shfl_xor(acc.x, 32);
        acc.y += __shfl_xor(acc.y, 32);
        acc.z += __shfl_xor(acc.z, 32);
        acc.w += __shfl_xor(acc.w, 32);
        if (lane < 32) {
            float4* o = (float4*)(out + (size_t)t * DCH + lane * 4);
            float4 cur = *o;
            cur.x += acc.x; cur.y += acc.y; cur.z += acc.z; cur.w += acc.w;
            *o = cur;
        }
    }
}

// --------------------------------------------------------------------- launch
extern "C" void kernel_launch(void* const* d_in, const int* in_sizes, int n_in,
                              void* d_out, int out_size, void* d_ws, size_t ws_size,
                              hipStream_t stream) {
    const float* x     = (const float*)d_in[0];
    const int*   ei    = (const int*)d_in[1];
    const float* gamma = (const float*)d_in[2];
    const float* beta  = (const float*)d_in[3];
    const float* Wl    = (const float*)d_in[4];
    const float* bl    = (const float*)d_in[5];
    const float* Wr    = (const float*)d_in[6];
    const float* br    = (const float*)d_in[7];
    const float* att   = (const float*)d_in[8];
    const float* resW  = (const float*)d_in[9];
    const float* bias  = (const float*)d_in[10];
    float* out = (float*)d_out;

    int n = in_sizes[0] / DCH;
    int E = in_sizes[1] / 2;
    const int* src = ei;
    const int* dstIdx = ei + E;

    char* ws = (char*)d_ws;
    size_t off = 0;
    auto alloc = [&](size_t bytes) -> void* {
        void* p = ws + off;
        off = (off + bytes + 255) & ~(size_t)255;
        return p;
    };

    int nb = (n + 255) / 256;

    unsigned short* xl = (unsigned short*)alloc((size_t)n * 256 * 2);  // 51.2 MB
    unsigned short* xr = (unsigned short*)alloc((size_t)n * 256 * 2);  // 51.2 MB
    unsigned short* wfrag = (unsigned short*)alloc(160 * 64 * 8 * 2);  // 160 KB
    int* cnt   = (int*)alloc((size_t)n * 4);
    int* offs  = (int*)alloc((size_t)(n + 1) * 4);
    int* bsum  = (int*)alloc((size_t)nb * 4);
    int* fillc = (int*)alloc((size_t)n * 4);
    int* sbuf  = (int*)alloc((size_t)E * 4);                           // 6.4 MB

    prep_and_zero<<<40 + nb, 256, 0, stream>>>(Wl, Wr, resW, wfrag, cnt, n);
    hist_dst<<<2048, 256, 0, stream>>>(dstIdx, cnt, E);
    scan_block<<<nb, 256, 0, stream>>>(cnt, offs, bsum, n);
    scan_bsum_par<<<1, 512, 0, stream>>>(bsum, nb);
    scan_add<<<nb, 256, 0, stream>>>(offs, fillc, bsum, n, E);
    fill_csr<<<2048, 256, 0, stream>>>(src, dstIdx, fillc, sbuf, E);

    int nrb = (n + 127) / 128;
    gemm_mfma<<<nrb, 256, 0, stream>>>(x, gamma, beta, wfrag, bl, br, bias,
                                       xl, xr, out, n);
    gat_aggregate<<<2048, 256, 0, stream>>>(offs, sbuf, xl, xr, att, out, n);
}

// Round 8
// 435.812 us; speedup vs baseline: 5.5273x; 1.0131x over previous
//
#include <hip/hip_runtime.h>
#include <hip/hip_bf16.h>
#include <cstdint>
#include <cstddef>

#define DCH 128
#define NHEADS 2
#define NEG_SLOPE 0.2f

typedef __attribute__((ext_vector_type(8))) short short8v;
typedef __attribute__((ext_vector_type(4))) float f32x4;
typedef _Float16 h2 __attribute__((ext_vector_type(2)));
typedef _Float16 h4 __attribute__((ext_vector_type(4)));

// ---------------------------------------------------------------- utilities
__device__ __forceinline__ unsigned short f2bf(float f) {
    union { float f; unsigned int i; } v; v.f = f;
    unsigned int r = v.i + 0x7fffu + ((v.i >> 16) & 1u);   // RNE
    return (unsigned short)(r >> 16);
}
__device__ __forceinline__ unsigned short f2h_bits(float f) {
    _Float16 h = (_Float16)f;
    union { _Float16 h; unsigned short u; } v; v.h = h; return v.u;
}

__device__ __forceinline__ h2 lrelu2(h2 v, h2 ns) {
    h2 f = v * ns;
#if __has_builtin(__builtin_elementwise_max)
    return __builtin_elementwise_max(v, f);
#else
    h2 r; r[0] = v[0] > f[0] ? v[0] : f[0]; r[1] = v[1] > f[1] ? v[1] : f[1];
    return r;
#endif
}
__device__ __forceinline__ float dot4h(h2 a0, h2 a1, h2 b0, h2 b1) {
#if __has_builtin(__builtin_amdgcn_fdot2)
    return __builtin_amdgcn_fdot2(a0, b0, __builtin_amdgcn_fdot2(a1, b1, 0.f, false), false);
#else
    return (float)a0[0]*(float)b0[0] + (float)a0[1]*(float)b0[1]
         + (float)a1[0]*(float)b1[0] + (float)a1[1]*(float)b1[1];
#endif
}

// 32-lane-half sum: every lane ends with the sum over its 32-lane half.
// 4 row_ror DPP adds (VALU-only; rotation pairing is valid for a commutative
// sum, every lane accumulates all 16 row values) + one ds_swizzle xor16.
__device__ __forceinline__ float halfsum(float p) {
    p += __int_as_float(__builtin_amdgcn_update_dpp(
            0, __float_as_int(p), 0x121, 0xF, 0xF, false));  // row_ror:1
    p += __int_as_float(__builtin_amdgcn_update_dpp(
            0, __float_as_int(p), 0x122, 0xF, 0xF, false));  // row_ror:2
    p += __int_as_float(__builtin_amdgcn_update_dpp(
            0, __float_as_int(p), 0x124, 0xF, 0xF, false));  // row_ror:4
    p += __int_as_float(__builtin_amdgcn_update_dpp(
            0, __float_as_int(p), 0x128, 0xF, 0xF, false));  // row_ror:8
    p += __int_as_float(__builtin_amdgcn_ds_swizzle(
            __float_as_int(p), 0x401F));                     // lane ^= 16
    return p;
}

// ------------------------------- merged: weights->bf16 fragments + zero cnt
// blocks [0,40): wfrag; blocks [40, ...): cnt[i] = 0.
__global__ void prep_and_zero(const float* __restrict__ Wl, const float* __restrict__ Wr,
                              const float* __restrict__ resW,
                              unsigned short* __restrict__ wfrag,
                              int* __restrict__ cnt, int n) {
    if (blockIdx.x >= 40) {
        int i = (blockIdx.x - 40) * 256 + threadIdx.x;
        if (i < n) cnt[i] = 0;
        return;
    }
    int gid  = blockIdx.x * 256 + threadIdx.x;   // 10240 threads
    int lane = gid & 63;
    int f    = gid >> 6;                          // 0..159
    int ks   = f & 3;
    int ct   = f >> 2;
    int col  = ct * 16 + (lane & 15);
    int k0   = ks * 32 + (lane >> 4) * 8;
    const float* W; int ldB, c;
    if (col < 256)      { W = Wl;   ldB = 256; c = col; }
    else if (col < 512) { W = Wr;   ldB = 256; c = col - 256; }
    else                { W = resW; ldB = 128; c = col - 512; }
    unsigned short tmp[8];
#pragma unroll
    for (int j = 0; j < 8; ++j) tmp[j] = f2bf(W[(size_t)(k0 + j) * ldB + c]);
    ushort4* dst = (ushort4*)(wfrag + (size_t)gid * 8);
    dst[0] = make_ushort4(tmp[0], tmp[1], tmp[2], tmp[3]);
    dst[1] = make_ushort4(tmp[4], tmp[5], tmp[6], tmp[7]);
}

// ---------------- fused LN+ReLU + MFMA GEMM (128 rows x 640 cols per block)
// A = relu(LN(x)) staged bf16 in LDS, XOR-swizzled (byte ^= (row&7)<<4).
// OPERAND-SWAPPED MFMA: mfma(wfrag, afrag) computes D^T, so lane&15 = node
// row and regs i = 4 consecutive output columns -> vector epilogue stores
// (ushort4 for xl/xr, float4 for out) instead of scalar.
__launch_bounds__(256)
__global__ void gemm_mfma(const float* __restrict__ x,
                          const float* __restrict__ gamma, const float* __restrict__ beta,
                          const unsigned short* __restrict__ wfrag,
                          const float* __restrict__ bl, const float* __restrict__ br,
                          const float* __restrict__ bias,
                          unsigned short* __restrict__ xl, unsigned short* __restrict__ xr,
                          float* __restrict__ out, int n) {
    __shared__ __align__(16) unsigned short As[128 * 128];  // 32 KB, swizzled
    int row0 = blockIdx.x * 128;
    int tid  = threadIdx.x;

    // ---- stage A with fused LayerNorm+ReLU (32 threads per row, 16 passes)
    {
        int r  = tid >> 5;            // 0..7
        int k4 = (tid & 31) * 4;      // 0,4,...,124
        float4 g4  = *(const float4*)(gamma + k4);
        float4 be4 = *(const float4*)(beta + k4);
#pragma unroll
        for (int i = 0; i < 16; ++i) {
            int row  = r + i * 8;
            int grow = row0 + row;
            float4 a = (grow < n) ? *(const float4*)(x + (size_t)grow * DCH + k4)
                                  : make_float4(0.f, 0.f, 0.f, 0.f);
            float s  = a.x + a.y + a.z + a.w;
            float sq = a.x * a.x + a.y * a.y + a.z * a.z + a.w * a.w;
#pragma unroll
            for (int msk = 16; msk; msk >>= 1) {
                s  += __shfl_xor(s, msk);
                sq += __shfl_xor(sq, msk);
            }
            float mu = s * (1.f / DCH);
            float rs = rsqrtf(sq * (1.f / DCH) - mu * mu + 1e-5f);
            ushort4 u;
            u.x = f2bf(fmaxf((a.x - mu) * rs * g4.x + be4.x, 0.f));
            u.y = f2bf(fmaxf((a.y - mu) * rs * g4.y + be4.y, 0.f));
            u.z = f2bf(fmaxf((a.z - mu) * rs * g4.z + be4.z, 0.f));
            u.w = f2bf(fmaxf((a.w - mu) * rs * g4.w + be4.w, 0.f));
            int byteoff = row * 256 + ((k4 * 2) ^ ((row & 7) << 4));
            *(ushort4*)((char*)As + byteoff) = u;
        }
    }
    __syncthreads();

    int wv = tid >> 6, lane = tid & 63;

    // activation fragments: 2 node-groups x 4 K-slices (B-operand layout:
    // lane&15 = node, k = (lane>>4)*8+j) -- reused across 40 col-tiles
    short8v afrag[2][4];
#pragma unroll
    for (int g = 0; g < 2; ++g) {
        int arow = wv * 32 + g * 16 + (lane & 15);
#pragma unroll
        for (int ks = 0; ks < 4; ++ks) {
            int kbyte = (ks * 64 + (lane >> 4) * 16) ^ ((arow & 7) << 4);
            afrag[g][ks] = *(const short8v*)((const char*)As + arow * 256 + kbyte);
        }
    }

    int node0 = row0 + wv * 32 + (lane & 15);        // group 0 node
    int node1 = node0 + 16;                          // group 1 node
    bool v0 = node0 < n, v1 = node1 < n;
    int cq = (lane >> 4) << 2;                       // column quad 0,4,8,12

#pragma unroll 2
    for (int ct = 0; ct < 40; ++ct) {
        const unsigned short* bp = wfrag + ((size_t)(ct * 4) * 64 + lane) * 8;
        short8v b0 = *(const short8v*)(bp);
        short8v b1 = *(const short8v*)(bp + 64 * 8);
        short8v b2 = *(const short8v*)(bp + 128 * 8);
        short8v b3 = *(const short8v*)(bp + 192 * 8);
        f32x4 acc0 = {0.f, 0.f, 0.f, 0.f};
        f32x4 acc1 = {0.f, 0.f, 0.f, 0.f};
        acc0 = __builtin_amdgcn_mfma_f32_16x16x32_bf16(b0, afrag[0][0], acc0, 0, 0, 0);
        acc1 = __builtin_amdgcn_mfma_f32_16x16x32_bf16(b0, afrag[1][0], acc1, 0, 0, 0);
        acc0 = __builtin_amdgcn_mfma_f32_16x16x32_bf16(b1, afrag[0][1], acc0, 0, 0, 0);
        acc1 = __builtin_amdgcn_mfma_f32_16x16x32_bf16(b1, afrag[1][1], acc1, 0, 0, 0);
        acc0 = __builtin_amdgcn_mfma_f32_16x16x32_bf16(b2, afrag[0][2], acc0, 0, 0, 0);
        acc1 = __builtin_amdgcn_mfma_f32_16x16x32_bf16(b2, afrag[1][2], acc1, 0, 0, 0);
        acc0 = __builtin_amdgcn_mfma_f32_16x16x32_bf16(b3, afrag[0][3], acc0, 0, 0, 0);
        acc1 = __builtin_amdgcn_mfma_f32_16x16x32_bf16(b3, afrag[1][3], acc1, 0, 0, 0);

        // D^T: lane&15 = node, regs i = columns c0..c0+3
        int c0 = ct * 16 + cq;
        if (ct < 32) {
            unsigned short* dst; int c; const float* bv;
            if (ct < 16) { dst = xl; c = c0;       bv = bl; }
            else         { dst = xr; c = c0 - 256; bv = br; }
            float4 bb = *(const float4*)(bv + c);
            if (v0) {
                ushort4 u = make_ushort4(f2h_bits(acc0[0] + bb.x), f2h_bits(acc0[1] + bb.y),
                                         f2h_bits(acc0[2] + bb.z), f2h_bits(acc0[3] + bb.w));
                *(ushort4*)(dst + (size_t)node0 * 256 + c) = u;
            }
            if (v1) {
                ushort4 u = make_ushort4(f2h_bits(acc1[0] + bb.x), f2h_bits(acc1[1] + bb.y),
                                         f2h_bits(acc1[2] + bb.z), f2h_bits(acc1[3] + bb.w));
                *(ushort4*)(dst + (size_t)node1 * 256 + c) = u;
            }
        } else {
            int c = c0 - 512;
            float4 bb = *(const float4*)(bias + c);
            if (v0) {
                float4 xv = *(const float4*)(x + (size_t)node0 * DCH + c);
                float4 o = make_float4(acc0[0] + bb.x + xv.x, acc0[1] + bb.y + xv.y,
                                       acc0[2] + bb.z + xv.z, acc0[3] + bb.w + xv.w);
                *(float4*)(out + (size_t)node0 * DCH + c) = o;
            }
            if (v1) {
                float4 xv = *(const float4*)(x + (size_t)node1 * DCH + c);
                float4 o = make_float4(acc1[0] + bb.x + xv.x, acc1[1] + bb.y + xv.y,
                                       acc1[2] + bb.z + xv.z, acc1[3] + bb.w + xv.w);
                *(float4*)(out + (size_t)node1 * DCH + c) = o;
            }
        }
    }
}

// --------------------------------------------------------------- CSR build
__global__ void hist_dst(const int* __restrict__ dst, int* __restrict__ cnt, int E) {
    int i = blockIdx.x * blockDim.x + threadIdx.x;
    int E4 = E >> 2;
    if (i < E4) {
        int4 d = ((const int4*)dst)[i];
        atomicAdd(&cnt[d.x], 1); atomicAdd(&cnt[d.y], 1);
        atomicAdd(&cnt[d.z], 1); atomicAdd(&cnt[d.w], 1);
    }
    if (i < (E & 3)) atomicAdd(&cnt[dst[E4 * 4 + i]], 1);
}

__global__ void scan_block(const int* __restrict__ cnt, int* __restrict__ offs,
                           int* __restrict__ bsum, int n) {
    __shared__ int sm[256];
    int t = threadIdx.x;
    int i = blockIdx.x * 256 + t;
    int v = (i < n) ? cnt[i] : 0;
    sm[t] = v;
    __syncthreads();
#pragma unroll
    for (int d = 1; d < 256; d <<= 1) {
        int add = (t >= d) ? sm[t - d] : 0;
        __syncthreads();
        sm[t] += add;
        __syncthreads();
    }
    if (i < n) offs[i] = sm[t] - v;
    if (t == 255) bsum[blockIdx.x] = sm[t];
}

// parallel exclusive scan of block sums (single block; nb <= 512 fast path)
__global__ void scan_bsum_par(int* __restrict__ bsum, int nb) {
    __shared__ int sm[512];
    int t = threadIdx.x;
    if (nb <= 512) {
        int v = (t < nb) ? bsum[t] : 0;
        sm[t] = v;
        __syncthreads();
#pragma unroll
        for (int d = 1; d < 512; d <<= 1) {
            int add = (t >= d) ? sm[t - d] : 0;
            __syncthreads();
            sm[t] += add;
            __syncthreads();
        }
        if (t < nb) bsum[t] = sm[t] - v;
    } else if (t == 0) {
        int acc = 0;
        for (int i = 0; i < nb; ++i) { int v = bsum[i]; bsum[i] = acc; acc += v; }
    }
}

// add block offsets; also pre-init fillc = offs so fill_csr skips one read
__global__ void scan_add(int* __restrict__ offs, int* __restrict__ fillc,
                         const int* __restrict__ bsum, int n, int E) {
    int i = blockIdx.x * 256 + threadIdx.x;
    if (i < n) {
        int v = offs[i] + bsum[blockIdx.x];
        offs[i]  = v;
        fillc[i] = v;
    }
    if (i == 0) offs[n] = E;
}

__global__ void fill_csr(const int* __restrict__ src, const int* __restrict__ dst,
                         int* __restrict__ fillc, int* __restrict__ sbuf, int E) {
    int i = blockIdx.x * blockDim.x + threadIdx.x;
    int E4 = E >> 2;
    if (i < E4) {
        int4 d = ((const int4*)dst)[i];
        int4 s = ((const int4*)src)[i];
        sbuf[atomicAdd(&fillc[d.x], 1)] = s.x;
        sbuf[atomicAdd(&fillc[d.y], 1)] = s.y;
        sbuf[atomicAdd(&fillc[d.z], 1)] = s.z;
        sbuf[atomicAdd(&fillc[d.w], 1)] = s.w;
    }
    if (i < (E & 3)) {
        int e = E4 * 4 + i;
        sbuf[atomicAdd(&fillc[dst[e]], 1)] = src[e];
    }
}

// --------------- single-pass fused attention + softmax + aggregation (f16)
// One wave per dst node t. Packed-f16 leaky-relu + v_dot2_f32_f16 dot; att
// pre-scaled by log2(e) (exp2 softmax). Lane-local per-head online (m,z)
// with defer-max; DPP row_ror + 1 ds_swizzle reduction; 4-way edge unroll.
__launch_bounds__(256)
__global__ void gat_aggregate(const int* __restrict__ offs, const int* __restrict__ sbuf,
                              const unsigned short* __restrict__ xl_,
                              const unsigned short* __restrict__ xr_,
                              const float* __restrict__ att,
                              float* __restrict__ out, int n) {
    const _Float16* xl = (const _Float16*)xl_;
    const _Float16* xr = (const _Float16*)xr_;
    int lane = threadIdx.x & 63;
    int wid  = __builtin_amdgcn_readfirstlane((blockIdx.x * blockDim.x + threadIdx.x) >> 6);
    int nw   = (gridDim.x * blockDim.x) >> 6;

    const float LOG2E = 1.4426950408889634f;
    float4 af = *(const float4*)(att + lane * 4);   // flat[256]: lanes 0..31 head0
    h2 av0 = {(_Float16)(af.x * LOG2E), (_Float16)(af.y * LOG2E)};
    h2 av1 = {(_Float16)(af.z * LOG2E), (_Float16)(af.w * LOG2E)};
    h2 ns  = {(_Float16)NEG_SLOPE, (_Float16)NEG_SLOPE};

    for (int t = wid; t < n; t += nw) {
        int beg = offs[t];
        int end = offs[t + 1];
        if (beg == end) continue;
        h4 r4 = *(const h4*)(xr + (size_t)t * 256 + lane * 4);
        h2 r0 = __builtin_shufflevector(r4, r4, 0, 1);
        h2 r1 = __builtin_shufflevector(r4, r4, 2, 3);

        float m = -INFINITY, z = 0.f;            // per-lane: own head's state
        float4 acc = make_float4(0.f, 0.f, 0.f, 0.f);
        int j = beg;
        for (; j + 4 <= end; j += 4) {
            int s0 = sbuf[j], s1 = sbuf[j + 1], s2 = sbuf[j + 2], s3 = sbuf[j + 3];
            h4 l0 = *(const h4*)(xl + (size_t)s0 * 256 + lane * 4);
            h4 l1 = *(const h4*)(xl + (size_t)s1 * 256 + lane * 4);
            h4 l2 = *(const h4*)(xl + (size_t)s2 * 256 + lane * 4);
            h4 l3 = *(const h4*)(xl + (size_t)s3 * 256 + lane * 4);
            float p0 = dot4h(lrelu2(__builtin_shufflevector(l0, l0, 0, 1) + r0, ns),
                             lrelu2(__builtin_shufflevector(l0, l0, 2, 3) + r1, ns), av0, av1);
            float p1 = dot4h(lrelu2(__builtin_shufflevector(l1, l1, 0, 1) + r0, ns),
                             lrelu2(__builtin_shufflevector(l1, l1, 2, 3) + r1, ns), av0, av1);
            float p2 = dot4h(lrelu2(__builtin_shufflevector(l2, l2, 0, 1) + r0, ns),
                             lrelu2(__builtin_shufflevector(l2, l2, 2, 3) + r1, ns), av0, av1);
            float p3 = dot4h(lrelu2(__builtin_shufflevector(l3, l3, 0, 1) + r0, ns),
                             lrelu2(__builtin_shufflevector(l3, l3, 2, 3) + r1, ns), av0, av1);
            p0 = halfsum(p0);
            p1 = halfsum(p1);
            p2 = halfsum(p2);
            p3 = halfsum(p3);
            float pm = fmaxf(fmaxf(p0, p1), fmaxf(p2, p3));
            if (__any(pm - m > 11.5f)) {         // 8/ln2: raise reference max
                float mn = fmaxf(m, pm);
                float sc = __builtin_amdgcn_exp2f(m - mn);   // 0 on first group
                z *= sc;
                acc.x *= sc; acc.y *= sc; acc.z *= sc; acc.w *= sc;
                m = mn;
            }
            float w0 = __builtin_amdgcn_exp2f(p0 - m);
            float w1 = __builtin_amdgcn_exp2f(p1 - m);
            float w2 = __builtin_amdgcn_exp2f(p2 - m);
            float w3 = __builtin_amdgcn_exp2f(p3 - m);
            z += (w0 + w1) + (w2 + w3);
            acc.x = fmaf((float)l0[0], w0, acc.x); acc.y = fmaf((float)l0[1], w0, acc.y);
            acc.z = fmaf((float)l0[2], w0, acc.z); acc.w = fmaf((float)l0[3], w0, acc.w);
            acc.x = fmaf((float)l1[0], w1, acc.x); acc.y = fmaf((float)l1[1], w1, acc.y);
            acc.z = fmaf((float)l1[2], w1, acc.z); acc.w = fmaf((float)l1[3], w1, acc.w);
            acc.x = fmaf((float)l2[0], w2, acc.x); acc.y = fmaf((float)l2[1], w2, acc.y);
            acc.z = fmaf((float)l2[2], w2, acc.z); acc.w = fmaf((float)l2[3], w2, acc.w);
            acc.x = fmaf((float)l3[0], w3, acc.x); acc.y = fmaf((float)l3[1], w3, acc.y);
            acc.z = fmaf((float)l3[2], w3, acc.z); acc.w = fmaf((float)l3[3], w3, acc.w);
        }
        for (; j < end; ++j) {                   // tail (0..3 edges)
            int s = sbuf[j];
            h4 l0 = *(const h4*)(xl + (size_t)s * 256 + lane * 4);
            float p = dot4h(lrelu2(__builtin_shufflevector(l0, l0, 0, 1) + r0, ns),
                            lrelu2(__builtin_shufflevector(l0, l0, 2, 3) + r1, ns), av0, av1);
            p = halfsum(p);
            if (__any(p - m > 11.5f)) {
                float mn = fmaxf(m, p);
                float sc = __builtin_amdgcn_exp2f(m - mn);
                z *= sc;
                acc.x *= sc; acc.y *= sc; acc.z *= sc; acc.w *= sc;
                m = mn;
            }
            float w = __builtin_amdgcn_exp2f(p - m);
            z += w;
            acc.x = fmaf((float)l0[0], w, acc.x); acc.y = fmaf((float)l0[1], w, acc.y);
            acc.z = fmaf((float)l0[2], w, acc.z); acc.w = fmaf((float)l0[3], w, acc.w);
        }
        float inv = 0.5f / (z + 1e-16f);         // z uniform within each half
        acc.x *= inv; acc.y *= inv; acc.z *= inv; acc.w *= inv;
        // head mean: lane L (<32) += lane L+32 (same channels, head 1)
        acc.x += __shfl_xor(acc.x, 32);
        acc.y += __shfl_xor(acc.y, 32);
        acc.z += __shfl_xor(acc.z, 32);
        acc.w += __shfl_xor(acc.w, 32);
        if (lane < 32) {
            float4* o = (float4*)(out + (size_t)t * DCH + lane * 4);
            float4 cur = *o;
            cur.x += acc.x; cur.y += acc.y; cur.z += acc.z; cur.w += acc.w;
            *o = cur;
        }
    }
}

// --------------------------------------------------------------------- launch
extern "C" void kernel_launch(void* const* d_in, const int* in_sizes, int n_in,
                              void* d_out, int out_size, void* d_ws, size_t ws_size,
                              hipStream_t stream) {
    const float* x     = (const float*)d_in[0];
    const int*   ei    = (const int*)d_in[1];
    const float* gamma = (const float*)d_in[2];
    const float* beta  = (const float*)d_in[3];
    const float* Wl    = (const float*)d_in[4];
    const float* bl    = (const float*)d_in[5];
    const float* Wr    = (const float*)d_in[6];
    const float* br    = (const float*)d_in[7];
    const float* att   = (const float*)d_in[8];
    const float* resW  = (const float*)d_in[9];
    const float* bias  = (const float*)d_in[10];
    float* out = (float*)d_out;

    int n = in_sizes[0] / DCH;
    int E = in_sizes[1] / 2;
    const int* src = ei;
    const int* dstIdx = ei + E;

    char* ws = (char*)d_ws;
    size_t off = 0;
    auto alloc = [&](size_t bytes) -> void* {
        void* p = ws + off;
        off = (off + bytes + 255) & ~(size_t)255;
        return p;
    };

    int nb = (n + 255) / 256;

    unsigned short* xl = (unsigned short*)alloc((size_t)n * 256 * 2);  // 51.2 MB
    unsigned short* xr = (unsigned short*)alloc((size_t)n * 256 * 2);  // 51.2 MB
    unsigned short* wfrag = (unsigned short*)alloc(160 * 64 * 8 * 2);  // 160 KB
    int* cnt   = (int*)alloc((size_t)n * 4);
    int* offs  = (int*)alloc((size_t)(n + 1) * 4);
    int* bsum  = (int*)alloc((size_t)nb * 4);
    int* fillc = (int*)alloc((size_t)n * 4);
    int* sbuf  = (int*)alloc((size_t)E * 4);                           // 6.4 MB

    prep_and_zero<<<40 + nb, 256, 0, stream>>>(Wl, Wr, resW, wfrag, cnt, n);
    int ethr = (E / 4 + 255) / 256 + 1;
    hist_dst<<<ethr, 256, 0, stream>>>(dstIdx, cnt, E);
    scan_block<<<nb, 256, 0, stream>>>(cnt, offs, bsum, n);
    scan_bsum_par<<<1, 512, 0, stream>>>(bsum, nb);
    scan_add<<<nb, 256, 0, stream>>>(offs, fillc, bsum, n, E);
    fill_csr<<<ethr, 256, 0, stream>>>(src, dstIdx, fillc, sbuf, E);

    int nrb = (n + 127) / 128;
    gemm_mfma<<<nrb, 256, 0, stream>>>(x, gamma, beta, wfrag, bl, br, bias,
                                       xl, xr, out, n);
    gat_aggregate<<<2048, 256, 0, stream>>>(offs, sbuf, xl, xr, att, out, n);
}

// Round 9
// 349.877 us; speedup vs baseline: 6.8849x; 1.2456x over previous
//
#include <hip/hip_runtime.h>
#include <hip/hip_bf16.h>
#include <cstdint>
#include <cstddef>

#define DCH 128
#define NHEADS 2
#define NEG_SLOPE 0.2f

typedef __attribute__((ext_vector_type(8))) short short8v;
typedef __attribute__((ext_vector_type(4))) float f32x4;
typedef _Float16 h2 __attribute__((ext_vector_type(2)));
typedef _Float16 h4 __attribute__((ext_vector_type(4)));

// ---------------------------------------------------------------- utilities
__device__ __forceinline__ unsigned short f2bf(float f) {
    union { float f; unsigned int i; } v; v.f = f;
    unsigned int r = v.i + 0x7fffu + ((v.i >> 16) & 1u);   // RNE
    return (unsigned short)(r >> 16);
}
__device__ __forceinline__ unsigned short f2h_bits(float f) {
    _Float16 h = (_Float16)f;
    union { _Float16 h; unsigned short u; } v; v.h = h; return v.u;
}

__device__ __forceinline__ h2 lrelu2(h2 v, h2 ns) {
    h2 f = v * ns;
#if __has_builtin(__builtin_elementwise_max)
    return __builtin_elementwise_max(v, f);
#else
    h2 r; r[0] = v[0] > f[0] ? v[0] : f[0]; r[1] = v[1] > f[1] ? v[1] : f[1];
    return r;
#endif
}
__device__ __forceinline__ float dot4h(h2 a0, h2 a1, h2 b0, h2 b1) {
#if __has_builtin(__builtin_amdgcn_fdot2)
    return __builtin_amdgcn_fdot2(a0, b0, __builtin_amdgcn_fdot2(a1, b1, 0.f, false), false);
#else
    return (float)a0[0]*(float)b0[0] + (float)a0[1]*(float)b0[1]
         + (float)a1[0]*(float)b1[0] + (float)a1[1]*(float)b1[1];
#endif
}

// 32-lane-half sum via DPP row_ror + one ds_swizzle (xor16).
__device__ __forceinline__ float halfsum(float p) {
    p += __int_as_float(__builtin_amdgcn_update_dpp(
            0, __float_as_int(p), 0x121, 0xF, 0xF, false));  // row_ror:1
    p += __int_as_float(__builtin_amdgcn_update_dpp(
            0, __float_as_int(p), 0x122, 0xF, 0xF, false));  // row_ror:2
    p += __int_as_float(__builtin_amdgcn_update_dpp(
            0, __float_as_int(p), 0x124, 0xF, 0xF, false));  // row_ror:4
    p += __int_as_float(__builtin_amdgcn_update_dpp(
            0, __float_as_int(p), 0x128, 0xF, 0xF, false));  // row_ror:8
    p += __int_as_float(__builtin_amdgcn_ds_swizzle(
            __float_as_int(p), 0x401F));                     // lane ^= 16
    return p;
}

// ------------------------------- merged: weights->bf16 fragments + zero cnt
__global__ void prep_and_zero(const float* __restrict__ Wl, const float* __restrict__ Wr,
                              const float* __restrict__ resW,
                              unsigned short* __restrict__ wfrag,
                              int* __restrict__ cnt, int n) {
    if (blockIdx.x >= 40) {
        int i = (blockIdx.x - 40) * 256 + threadIdx.x;
        if (i < n) cnt[i] = 0;
        return;
    }
    int gid  = blockIdx.x * 256 + threadIdx.x;   // 10240 threads
    int lane = gid & 63;
    int f    = gid >> 6;                          // 0..159
    int ks   = f & 3;
    int ct   = f >> 2;
    int col  = ct * 16 + (lane & 15);
    int k0   = ks * 32 + (lane >> 4) * 8;
    const float* W; int ldB, c;
    if (col < 256)      { W = Wl;   ldB = 256; c = col; }
    else if (col < 512) { W = Wr;   ldB = 256; c = col - 256; }
    else                { W = resW; ldB = 128; c = col - 512; }
    unsigned short tmp[8];
#pragma unroll
    for (int j = 0; j < 8; ++j) tmp[j] = f2bf(W[(size_t)(k0 + j) * ldB + c]);
    ushort4* dst = (ushort4*)(wfrag + (size_t)gid * 8);
    dst[0] = make_ushort4(tmp[0], tmp[1], tmp[2], tmp[3]);
    dst[1] = make_ushort4(tmp[4], tmp[5], tmp[6], tmp[7]);
}

// ------- combined dispatch: blocks [0,nrb) = LN+MFMA GEMM, rest = fill_csr
// (independent work overlapped on different CUs; both only feed gat_aggregate)
__launch_bounds__(256)
__global__ void gemm_fill(const float* __restrict__ x,
                          const float* __restrict__ gamma, const float* __restrict__ beta,
                          const unsigned short* __restrict__ wfrag,
                          const float* __restrict__ bl, const float* __restrict__ br,
                          const float* __restrict__ bias,
                          unsigned short* __restrict__ xl, unsigned short* __restrict__ xr,
                          float* __restrict__ out, int n,
                          const int* __restrict__ srcIdx, const int* __restrict__ dstIdx,
                          int* __restrict__ fillc, int* __restrict__ sbuf, int E, int nrb) {
    __shared__ __align__(16) unsigned short As[128 * 128];  // 32 KB, swizzled

    if ((int)blockIdx.x >= nrb) {
        // ---------------- fill_csr part
        int i = (blockIdx.x - nrb) * 256 + threadIdx.x;
        int E4 = E >> 2;
        if (i < E4) {
            int4 d = ((const int4*)dstIdx)[i];
            int4 s = ((const int4*)srcIdx)[i];
            sbuf[atomicAdd(&fillc[d.x], 1)] = s.x;
            sbuf[atomicAdd(&fillc[d.y], 1)] = s.y;
            sbuf[atomicAdd(&fillc[d.z], 1)] = s.z;
            sbuf[atomicAdd(&fillc[d.w], 1)] = s.w;
        }
        if (i < (E & 3)) {
            int e = E4 * 4 + i;
            sbuf[atomicAdd(&fillc[dstIdx[e]], 1)] = srcIdx[e];
        }
        return;
    }

    // ---------------- GEMM part (operand-swapped MFMA, vector epilogue)
    int row0 = blockIdx.x * 128;
    int tid  = threadIdx.x;

    {
        int r  = tid >> 5;            // 0..7
        int k4 = (tid & 31) * 4;      // 0,4,...,124
        float4 g4  = *(const float4*)(gamma + k4);
        float4 be4 = *(const float4*)(beta + k4);
#pragma unroll
        for (int i = 0; i < 16; ++i) {
            int row  = r + i * 8;
            int grow = row0 + row;
            float4 a = (grow < n) ? *(const float4*)(x + (size_t)grow * DCH + k4)
                                  : make_float4(0.f, 0.f, 0.f, 0.f);
            float s  = a.x + a.y + a.z + a.w;
            float sq = a.x * a.x + a.y * a.y + a.z * a.z + a.w * a.w;
#pragma unroll
            for (int msk = 16; msk; msk >>= 1) {
                s  += __shfl_xor(s, msk);
                sq += __shfl_xor(sq, msk);
            }
            float mu = s * (1.f / DCH);
            float rs = rsqrtf(sq * (1.f / DCH) - mu * mu + 1e-5f);
            ushort4 u;
            u.x = f2bf(fmaxf((a.x - mu) * rs * g4.x + be4.x, 0.f));
            u.y = f2bf(fmaxf((a.y - mu) * rs * g4.y + be4.y, 0.f));
            u.z = f2bf(fmaxf((a.z - mu) * rs * g4.z + be4.z, 0.f));
            u.w = f2bf(fmaxf((a.w - mu) * rs * g4.w + be4.w, 0.f));
            int byteoff = row * 256 + ((k4 * 2) ^ ((row & 7) << 4));
            *(ushort4*)((char*)As + byteoff) = u;
        }
    }
    __syncthreads();

    int wv = tid >> 6, lane = tid & 63;

    short8v afrag[2][4];
#pragma unroll
    for (int g = 0; g < 2; ++g) {
        int arow = wv * 32 + g * 16 + (lane & 15);
#pragma unroll
        for (int ks = 0; ks < 4; ++ks) {
            int kbyte = (ks * 64 + (lane >> 4) * 16) ^ ((arow & 7) << 4);
            afrag[g][ks] = *(const short8v*)((const char*)As + arow * 256 + kbyte);
        }
    }

    int node0 = row0 + wv * 32 + (lane & 15);
    int node1 = node0 + 16;
    bool v0 = node0 < n, v1 = node1 < n;
    int cq = (lane >> 4) << 2;

#pragma unroll 2
    for (int ct = 0; ct < 40; ++ct) {
        const unsigned short* bp = wfrag + ((size_t)(ct * 4) * 64 + lane) * 8;
        short8v b0 = *(const short8v*)(bp);
        short8v b1 = *(const short8v*)(bp + 64 * 8);
        short8v b2 = *(const short8v*)(bp + 128 * 8);
        short8v b3 = *(const short8v*)(bp + 192 * 8);
        f32x4 acc0 = {0.f, 0.f, 0.f, 0.f};
        f32x4 acc1 = {0.f, 0.f, 0.f, 0.f};
        acc0 = __builtin_amdgcn_mfma_f32_16x16x32_bf16(b0, afrag[0][0], acc0, 0, 0, 0);
        acc1 = __builtin_amdgcn_mfma_f32_16x16x32_bf16(b0, afrag[1][0], acc1, 0, 0, 0);
        acc0 = __builtin_amdgcn_mfma_f32_16x16x32_bf16(b1, afrag[0][1], acc0, 0, 0, 0);
        acc1 = __builtin_amdgcn_mfma_f32_16x16x32_bf16(b1, afrag[1][1], acc1, 0, 0, 0);
        acc0 = __builtin_amdgcn_mfma_f32_16x16x32_bf16(b2, afrag[0][2], acc0, 0, 0, 0);
        acc1 = __builtin_amdgcn_mfma_f32_16x16x32_bf16(b2, afrag[1][2], acc1, 0, 0, 0);
        acc0 = __builtin_amdgcn_mfma_f32_16x16x32_bf16(b3, afrag[0][3], acc0, 0, 0, 0);
        acc1 = __builtin_amdgcn_mfma_f32_16x16x32_bf16(b3, afrag[1][3], acc1, 0, 0, 0);

        int c0 = ct * 16 + cq;
        if (ct < 32) {
            unsigned short* dst; int c; const float* bv;
            if (ct < 16) { dst = xl; c = c0;       bv = bl; }
            else         { dst = xr; c = c0 - 256; bv = br; }
            float4 bb = *(const float4*)(bv + c);
            if (v0) {
                ushort4 u = make_ushort4(f2h_bits(acc0[0] + bb.x), f2h_bits(acc0[1] + bb.y),
                                         f2h_bits(acc0[2] + bb.z), f2h_bits(acc0[3] + bb.w));
                *(ushort4*)(dst + (size_t)node0 * 256 + c) = u;
            }
            if (v1) {
                ushort4 u = make_ushort4(f2h_bits(acc1[0] + bb.x), f2h_bits(acc1[1] + bb.y),
                                         f2h_bits(acc1[2] + bb.z), f2h_bits(acc1[3] + bb.w));
                *(ushort4*)(dst + (size_t)node1 * 256 + c) = u;
            }
        } else {
            int c = c0 - 512;
            float4 bb = *(const float4*)(bias + c);
            if (v0) {
                float4 xv = *(const float4*)(x + (size_t)node0 * DCH + c);
                float4 o = make_float4(acc0[0] + bb.x + xv.x, acc0[1] + bb.y + xv.y,
                                       acc0[2] + bb.z + xv.z, acc0[3] + bb.w + xv.w);
                *(float4*)(out + (size_t)node0 * DCH + c) = o;
            }
            if (v1) {
                float4 xv = *(const float4*)(x + (size_t)node1 * DCH + c);
                float4 o = make_float4(acc1[0] + bb.x + xv.x, acc1[1] + bb.y + xv.y,
                                       acc1[2] + bb.z + xv.z, acc1[3] + bb.w + xv.w);
                *(float4*)(out + (size_t)node1 * DCH + c) = o;
            }
        }
    }
}

// --------------------------------------------------------------- CSR build
__global__ void hist_dst(const int* __restrict__ dst, int* __restrict__ cnt, int E) {
    int i = blockIdx.x * blockDim.x + threadIdx.x;
    int E4 = E >> 2;
    if (i < E4) {
        int4 d = ((const int4*)dst)[i];
        atomicAdd(&cnt[d.x], 1); atomicAdd(&cnt[d.y], 1);
        atomicAdd(&cnt[d.z], 1); atomicAdd(&cnt[d.w], 1);
    }
    if (i < (E & 3)) atomicAdd(&cnt[dst[E4 * 4 + i]], 1);
}

__global__ void scan_block(const int* __restrict__ cnt, int* __restrict__ offs,
                           int* __restrict__ bsum, int n) {
    __shared__ int sm[256];
    int t = threadIdx.x;
    int i = blockIdx.x * 256 + t;
    int v = (i < n) ? cnt[i] : 0;
    sm[t] = v;
    __syncthreads();
#pragma unroll
    for (int d = 1; d < 256; d <<= 1) {
        int add = (t >= d) ? sm[t - d] : 0;
        __syncthreads();
        sm[t] += add;
        __syncthreads();
    }
    if (i < n) offs[i] = sm[t] - v;
    if (t == 255) bsum[blockIdx.x] = sm[t];
}

__global__ void scan_bsum_par(int* __restrict__ bsum, int nb) {
    __shared__ int sm[512];
    int t = threadIdx.x;
    if (nb <= 512) {
        int v = (t < nb) ? bsum[t] : 0;
        sm[t] = v;
        __syncthreads();
#pragma unroll
        for (int d = 1; d < 512; d <<= 1) {
            int add = (t >= d) ? sm[t - d] : 0;
            __syncthreads();
            sm[t] += add;
            __syncthreads();
        }
        if (t < nb) bsum[t] = sm[t] - v;
    } else if (t == 0) {
        int acc = 0;
        for (int i = 0; i < nb; ++i) { int v = bsum[i]; bsum[i] = acc; acc += v; }
    }
}

__global__ void scan_add(int* __restrict__ offs, int* __restrict__ fillc,
                         const int* __restrict__ bsum, int n, int E) {
    int i = blockIdx.x * 256 + threadIdx.x;
    if (i < n) {
        int v = offs[i] + bsum[blockIdx.x];
        offs[i]  = v;
        fillc[i] = v;
    }
    if (i == 0) offs[n] = E;
}

// --------------- single-pass fused attention + softmax + aggregation (f16)
// One wave per dst node t; lane-local per-head online (m,z) + defer-max.
// Software-pipelined edge loop: group j+4's indices and xl gathers issue
// while group j computes (hides L2/L3 gather latency).
__launch_bounds__(256)
__global__ void gat_aggregate(const int* __restrict__ offs, const int* __restrict__ sbuf,
                              const unsigned short* __restrict__ xl_,
                              const unsigned short* __restrict__ xr_,
                              const float* __restrict__ att,
                              float* __restrict__ out, int n) {
    const _Float16* xl = (const _Float16*)xl_;
    const _Float16* xr = (const _Float16*)xr_;
    int lane = threadIdx.x & 63;
    int wid  = __builtin_amdgcn_readfirstlane((blockIdx.x * blockDim.x + threadIdx.x) >> 6);
    int nw   = (gridDim.x * blockDim.x) >> 6;

    const float LOG2E = 1.4426950408889634f;
    float4 af = *(const float4*)(att + lane * 4);   // flat[256]: lanes 0..31 head0
    h2 av0 = {(_Float16)(af.x * LOG2E), (_Float16)(af.y * LOG2E)};
    h2 av1 = {(_Float16)(af.z * LOG2E), (_Float16)(af.w * LOG2E)};
    h2 ns  = {(_Float16)NEG_SLOPE, (_Float16)NEG_SLOPE};

    for (int t = wid; t < n; t += nw) {
        int beg = offs[t];
        int end = offs[t + 1];
        if (beg == end) continue;
        h4 r4 = *(const h4*)(xr + (size_t)t * 256 + lane * 4);
        h2 r0 = __builtin_shufflevector(r4, r4, 0, 1);
        h2 r1 = __builtin_shufflevector(r4, r4, 2, 3);

        float m = -INFINITY, z = 0.f;            // per-lane: own head's state
        float4 acc = make_float4(0.f, 0.f, 0.f, 0.f);

        auto process4 = [&](h4 l0, h4 l1, h4 l2, h4 l3) {
            float p0 = dot4h(lrelu2(__builtin_shufflevector(l0, l0, 0, 1) + r0, ns),
                             lrelu2(__builtin_shufflevector(l0, l0, 2, 3) + r1, ns), av0, av1);
            float p1 = dot4h(lrelu2(__builtin_shufflevector(l1, l1, 0, 1) + r0, ns),
                             lrelu2(__builtin_shufflevector(l1, l1, 2, 3) + r1, ns), av0, av1);
            float p2 = dot4h(lrelu2(__builtin_shufflevector(l2, l2, 0, 1) + r0, ns),
                             lrelu2(__builtin_shufflevector(l2, l2, 2, 3) + r1, ns), av0, av1);
            float p3 = dot4h(lrelu2(__builtin_shufflevector(l3, l3, 0, 1) + r0, ns),
                             lrelu2(__builtin_shufflevector(l3, l3, 2, 3) + r1, ns), av0, av1);
            p0 = halfsum(p0); p1 = halfsum(p1); p2 = halfsum(p2); p3 = halfsum(p3);
            float pm = fmaxf(fmaxf(p0, p1), fmaxf(p2, p3));
            if (__any(pm - m > 11.5f)) {
                float mn = fmaxf(m, pm);
                float sc = __builtin_amdgcn_exp2f(m - mn);   // 0 on first group
                z *= sc;
                acc.x *= sc; acc.y *= sc; acc.z *= sc; acc.w *= sc;
                m = mn;
            }
            float w0 = __builtin_amdgcn_exp2f(p0 - m);
            float w1 = __builtin_amdgcn_exp2f(p1 - m);
            float w2 = __builtin_amdgcn_exp2f(p2 - m);
            float w3 = __builtin_amdgcn_exp2f(p3 - m);
            z += (w0 + w1) + (w2 + w3);
            acc.x = fmaf((float)l0[0], w0, acc.x); acc.y = fmaf((float)l0[1], w0, acc.y);
            acc.z = fmaf((float)l0[2], w0, acc.z); acc.w = fmaf((float)l0[3], w0, acc.w);
            acc.x = fmaf((float)l1[0], w1, acc.x); acc.y = fmaf((float)l1[1], w1, acc.y);
            acc.z = fmaf((float)l1[2], w1, acc.z); acc.w = fmaf((float)l1[3], w1, acc.w);
            acc.x = fmaf((float)l2[0], w2, acc.x); acc.y = fmaf((float)l2[1], w2, acc.y);
            acc.z = fmaf((float)l2[2], w2, acc.z); acc.w = fmaf((float)l2[3], w2, acc.w);
            acc.x = fmaf((float)l3[0], w3, acc.x); acc.y = fmaf((float)l3[1], w3, acc.y);
            acc.z = fmaf((float)l3[2], w3, acc.z); acc.w = fmaf((float)l3[3], w3, acc.w);
        };

        int j = beg;
        h4 c0, c1, c2, c3;
        bool have = (j + 4 <= end);
        if (have) {
            int s0 = sbuf[j], s1 = sbuf[j + 1], s2 = sbuf[j + 2], s3 = sbuf[j + 3];
            c0 = *(const h4*)(xl + (size_t)s0 * 256 + lane * 4);
            c1 = *(const h4*)(xl + (size_t)s1 * 256 + lane * 4);
            c2 = *(const h4*)(xl + (size_t)s2 * 256 + lane * 4);
            c3 = *(const h4*)(xl + (size_t)s3 * 256 + lane * 4);
        }
        for (; j + 8 <= end; j += 4) {
            // prefetch next group while current computes
            int s0 = sbuf[j + 4], s1 = sbuf[j + 5], s2 = sbuf[j + 6], s3 = sbuf[j + 7];
            h4 n0 = *(const h4*)(xl + (size_t)s0 * 256 + lane * 4);
            h4 n1 = *(const h4*)(xl + (size_t)s1 * 256 + lane * 4);
            h4 n2 = *(const h4*)(xl + (size_t)s2 * 256 + lane * 4);
            h4 n3 = *(const h4*)(xl + (size_t)s3 * 256 + lane * 4);
            process4(c0, c1, c2, c3);
            c0 = n0; c1 = n1; c2 = n2; c3 = n3;
        }
        if (have) { process4(c0, c1, c2, c3); j += 4; }
        for (; j < end; ++j) {                   // tail (0..3 edges)
            int s = sbuf[j];
            h4 l0 = *(const h4*)(xl + (size_t)s * 256 + lane * 4);
            float p = dot4h(lrelu2(__builtin_shufflevector(l0, l0, 0, 1) + r0, ns),
                            lrelu2(__builtin_shufflevector(l0, l0, 2, 3) + r1, ns), av0, av1);
            p = halfsum(p);
            if (__any(p - m > 11.5f)) {
                float mn = fmaxf(m, p);
                float sc = __builtin_amdgcn_exp2f(m - mn);
                z *= sc;
                acc.x *= sc; acc.y *= sc; acc.z *= sc; acc.w *= sc;
                m = mn;
            }
            float w = __builtin_amdgcn_exp2f(p - m);
            z += w;
            acc.x = fmaf((float)l0[0], w, acc.x); acc.y = fmaf((float)l0[1], w, acc.y);
            acc.z = fmaf((float)l0[2], w, acc.z); acc.w = fmaf((float)l0[3], w, acc.w);
        }
        float inv = 0.5f / (z + 1e-16f);         // z uniform within each half
        acc.x *= inv; acc.y *= inv; acc.z *= inv; acc.w *= inv;
        // head mean: lane L (<32) += lane L+32 (same channels, head 1)
        acc.x += __shfl_xor(acc.x, 32);
        acc.y += __shfl_xor(acc.y, 32);
        acc.z += __shfl_xor(acc.z, 32);
        acc.w += __shfl_xor(acc.w, 32);
        if (lane < 32) {
            float4* o = (float4*)(out + (size_t)t * DCH + lane * 4);
            float4 cur = *o;
            cur.x += acc.x; cur.y += acc.y; cur.z += acc.z; cur.w += acc.w;
            *o = cur;
        }
    }
}

// --------------------------------------------------------------------- launch
extern "C" void kernel_launch(void* const* d_in, const int* in_sizes, int n_in,
                              void* d_out, int out_size, void* d_ws, size_t ws_size,
                              hipStream_t stream) {
    const float* x     = (const float*)d_in[0];
    const int*   ei    = (const int*)d_in[1];
    const float* gamma = (const float*)d_in[2];
    const float* beta  = (const float*)d_in[3];
    const float* Wl    = (const float*)d_in[4];
    const float* bl    = (const float*)d_in[5];
    const float* Wr    = (const float*)d_in[6];
    const float* br    = (const float*)d_in[7];
    const float* att   = (const float*)d_in[8];
    const float* resW  = (const float*)d_in[9];
    const float* bias  = (const float*)d_in[10];
    float* out = (float*)d_out;

    int n = in_sizes[0] / DCH;
    int E = in_sizes[1] / 2;
    const int* src = ei;
    const int* dstIdx = ei + E;

    char* ws = (char*)d_ws;
    size_t off = 0;
    auto alloc = [&](size_t bytes) -> void* {
        void* p = ws + off;
        off = (off + bytes + 255) & ~(size_t)255;
        return p;
    };

    int nb = (n + 255) / 256;

    unsigned short* xl = (unsigned short*)alloc((size_t)n * 256 * 2);  // 51.2 MB
    unsigned short* xr = (unsigned short*)alloc((size_t)n * 256 * 2);  // 51.2 MB
    unsigned short* wfrag = (unsigned short*)alloc(160 * 64 * 8 * 2);  // 160 KB
    int* cnt   = (int*)alloc((size_t)n * 4);
    int* offs  = (int*)alloc((size_t)(n + 1) * 4);
    int* bsum  = (int*)alloc((size_t)nb * 4);
    int* fillc = (int*)alloc((size_t)n * 4);
    int* sbuf  = (int*)alloc((size_t)E * 4);                           // 6.4 MB

    prep_and_zero<<<40 + nb, 256, 0, stream>>>(Wl, Wr, resW, wfrag, cnt, n);
    int ethr = (E / 4 + 255) / 256 + 1;
    hist_dst<<<ethr, 256, 0, stream>>>(dstIdx, cnt, E);
    scan_block<<<nb, 256, 0, stream>>>(cnt, offs, bsum, n);
    scan_bsum_par<<<1, 512, 0, stream>>>(bsum, nb);
    scan_add<<<nb, 256, 0, stream>>>(offs, fillc, bsum, n, E);

    int nrb = (n + 127) / 128;
    gemm_fill<<<nrb + ethr, 256, 0, stream>>>(x, gamma, beta, wfrag, bl, br, bias,
                                              xl, xr, out, n,
                                              src, dstIdx, fillc, sbuf, E, nrb);
    gat_aggregate<<<2048, 256, 0, stream>>>(offs, sbuf, xl, xr, att, out, n);
}

// Round 10
// 324.797 us; speedup vs baseline: 7.4165x; 1.0772x over previous
//
#include <hip/hip_runtime.h>
#include <hip/hip_bf16.h>
#include <cstdint>
#include <cstddef>

#define DCH 128
#define NHEADS 2
#define NEG_SLOPE 0.2f

typedef __attribute__((ext_vector_type(8))) short short8v;
typedef __attribute__((ext_vector_type(4))) float f32x4;
typedef _Float16 h2 __attribute__((ext_vector_type(2)));
typedef _Float16 h4 __attribute__((ext_vector_type(4)));

// ---------------------------------------------------------------- utilities
__device__ __forceinline__ unsigned short f2bf(float f) {
    union { float f; unsigned int i; } v; v.f = f;
    unsigned int r = v.i + 0x7fffu + ((v.i >> 16) & 1u);   // RNE
    return (unsigned short)(r >> 16);
}
__device__ __forceinline__ unsigned short f2h_bits(float f) {
    _Float16 h = (_Float16)f;
    union { _Float16 h; unsigned short u; } v; v.h = h; return v.u;
}

__device__ __forceinline__ h2 lrelu2(h2 v, h2 ns) {
    h2 f = v * ns;
#if __has_builtin(__builtin_elementwise_max)
    return __builtin_elementwise_max(v, f);
#else
    h2 r; r[0] = v[0] > f[0] ? v[0] : f[0]; r[1] = v[1] > f[1] ? v[1] : f[1];
    return r;
#endif
}
__device__ __forceinline__ float dot4h(h2 a0, h2 a1, h2 b0, h2 b1) {
#if __has_builtin(__builtin_amdgcn_fdot2)
    return __builtin_amdgcn_fdot2(a0, b0, __builtin_amdgcn_fdot2(a1, b1, 0.f, false), false);
#else
    return (float)a0[0]*(float)b0[0] + (float)a0[1]*(float)b0[1]
         + (float)a1[0]*(float)b1[0] + (float)a1[1]*(float)b1[1];
#endif
}

// 32-lane-half sum via DPP row_ror + one ds_swizzle (xor16).
__device__ __forceinline__ float halfsum(float p) {
    p += __int_as_float(__builtin_amdgcn_update_dpp(
            0, __float_as_int(p), 0x121, 0xF, 0xF, false));  // row_ror:1
    p += __int_as_float(__builtin_amdgcn_update_dpp(
            0, __float_as_int(p), 0x122, 0xF, 0xF, false));  // row_ror:2
    p += __int_as_float(__builtin_amdgcn_update_dpp(
            0, __float_as_int(p), 0x124, 0xF, 0xF, false));  // row_ror:4
    p += __int_as_float(__builtin_amdgcn_update_dpp(
            0, __float_as_int(p), 0x128, 0xF, 0xF, false));  // row_ror:8
    p += __int_as_float(__builtin_amdgcn_ds_swizzle(
            __float_as_int(p), 0x401F));                     // lane ^= 16
    return p;
}

// ------------------------------- merged: weights->bf16 fragments + zero cnt
__global__ void prep_and_zero(const float* __restrict__ Wl, const float* __restrict__ Wr,
                              const float* __restrict__ resW,
                              unsigned short* __restrict__ wfrag,
                              int* __restrict__ cnt, int n) {
    if (blockIdx.x >= 40) {
        int i = (blockIdx.x - 40) * 256 + threadIdx.x;
        if (i < n) cnt[i] = 0;
        return;
    }
    int gid  = blockIdx.x * 256 + threadIdx.x;   // 10240 threads
    int lane = gid & 63;
    int f    = gid >> 6;                          // 0..159
    int ks   = f & 3;
    int ct   = f >> 2;
    int col  = ct * 16 + (lane & 15);
    int k0   = ks * 32 + (lane >> 4) * 8;
    const float* W; int ldB, c;
    if (col < 256)      { W = Wl;   ldB = 256; c = col; }
    else if (col < 512) { W = Wr;   ldB = 256; c = col - 256; }
    else                { W = resW; ldB = 128; c = col - 512; }
    unsigned short tmp[8];
#pragma unroll
    for (int j = 0; j < 8; ++j) tmp[j] = f2bf(W[(size_t)(k0 + j) * ldB + c]);
    ushort4* dst = (ushort4*)(wfrag + (size_t)gid * 8);
    dst[0] = make_ushort4(tmp[0], tmp[1], tmp[2], tmp[3]);
    dst[1] = make_ushort4(tmp[4], tmp[5], tmp[6], tmp[7]);
}

// ------- combined dispatch: blocks [0,nrb) = LN+MFMA GEMM, rest = fill_csr
// GEMM outputs staged in LDS (32KB, aliases the A tile) and flushed as
// full-line contiguous row segments -> no partial-line write amplification.
__launch_bounds__(256)
__global__ void gemm_fill(const float* __restrict__ x,
                          const float* __restrict__ gamma, const float* __restrict__ beta,
                          const unsigned short* __restrict__ wfrag,
                          const float* __restrict__ bl, const float* __restrict__ br,
                          const float* __restrict__ bias,
                          unsigned short* __restrict__ xl, unsigned short* __restrict__ xr,
                          float* __restrict__ out, int n,
                          const int* __restrict__ srcIdx, const int* __restrict__ dstIdx,
                          int* __restrict__ fillc, int* __restrict__ sbuf, int E, int nrb) {
    __shared__ __align__(16) unsigned char smem[128 * 256];  // 32 KB (As / stage)

    if ((int)blockIdx.x >= nrb) {
        // ---------------- fill_csr part
        int i = (blockIdx.x - nrb) * 256 + threadIdx.x;
        int E4 = E >> 2;
        if (i < E4) {
            int4 d = ((const int4*)dstIdx)[i];
            int4 s = ((const int4*)srcIdx)[i];
            sbuf[atomicAdd(&fillc[d.x], 1)] = s.x;
            sbuf[atomicAdd(&fillc[d.y], 1)] = s.y;
            sbuf[atomicAdd(&fillc[d.z], 1)] = s.z;
            sbuf[atomicAdd(&fillc[d.w], 1)] = s.w;
        }
        if (i < (E & 3)) {
            int e = E4 * 4 + i;
            sbuf[atomicAdd(&fillc[dstIdx[e]], 1)] = srcIdx[e];
        }
        return;
    }

    // ---------------- GEMM part
    int row0 = blockIdx.x * 128;
    int tid  = threadIdx.x;
    unsigned short* As = (unsigned short*)smem;

    // stage A with fused LayerNorm+ReLU (bf16, XOR-swizzled)
    {
        int r  = tid >> 5;            // 0..7
        int k4 = (tid & 31) * 4;      // 0,4,...,124
        float4 g4  = *(const float4*)(gamma + k4);
        float4 be4 = *(const float4*)(beta + k4);
#pragma unroll
        for (int i = 0; i < 16; ++i) {
            int row  = r + i * 8;
            int grow = row0 + row;
            float4 a = (grow < n) ? *(const float4*)(x + (size_t)grow * DCH + k4)
                                  : make_float4(0.f, 0.f, 0.f, 0.f);
            float s  = a.x + a.y + a.z + a.w;
            float sq = a.x * a.x + a.y * a.y + a.z * a.z + a.w * a.w;
#pragma unroll
            for (int msk = 16; msk; msk >>= 1) {
                s  += __shfl_xor(s, msk);
                sq += __shfl_xor(sq, msk);
            }
            float mu = s * (1.f / DCH);
            float rs = rsqrtf(sq * (1.f / DCH) - mu * mu + 1e-5f);
            ushort4 u;
            u.x = f2bf(fmaxf((a.x - mu) * rs * g4.x + be4.x, 0.f));
            u.y = f2bf(fmaxf((a.y - mu) * rs * g4.y + be4.y, 0.f));
            u.z = f2bf(fmaxf((a.z - mu) * rs * g4.z + be4.z, 0.f));
            u.w = f2bf(fmaxf((a.w - mu) * rs * g4.w + be4.w, 0.f));
            int byteoff = row * 256 + ((k4 * 2) ^ ((row & 7) << 4));
            *(ushort4*)((char*)As + byteoff) = u;
        }
    }
    __syncthreads();

    int wv = tid >> 6, lane = tid & 63;

    short8v afrag[2][4];
#pragma unroll
    for (int g = 0; g < 2; ++g) {
        int arow = wv * 32 + g * 16 + (lane & 15);
#pragma unroll
        for (int ks = 0; ks < 4; ++ks) {
            int kbyte = (ks * 64 + (lane >> 4) * 16) ^ ((arow & 7) << 4);
            afrag[g][ks] = *(const short8v*)((const char*)As + arow * 256 + kbyte);
        }
    }
    __syncthreads();   // all fragment reads done; smem is now the stage buffer

    int nodeL0 = wv * 32 + (lane & 15);      // local node, group 0 (0..127)
    int nodeL1 = nodeL0 + 16;                // group 1
    int cq = (lane >> 4) << 2;               // column quad 0,4,8,12

    // one MFMA column-tile: 4 B-fragment loads + 8 MFMA into acc0/acc1
    auto mfma_ct = [&](int ct, f32x4& a0, f32x4& a1) {
        const unsigned short* bp = wfrag + ((size_t)(ct * 4) * 64 + lane) * 8;
        short8v b0 = *(const short8v*)(bp);
        short8v b1 = *(const short8v*)(bp + 64 * 8);
        short8v b2 = *(const short8v*)(bp + 128 * 8);
        short8v b3 = *(const short8v*)(bp + 192 * 8);
        a0 = __builtin_amdgcn_mfma_f32_16x16x32_bf16(b0, afrag[0][0], a0, 0, 0, 0);
        a1 = __builtin_amdgcn_mfma_f32_16x16x32_bf16(b0, afrag[1][0], a1, 0, 0, 0);
        a0 = __builtin_amdgcn_mfma_f32_16x16x32_bf16(b1, afrag[0][1], a0, 0, 0, 0);
        a1 = __builtin_amdgcn_mfma_f32_16x16x32_bf16(b1, afrag[1][1], a1, 0, 0, 0);
        a0 = __builtin_amdgcn_mfma_f32_16x16x32_bf16(b2, afrag[0][2], a0, 0, 0, 0);
        a1 = __builtin_amdgcn_mfma_f32_16x16x32_bf16(b2, afrag[1][2], a1, 0, 0, 0);
        a0 = __builtin_amdgcn_mfma_f32_16x16x32_bf16(b3, afrag[0][3], a0, 0, 0, 0);
        a1 = __builtin_amdgcn_mfma_f32_16x16x32_bf16(b3, afrag[1][3], a1, 0, 0, 0);
    };

    // ---- xl / xr: 4 flush-groups of 8 cts; stage = [128 nodes][128 cols] f16
    for (int fg = 0; fg < 4; ++fg) {
        unsigned short* dstG = (fg < 2) ? xl : xr;
        const float* bv      = (fg < 2) ? bl : br;
        int half = fg & 1;                      // which 128-col half of 256
#pragma unroll
        for (int ctl = 0; ctl < 8; ++ctl) {
            int ct = fg * 8 + ctl;
            f32x4 acc0 = {0.f, 0.f, 0.f, 0.f};
            f32x4 acc1 = {0.f, 0.f, 0.f, 0.f};
            mfma_ct(ct, acc0, acc1);
            int c = ct * 16 + cq - ((fg < 2) ? 0 : 256);   // col in [0,256)
            float4 bb = *(const float4*)(bv + c);
            int cb = ctl * 32 + cq * 2;                    // byte in [0,256)
            ushort4 u0 = make_ushort4(f2h_bits(acc0[0] + bb.x), f2h_bits(acc0[1] + bb.y),
                                      f2h_bits(acc0[2] + bb.z), f2h_bits(acc0[3] + bb.w));
            *(ushort4*)(smem + nodeL0 * 256 + (cb ^ ((nodeL0 & 7) << 4))) = u0;
            ushort4 u1 = make_ushort4(f2h_bits(acc1[0] + bb.x), f2h_bits(acc1[1] + bb.y),
                                      f2h_bits(acc1[2] + bb.z), f2h_bits(acc1[3] + bb.w));
            *(ushort4*)(smem + nodeL1 * 256 + (cb ^ ((nodeL1 & 7) << 4))) = u1;
        }
        __syncthreads();
#pragma unroll
        for (int it = 0; it < 8; ++it) {        // flush 32KB, full-line stores
            int chunk = it * 256 + tid;
            int row  = chunk >> 4;
            int colb = (chunk & 15) * 16;
            int grow = row0 + row;
            if (grow < n) {
                int4 v = *(const int4*)(smem + row * 256 + (colb ^ ((row & 7) << 4)));
                *(int4*)((char*)dstG + (size_t)grow * 512 + half * 256 + colb) = v;
            }
        }
        __syncthreads();
    }

    // ---- out: 2 flush-groups of 4 cts; stage = [128 rows][64 cols] f32
    for (int fg = 0; fg < 2; ++fg) {
#pragma unroll
        for (int ctl = 0; ctl < 4; ++ctl) {
            int ct = 32 + fg * 4 + ctl;
            f32x4 acc0 = {0.f, 0.f, 0.f, 0.f};
            f32x4 acc1 = {0.f, 0.f, 0.f, 0.f};
            mfma_ct(ct, acc0, acc1);
            int c = ct * 16 + cq - 512;                    // col in [0,128)
            float4 bb = *(const float4*)(bias + c);
            int cb = ctl * 64 + cq * 4;                    // byte in [0,256)
            float4 w0 = make_float4(acc0[0] + bb.x, acc0[1] + bb.y,
                                    acc0[2] + bb.z, acc0[3] + bb.w);
            *(float4*)(smem + nodeL0 * 256 + (cb ^ ((nodeL0 & 7) << 4))) = w0;
            float4 w1 = make_float4(acc1[0] + bb.x, acc1[1] + bb.y,
                                    acc1[2] + bb.z, acc1[3] + bb.w);
            *(float4*)(smem + nodeL1 * 256 + (cb ^ ((nodeL1 & 7) << 4))) = w1;
        }
        __syncthreads();
#pragma unroll
        for (int it = 0; it < 8; ++it) {        // flush 32KB, + residual x
            int chunk = it * 256 + tid;
            int row  = chunk >> 4;
            int colb = (chunk & 15) * 16;
            int grow = row0 + row;
            if (grow < n) {
                float4 v = *(const float4*)(smem + row * 256 + (colb ^ ((row & 7) << 4)));
                float4 xv = *(const float4*)((const char*)x + (size_t)grow * 512 + fg * 256 + colb);
                v.x += xv.x; v.y += xv.y; v.z += xv.z; v.w += xv.w;
                *(float4*)((char*)out + (size_t)grow * 512 + fg * 256 + colb) = v;
            }
        }
        __syncthreads();
    }
}

// --------------------------------------------------------------- CSR build
__global__ void hist_dst(const int* __restrict__ dst, int* __restrict__ cnt, int E) {
    int i = blockIdx.x * blockDim.x + threadIdx.x;
    int E4 = E >> 2;
    if (i < E4) {
        int4 d = ((const int4*)dst)[i];
        atomicAdd(&cnt[d.x], 1); atomicAdd(&cnt[d.y], 1);
        atomicAdd(&cnt[d.z], 1); atomicAdd(&cnt[d.w], 1);
    }
    if (i < (E & 3)) atomicAdd(&cnt[dst[E4 * 4 + i]], 1);
}

__global__ void scan_block(const int* __restrict__ cnt, int* __restrict__ offs,
                           int* __restrict__ bsum, int n) {
    __shared__ int sm[256];
    int t = threadIdx.x;
    int i = blockIdx.x * 256 + t;
    int v = (i < n) ? cnt[i] : 0;
    sm[t] = v;
    __syncthreads();
#pragma unroll
    for (int d = 1; d < 256; d <<= 1) {
        int add = (t >= d) ? sm[t - d] : 0;
        __syncthreads();
        sm[t] += add;
        __syncthreads();
    }
    if (i < n) offs[i] = sm[t] - v;
    if (t == 255) bsum[blockIdx.x] = sm[t];
}

__global__ void scan_bsum_par(int* __restrict__ bsum, int nb) {
    __shared__ int sm[512];
    int t = threadIdx.x;
    if (nb <= 512) {
        int v = (t < nb) ? bsum[t] : 0;
        sm[t] = v;
        __syncthreads();
#pragma unroll
        for (int d = 1; d < 512; d <<= 1) {
            int add = (t >= d) ? sm[t - d] : 0;
            __syncthreads();
            sm[t] += add;
            __syncthreads();
        }
        if (t < nb) bsum[t] = sm[t] - v;
    } else if (t == 0) {
        int acc = 0;
        for (int i = 0; i < nb; ++i) { int v = bsum[i]; bsum[i] = acc; acc += v; }
    }
}

__global__ void scan_add(int* __restrict__ offs, int* __restrict__ fillc,
                         const int* __restrict__ bsum, int n, int E) {
    int i = blockIdx.x * 256 + threadIdx.x;
    if (i < n) {
        int v = offs[i] + bsum[blockIdx.x];
        offs[i]  = v;
        fillc[i] = v;
    }
    if (i == 0) offs[n] = E;
}

// --------------- single-pass fused attention + softmax + aggregation (f16)
// One wave per dst node t; lane-local per-head online (m,z) + defer-max;
// software-pipelined 4-edge groups (next group's gathers issue during compute).
__launch_bounds__(256)
__global__ void gat_aggregate(const int* __restrict__ offs, const int* __restrict__ sbuf,
                              const unsigned short* __restrict__ xl_,
                              const unsigned short* __restrict__ xr_,
                              const float* __restrict__ att,
                              float* __restrict__ out, int n) {
    const _Float16* xl = (const _Float16*)xl_;
    const _Float16* xr = (const _Float16*)xr_;
    int lane = threadIdx.x & 63;
    int wid  = __builtin_amdgcn_readfirstlane((blockIdx.x * blockDim.x + threadIdx.x) >> 6);
    int nw   = (gridDim.x * blockDim.x) >> 6;

    const float LOG2E = 1.4426950408889634f;
    float4 af = *(const float4*)(att + lane * 4);   // flat[256]: lanes 0..31 head0
    h2 av0 = {(_Float16)(af.x * LOG2E), (_Float16)(af.y * LOG2E)};
    h2 av1 = {(_Float16)(af.z * LOG2E), (_Float16)(af.w * LOG2E)};
    h2 ns  = {(_Float16)NEG_SLOPE, (_Float16)NEG_SLOPE};

    for (int t = wid; t < n; t += nw) {
        int beg = offs[t];
        int end = offs[t + 1];
        if (beg == end) continue;
        h4 r4 = *(const h4*)(xr + (size_t)t * 256 + lane * 4);
        h2 r0 = __builtin_shufflevector(r4, r4, 0, 1);
        h2 r1 = __builtin_shufflevector(r4, r4, 2, 3);

        float m = -INFINITY, z = 0.f;
        float4 acc = make_float4(0.f, 0.f, 0.f, 0.f);

        auto process4 = [&](h4 l0, h4 l1, h4 l2, h4 l3) {
            float p0 = dot4h(lrelu2(__builtin_shufflevector(l0, l0, 0, 1) + r0, ns),
                             lrelu2(__builtin_shufflevector(l0, l0, 2, 3) + r1, ns), av0, av1);
            float p1 = dot4h(lrelu2(__builtin_shufflevector(l1, l1, 0, 1) + r0, ns),
                             lrelu2(__builtin_shufflevector(l1, l1, 2, 3) + r1, ns), av0, av1);
            float p2 = dot4h(lrelu2(__builtin_shufflevector(l2, l2, 0, 1) + r0, ns),
                             lrelu2(__builtin_shufflevector(l2, l2, 2, 3) + r1, ns), av0, av1);
            float p3 = dot4h(lrelu2(__builtin_shufflevector(l3, l3, 0, 1) + r0, ns),
                             lrelu2(__builtin_shufflevector(l3, l3, 2, 3) + r1, ns), av0, av1);
            p0 = halfsum(p0); p1 = halfsum(p1); p2 = halfsum(p2); p3 = halfsum(p3);
            float pm = fmaxf(fmaxf(p0, p1), fmaxf(p2, p3));
            if (__any(pm - m > 11.5f)) {
                float mn = fmaxf(m, pm);
                float sc = __builtin_amdgcn_exp2f(m - mn);   // 0 on first group
                z *= sc;
                acc.x *= sc; acc.y *= sc; acc.z *= sc; acc.w *= sc;
                m = mn;
            }
            float w0 = __builtin_amdgcn_exp2f(p0 - m);
            float w1 = __builtin_amdgcn_exp2f(p1 - m);
            float w2 = __builtin_amdgcn_exp2f(p2 - m);
            float w3 = __builtin_amdgcn_exp2f(p3 - m);
            z += (w0 + w1) + (w2 + w3);
            acc.x = fmaf((float)l0[0], w0, acc.x); acc.y = fmaf((float)l0[1], w0, acc.y);
            acc.z = fmaf((float)l0[2], w0, acc.z); acc.w = fmaf((float)l0[3], w0, acc.w);
            acc.x = fmaf((float)l1[0], w1, acc.x); acc.y = fmaf((float)l1[1], w1, acc.y);
            acc.z = fmaf((float)l1[2], w1, acc.z); acc.w = fmaf((float)l1[3], w1, acc.w);
            acc.x = fmaf((float)l2[0], w2, acc.x); acc.y = fmaf((float)l2[1], w2, acc.y);
            acc.z = fmaf((float)l2[2], w2, acc.z); acc.w = fmaf((float)l2[3], w2, acc.w);
            acc.x = fmaf((float)l3[0], w3, acc.x); acc.y = fmaf((float)l3[1], w3, acc.y);
            acc.z = fmaf((float)l3[2], w3, acc.z); acc.w = fmaf((float)l3[3], w3, acc.w);
        };

        int j = beg;
        h4 c0, c1, c2, c3;
        bool have = (j + 4 <= end);
        if (have) {
            int s0 = sbuf[j], s1 = sbuf[j + 1], s2 = sbuf[j + 2], s3 = sbuf[j + 3];
            c0 = *(const h4*)(xl + (size_t)s0 * 256 + lane * 4);
            c1 = *(const h4*)(xl + (size_t)s1 * 256 + lane * 4);
            c2 = *(const h4*)(xl + (size_t)s2 * 256 + lane * 4);
            c3 = *(const h4*)(xl + (size_t)s3 * 256 + lane * 4);
        }
        for (; j + 8 <= end; j += 4) {
            int s0 = sbuf[j + 4], s1 = sbuf[j + 5], s2 = sbuf[j + 6], s3 = sbuf[j + 7];
            h4 n0 = *(const h4*)(xl + (size_t)s0 * 256 + lane * 4);
            h4 n1 = *(const h4*)(xl + (size_t)s1 * 256 + lane * 4);
            h4 n2 = *(const h4*)(xl + (size_t)s2 * 256 + lane * 4);
            h4 n3 = *(const h4*)(xl + (size_t)s3 * 256 + lane * 4);
            process4(c0, c1, c2, c3);
            c0 = n0; c1 = n1; c2 = n2; c3 = n3;
        }
        if (have) { process4(c0, c1, c2, c3); j += 4; }
        for (; j < end; ++j) {
            int s = sbuf[j];
            h4 l0 = *(const h4*)(xl + (size_t)s * 256 + lane * 4);
            float p = dot4h(lrelu2(__builtin_shufflevector(l0, l0, 0, 1) + r0, ns),
                            lrelu2(__builtin_shufflevector(l0, l0, 2, 3) + r1, ns), av0, av1);
            p = halfsum(p);
            if (__any(p - m > 11.5f)) {
                float mn = fmaxf(m, p);
                float sc = __builtin_amdgcn_exp2f(m - mn);
                z *= sc;
                acc.x *= sc; acc.y *= sc; acc.z *= sc; acc.w *= sc;
                m = mn;
            }
            float w = __builtin_amdgcn_exp2f(p - m);
            z += w;
            acc.x = fmaf((float)l0[0], w, acc.x); acc.y = fmaf((float)l0[1], w, acc.y);
            acc.z = fmaf((float)l0[2], w, acc.z); acc.w = fmaf((float)l0[3], w, acc.w);
        }
        float inv = 0.5f / (z + 1e-16f);
        acc.x *= inv; acc.y *= inv; acc.z *= inv; acc.w *= inv;
        acc.x += __shfl_xor(acc.x, 32);
        acc.y += __shfl_xor(acc.y, 32);
        acc.z += __shfl_xor(acc.z, 32);
        acc.w += __shfl_xor(acc.w, 32);
        if (lane < 32) {
            float4* o = (float4*)(out + (size_t)t * DCH + lane * 4);
            float4 cur = *o;
            cur.x += acc.x; cur.y += acc.y; cur.z += acc.z; cur.w += acc.w;
            *o = cur;
        }
    }
}

// --------------------------------------------------------------------- launch
extern "C" void kernel_launch(void* const* d_in, const int* in_sizes, int n_in,
                              void* d_out, int out_size, void* d_ws, size_t ws_size,
                              hipStream_t stream) {
    const float* x     = (const float*)d_in[0];
    const int*   ei    = (const int*)d_in[1];
    const float* gamma = (const float*)d_in[2];
    const float* beta  = (const float*)d_in[3];
    const float* Wl    = (const float*)d_in[4];
    const float* bl    = (const float*)d_in[5];
    const float* Wr    = (const float*)d_in[6];
    const float* br    = (const float*)d_in[7];
    const float* att   = (const float*)d_in[8];
    const float* resW  = (const float*)d_in[9];
    const float* bias  = (const float*)d_in[10];
    float* out = (float*)d_out;

    int n = in_sizes[0] / DCH;
    int E = in_sizes[1] / 2;
    const int* src = ei;
    const int* dstIdx = ei + E;

    char* ws = (char*)d_ws;
    size_t off = 0;
    auto alloc = [&](size_t bytes) -> void* {
        void* p = ws + off;
        off = (off + bytes + 255) & ~(size_t)255;
        return p;
    };

    int nb = (n + 255) / 256;

    unsigned short* xl = (unsigned short*)alloc((size_t)n * 256 * 2);  // 51.2 MB
    unsigned short* xr = (unsigned short*)alloc((size_t)n * 256 * 2);  // 51.2 MB
    unsigned short* wfrag = (unsigned short*)alloc(160 * 64 * 8 * 2);  // 160 KB
    int* cnt   = (int*)alloc((size_t)n * 4);
    int* offs  = (int*)alloc((size_t)(n + 1) * 4);
    int* bsum  = (int*)alloc((size_t)nb * 4);
    int* fillc = (int*)alloc((size_t)n * 4);
    int* sbuf  = (int*)alloc((size_t)E * 4);                           // 6.4 MB

    prep_and_zero<<<40 + nb, 256, 0, stream>>>(Wl, Wr, resW, wfrag, cnt, n);
    int ethr = (E / 4 + 255) / 256 + 1;
    hist_dst<<<ethr, 256, 0, stream>>>(dstIdx, cnt, E);
    scan_block<<<nb, 256, 0, stream>>>(cnt, offs, bsum, n);
    scan_bsum_par<<<1, 512, 0, stream>>>(bsum, nb);
    scan_add<<<nb, 256, 0, stream>>>(offs, fillc, bsum, n, E);

    int nrb = (n + 127) / 128;
    gemm_fill<<<nrb + ethr, 256, 0, stream>>>(x, gamma, beta, wfrag, bl, br, bias,
                                              xl, xr, out, n,
                                              src, dstIdx, fillc, sbuf, E, nrb);
    gat_aggregate<<<2048, 256, 0, stream>>>(offs, sbuf, xl, xr, att, out, n);
}

// Round 11
// 292.828 us; speedup vs baseline: 8.2262x; 1.1092x over previous
//
#include <hip/hip_runtime.h>
#include <hip/hip_bf16.h>
#include <cstdint>
#include <cstddef>

#define DCH 128
#define NHEADS 2
#define NEG_SLOPE 0.2f

typedef __attribute__((ext_vector_type(8))) short short8v;
typedef __attribute__((ext_vector_type(4))) float f32x4;
typedef __attribute__((ext_vector_type(2))) float f32x2;
typedef _Float16 h4 __attribute__((ext_vector_type(4)));

// ---------------------------------------------------------------- utilities
__device__ __forceinline__ unsigned short f2bf(float f) {
    union { float f; unsigned int i; } v; v.f = f;
    unsigned int r = v.i + 0x7fffu + ((v.i >> 16) & 1u);   // RNE
    return (unsigned short)(r >> 16);
}
__device__ __forceinline__ unsigned short f2h_bits(float f) {
    _Float16 h = (_Float16)f;
    union { _Float16 h; unsigned short u; } v; v.h = h; return v.u;
}

// 32-lane-half sum via DPP row_ror + one ds_swizzle (xor16).
__device__ __forceinline__ float halfsum(float p) {
    p += __int_as_float(__builtin_amdgcn_update_dpp(
            0, __float_as_int(p), 0x121, 0xF, 0xF, false));  // row_ror:1
    p += __int_as_float(__builtin_amdgcn_update_dpp(
            0, __float_as_int(p), 0x122, 0xF, 0xF, false));  // row_ror:2
    p += __int_as_float(__builtin_amdgcn_update_dpp(
            0, __float_as_int(p), 0x124, 0xF, 0xF, false));  // row_ror:4
    p += __int_as_float(__builtin_amdgcn_update_dpp(
            0, __float_as_int(p), 0x128, 0xF, 0xF, false));  // row_ror:8
    p += __int_as_float(__builtin_amdgcn_ds_swizzle(
            __float_as_int(p), 0x401F));                     // lane ^= 16
    return p;
}

// ------------------------------- merged: weights->bf16 fragments + zero cnt
__global__ void prep_and_zero(const float* __restrict__ Wl, const float* __restrict__ Wr,
                              const float* __restrict__ resW,
                              unsigned short* __restrict__ wfrag,
                              int* __restrict__ cnt, int n) {
    if (blockIdx.x >= 40) {
        int i = (blockIdx.x - 40) * 256 + threadIdx.x;
        if (i < n) cnt[i] = 0;
        return;
    }
    int gid  = blockIdx.x * 256 + threadIdx.x;   // 10240 threads
    int lane = gid & 63;
    int f    = gid >> 6;                          // 0..159
    int ks   = f & 3;
    int ct   = f >> 2;
    int col  = ct * 16 + (lane & 15);
    int k0   = ks * 32 + (lane >> 4) * 8;
    const float* W; int ldB, c;
    if (col < 256)      { W = Wl;   ldB = 256; c = col; }
    else if (col < 512) { W = Wr;   ldB = 256; c = col - 256; }
    else                { W = resW; ldB = 128; c = col - 512; }
    unsigned short tmp[8];
#pragma unroll
    for (int j = 0; j < 8; ++j) tmp[j] = f2bf(W[(size_t)(k0 + j) * ldB + c]);
    ushort4* dst = (ushort4*)(wfrag + (size_t)gid * 8);
    dst[0] = make_ushort4(tmp[0], tmp[1], tmp[2], tmp[3]);
    dst[1] = make_ushort4(tmp[4], tmp[5], tmp[6], tmp[7]);
}

// ------- combined dispatch: blocks [0,nrb) = LN+MFMA GEMM, rest = fill_csr
// GEMM outputs staged in LDS, flushed as full-line row segments.
// xl stored FP8 (e4m3, 256 B/row); xr f16; out f32 (+bias+residual).
__launch_bounds__(256)
__global__ void gemm_fill(const float* __restrict__ x,
                          const float* __restrict__ gamma, const float* __restrict__ beta,
                          const unsigned short* __restrict__ wfrag,
                          const float* __restrict__ bl, const float* __restrict__ br,
                          const float* __restrict__ bias,
                          unsigned char* __restrict__ xl8, unsigned short* __restrict__ xr,
                          float* __restrict__ out, int n,
                          const int* __restrict__ srcIdx, const int* __restrict__ dstIdx,
                          int* __restrict__ fillc, int* __restrict__ sbuf, int E, int nrb) {
    __shared__ __align__(16) unsigned char smem[128 * 256];  // 32 KB (As / stage)

    if ((int)blockIdx.x >= nrb) {
        // ---------------- fill_csr part
        int i = (blockIdx.x - nrb) * 256 + threadIdx.x;
        int E4 = E >> 2;
        if (i < E4) {
            int4 d = ((const int4*)dstIdx)[i];
            int4 s = ((const int4*)srcIdx)[i];
            sbuf[atomicAdd(&fillc[d.x], 1)] = s.x;
            sbuf[atomicAdd(&fillc[d.y], 1)] = s.y;
            sbuf[atomicAdd(&fillc[d.z], 1)] = s.z;
            sbuf[atomicAdd(&fillc[d.w], 1)] = s.w;
        }
        if (i < (E & 3)) {
            int e = E4 * 4 + i;
            sbuf[atomicAdd(&fillc[dstIdx[e]], 1)] = srcIdx[e];
        }
        return;
    }

    // ---------------- GEMM part
    int row0 = blockIdx.x * 128;
    int tid  = threadIdx.x;
    unsigned short* As = (unsigned short*)smem;

    // stage A with fused LayerNorm+ReLU (bf16, XOR-swizzled)
    {
        int r  = tid >> 5;            // 0..7
        int k4 = (tid & 31) * 4;      // 0,4,...,124
        float4 g4  = *(const float4*)(gamma + k4);
        float4 be4 = *(const float4*)(beta + k4);
#pragma unroll
        for (int i = 0; i < 16; ++i) {
            int row  = r + i * 8;
            int grow = row0 + row;
            float4 a = (grow < n) ? *(const float4*)(x + (size_t)grow * DCH + k4)
                                  : make_float4(0.f, 0.f, 0.f, 0.f);
            float s  = a.x + a.y + a.z + a.w;
            float sq = a.x * a.x + a.y * a.y + a.z * a.z + a.w * a.w;
#pragma unroll
            for (int msk = 16; msk; msk >>= 1) {
                s  += __shfl_xor(s, msk);
                sq += __shfl_xor(sq, msk);
            }
            float mu = s * (1.f / DCH);
            float rs = rsqrtf(sq * (1.f / DCH) - mu * mu + 1e-5f);
            ushort4 u;
            u.x = f2bf(fmaxf((a.x - mu) * rs * g4.x + be4.x, 0.f));
            u.y = f2bf(fmaxf((a.y - mu) * rs * g4.y + be4.y, 0.f));
            u.z = f2bf(fmaxf((a.z - mu) * rs * g4.z + be4.z, 0.f));
            u.w = f2bf(fmaxf((a.w - mu) * rs * g4.w + be4.w, 0.f));
            int byteoff = row * 256 + ((k4 * 2) ^ ((row & 7) << 4));
            *(ushort4*)((char*)As + byteoff) = u;
        }
    }
    __syncthreads();

    int wv = tid >> 6, lane = tid & 63;

    short8v afrag[2][4];
#pragma unroll
    for (int g = 0; g < 2; ++g) {
        int arow = wv * 32 + g * 16 + (lane & 15);
#pragma unroll
        for (int ks = 0; ks < 4; ++ks) {
            int kbyte = (ks * 64 + (lane >> 4) * 16) ^ ((arow & 7) << 4);
            afrag[g][ks] = *(const short8v*)((const char*)As + arow * 256 + kbyte);
        }
    }
    __syncthreads();   // fragment reads done; smem becomes the stage buffer

    int nodeL0 = wv * 32 + (lane & 15);      // local node, group 0 (0..127)
    int nodeL1 = nodeL0 + 16;                // group 1
    int cq = (lane >> 4) << 2;               // column quad 0,4,8,12

    auto mfma_ct = [&](int ct, f32x4& a0, f32x4& a1) {
        const unsigned short* bp = wfrag + ((size_t)(ct * 4) * 64 + lane) * 8;
        short8v b0 = *(const short8v*)(bp);
        short8v b1 = *(const short8v*)(bp + 64 * 8);
        short8v b2 = *(const short8v*)(bp + 128 * 8);
        short8v b3 = *(const short8v*)(bp + 192 * 8);
        a0 = __builtin_amdgcn_mfma_f32_16x16x32_bf16(b0, afrag[0][0], a0, 0, 0, 0);
        a1 = __builtin_amdgcn_mfma_f32_16x16x32_bf16(b0, afrag[1][0], a1, 0, 0, 0);
        a0 = __builtin_amdgcn_mfma_f32_16x16x32_bf16(b1, afrag[0][1], a0, 0, 0, 0);
        a1 = __builtin_amdgcn_mfma_f32_16x16x32_bf16(b1, afrag[1][1], a1, 0, 0, 0);
        a0 = __builtin_amdgcn_mfma_f32_16x16x32_bf16(b2, afrag[0][2], a0, 0, 0, 0);
        a1 = __builtin_amdgcn_mfma_f32_16x16x32_bf16(b2, afrag[1][2], a1, 0, 0, 0);
        a0 = __builtin_amdgcn_mfma_f32_16x16x32_bf16(b3, afrag[0][3], a0, 0, 0, 0);
        a1 = __builtin_amdgcn_mfma_f32_16x16x32_bf16(b3, afrag[1][3], a1, 0, 0, 0);
    };

    // ---- xl (fp8): ONE flush-group of 16 cts; stage = [128 nodes][256 B]
    {
#pragma unroll
        for (int ct = 0; ct < 16; ++ct) {
            f32x4 acc0 = {0.f, 0.f, 0.f, 0.f};
            f32x4 acc1 = {0.f, 0.f, 0.f, 0.f};
            mfma_ct(ct, acc0, acc1);
            int c = ct * 16 + cq;
            float4 bb = *(const float4*)(bl + c);
            int cb = ct * 16 + cq;                       // byte in [0,256)
            int p0 = __builtin_amdgcn_cvt_pk_fp8_f32(acc0[0] + bb.x, acc0[1] + bb.y, 0, false);
            p0     = __builtin_amdgcn_cvt_pk_fp8_f32(acc0[2] + bb.z, acc0[3] + bb.w, p0, true);
            *(int*)(smem + nodeL0 * 256 + (cb ^ ((nodeL0 & 7) << 4))) = p0;
            int p1 = __builtin_amdgcn_cvt_pk_fp8_f32(acc1[0] + bb.x, acc1[1] + bb.y, 0, false);
            p1     = __builtin_amdgcn_cvt_pk_fp8_f32(acc1[2] + bb.z, acc1[3] + bb.w, p1, true);
            *(int*)(smem + nodeL1 * 256 + (cb ^ ((nodeL1 & 7) << 4))) = p1;
        }
        __syncthreads();
#pragma unroll
        for (int it = 0; it < 8; ++it) {        // flush 32KB, full-line stores
            int chunk = it * 256 + tid;
            int row  = chunk >> 4;
            int colb = (chunk & 15) * 16;
            int grow = row0 + row;
            if (grow < n) {
                int4 v = *(const int4*)(smem + row * 256 + (colb ^ ((row & 7) << 4)));
                *(int4*)(xl8 + (size_t)grow * 256 + colb) = v;
            }
        }
        __syncthreads();
    }

    // ---- xr (f16): 2 flush-groups of 8 cts; stage = [128 nodes][128 col f16]
    for (int fg = 0; fg < 2; ++fg) {
#pragma unroll
        for (int ctl = 0; ctl < 8; ++ctl) {
            int ct = 16 + fg * 8 + ctl;
            f32x4 acc0 = {0.f, 0.f, 0.f, 0.f};
            f32x4 acc1 = {0.f, 0.f, 0.f, 0.f};
            mfma_ct(ct, acc0, acc1);
            int c = ct * 16 + cq - 256;                  // col in [0,256)
            float4 bb = *(const float4*)(br + c);
            int cb = ctl * 32 + cq * 2;                  // byte in [0,256)
            ushort4 u0 = make_ushort4(f2h_bits(acc0[0] + bb.x), f2h_bits(acc0[1] + bb.y),
                                      f2h_bits(acc0[2] + bb.z), f2h_bits(acc0[3] + bb.w));
            *(ushort4*)(smem + nodeL0 * 256 + (cb ^ ((nodeL0 & 7) << 4))) = u0;
            ushort4 u1 = make_ushort4(f2h_bits(acc1[0] + bb.x), f2h_bits(acc1[1] + bb.y),
                                      f2h_bits(acc1[2] + bb.z), f2h_bits(acc1[3] + bb.w));
            *(ushort4*)(smem + nodeL1 * 256 + (cb ^ ((nodeL1 & 7) << 4))) = u1;
        }
        __syncthreads();
#pragma unroll
        for (int it = 0; it < 8; ++it) {
            int chunk = it * 256 + tid;
            int row  = chunk >> 4;
            int colb = (chunk & 15) * 16;
            int grow = row0 + row;
            if (grow < n) {
                int4 v = *(const int4*)(smem + row * 256 + (colb ^ ((row & 7) << 4)));
                *(int4*)((char*)xr + (size_t)grow * 512 + fg * 256 + colb) = v;
            }
        }
        __syncthreads();
    }

    // ---- out: 2 flush-groups of 4 cts; stage = [128 rows][64 col f32]
    for (int fg = 0; fg < 2; ++fg) {
#pragma unroll
        for (int ctl = 0; ctl < 4; ++ctl) {
            int ct = 32 + fg * 4 + ctl;
            f32x4 acc0 = {0.f, 0.f, 0.f, 0.f};
            f32x4 acc1 = {0.f, 0.f, 0.f, 0.f};
            mfma_ct(ct, acc0, acc1);
            int c = ct * 16 + cq - 512;                  // col in [0,128)
            float4 bb = *(const float4*)(bias + c);
            int cb = ctl * 64 + cq * 4;                  // byte in [0,256)
            float4 w0 = make_float4(acc0[0] + bb.x, acc0[1] + bb.y,
                                    acc0[2] + bb.z, acc0[3] + bb.w);
            *(float4*)(smem + nodeL0 * 256 + (cb ^ ((nodeL0 & 7) << 4))) = w0;
            float4 w1 = make_float4(acc1[0] + bb.x, acc1[1] + bb.y,
                                    acc1[2] + bb.z, acc1[3] + bb.w);
            *(float4*)(smem + nodeL1 * 256 + (cb ^ ((nodeL1 & 7) << 4))) = w1;
        }
        __syncthreads();
#pragma unroll
        for (int it = 0; it < 8; ++it) {        // flush + residual x
            int chunk = it * 256 + tid;
            int row  = chunk >> 4;
            int colb = (chunk & 15) * 16;
            int grow = row0 + row;
            if (grow < n) {
                float4 v = *(const float4*)(smem + row * 256 + (colb ^ ((row & 7) << 4)));
                float4 xv = *(const float4*)((const char*)x + (size_t)grow * 512 + fg * 256 + colb);
                v.x += xv.x; v.y += xv.y; v.z += xv.z; v.w += xv.w;
                *(float4*)((char*)out + (size_t)grow * 512 + fg * 256 + colb) = v;
            }
        }
        __syncthreads();
    }
}

// --------------------------------------------------------------- CSR build
__global__ void hist_dst(const int* __restrict__ dst, int* __restrict__ cnt, int E) {
    int i = blockIdx.x * blockDim.x + threadIdx.x;
    int E4 = E >> 2;
    if (i < E4) {
        int4 d = ((const int4*)dst)[i];
        atomicAdd(&cnt[d.x], 1); atomicAdd(&cnt[d.y], 1);
        atomicAdd(&cnt[d.z], 1); atomicAdd(&cnt[d.w], 1);
    }
    if (i < (E & 3)) atomicAdd(&cnt[dst[E4 * 4 + i]], 1);
}

__global__ void scan_block(const int* __restrict__ cnt, int* __restrict__ offs,
                           int* __restrict__ bsum, int n) {
    __shared__ int sm[256];
    int t = threadIdx.x;
    int i = blockIdx.x * 256 + t;
    int v = (i < n) ? cnt[i] : 0;
    sm[t] = v;
    __syncthreads();
#pragma unroll
    for (int d = 1; d < 256; d <<= 1) {
        int add = (t >= d) ? sm[t - d] : 0;
        __syncthreads();
        sm[t] += add;
        __syncthreads();
    }
    if (i < n) offs[i] = sm[t] - v;
    if (t == 255) bsum[blockIdx.x] = sm[t];
}

__global__ void scan_bsum_par(int* __restrict__ bsum, int nb) {
    __shared__ int sm[512];
    int t = threadIdx.x;
    if (nb <= 512) {
        int v = (t < nb) ? bsum[t] : 0;
        sm[t] = v;
        __syncthreads();
#pragma unroll
        for (int d = 1; d < 512; d <<= 1) {
            int add = (t >= d) ? sm[t - d] : 0;
            __syncthreads();
            sm[t] += add;
            __syncthreads();
        }
        if (t < nb) bsum[t] = sm[t] - v;
    } else if (t == 0) {
        int acc = 0;
        for (int i = 0; i < nb; ++i) { int v = bsum[i]; bsum[i] = acc; acc += v; }
    }
}

__global__ void scan_add(int* __restrict__ offs, int* __restrict__ fillc,
                         const int* __restrict__ bsum, int n, int E) {
    int i = blockIdx.x * 256 + threadIdx.x;
    if (i < n) {
        int v = offs[i] + bsum[blockIdx.x];
        offs[i]  = v;
        fillc[i] = v;
    }
    if (i == 0) offs[n] = E;
}

// --------------- single-pass fused attention + softmax + aggregation (fp8)
// One wave per dst node t. xl gathered as fp8 (4 B/lane, 256 B/edge —
// halves the L3 gather stream), expanded with v_cvt_pk_f32_fp8; logits and
// accumulation in f32. Lane-local per-head online (m,z) + defer-max;
// software-pipelined 4-edge groups.
__launch_bounds__(256)
__global__ void gat_aggregate(const int* __restrict__ offs, const int* __restrict__ sbuf,
                              const unsigned char* __restrict__ xl8,
                              const unsigned short* __restrict__ xr_,
                              const float* __restrict__ att,
                              float* __restrict__ out, int n) {
    const _Float16* xr = (const _Float16*)xr_;
    int lane = threadIdx.x & 63;
    int wid  = __builtin_amdgcn_readfirstlane((blockIdx.x * blockDim.x + threadIdx.x) >> 6);
    int nw   = (gridDim.x * blockDim.x) >> 6;

    const float LOG2E = 1.4426950408889634f;
    float4 af = *(const float4*)(att + lane * 4);   // flat[256]: lanes 0..31 head0
    float ax = af.x * LOG2E, ay = af.y * LOG2E, az = af.z * LOG2E, aw = af.w * LOG2E;

    for (int t = wid; t < n; t += nw) {
        int beg = offs[t];
        int end = offs[t + 1];
        if (beg == end) continue;
        h4 rr = *(const h4*)(xr + (size_t)t * 256 + lane * 4);
        float rx = (float)rr[0], ry = (float)rr[1], rz = (float)rr[2], rw = (float)rr[3];

        float m = -INFINITY, z = 0.f;
        float4 acc = make_float4(0.f, 0.f, 0.f, 0.f);

        auto process4 = [&](int u0, int u1, int u2, int u3) {
            f32x2 l0a = __builtin_amdgcn_cvt_pk_f32_fp8(u0, false);
            f32x2 l0b = __builtin_amdgcn_cvt_pk_f32_fp8(u0, true);
            f32x2 l1a = __builtin_amdgcn_cvt_pk_f32_fp8(u1, false);
            f32x2 l1b = __builtin_amdgcn_cvt_pk_f32_fp8(u1, true);
            f32x2 l2a = __builtin_amdgcn_cvt_pk_f32_fp8(u2, false);
            f32x2 l2b = __builtin_amdgcn_cvt_pk_f32_fp8(u2, true);
            f32x2 l3a = __builtin_amdgcn_cvt_pk_f32_fp8(u3, false);
            f32x2 l3b = __builtin_amdgcn_cvt_pk_f32_fp8(u3, true);

            auto logit = [&](f32x2 la, f32x2 lb) {
                float vx = la.x + rx; vx = fmaxf(vx, NEG_SLOPE * vx);
                float vy = la.y + ry; vy = fmaxf(vy, NEG_SLOPE * vy);
                float vz = lb.x + rz; vz = fmaxf(vz, NEG_SLOPE * vz);
                float vw = lb.y + rw; vw = fmaxf(vw, NEG_SLOPE * vw);
                return fmaf(vw, aw, fmaf(vz, az, fmaf(vy, ay, vx * ax)));
            };
            float p0 = halfsum(logit(l0a, l0b));
            float p1 = halfsum(logit(l1a, l1b));
            float p2 = halfsum(logit(l2a, l2b));
            float p3 = halfsum(logit(l3a, l3b));
            float pm = fmaxf(fmaxf(p0, p1), fmaxf(p2, p3));
            if (__any(pm - m > 11.5f)) {
                float mn = fmaxf(m, pm);
                float sc = __builtin_amdgcn_exp2f(m - mn);   // 0 on first group
                z *= sc;
                acc.x *= sc; acc.y *= sc; acc.z *= sc; acc.w *= sc;
                m = mn;
            }
            float w0 = __builtin_amdgcn_exp2f(p0 - m);
            float w1 = __builtin_amdgcn_exp2f(p1 - m);
            float w2 = __builtin_amdgcn_exp2f(p2 - m);
            float w3 = __builtin_amdgcn_exp2f(p3 - m);
            z += (w0 + w1) + (w2 + w3);
            acc.x = fmaf(l0a.x, w0, acc.x); acc.y = fmaf(l0a.y, w0, acc.y);
            acc.z = fmaf(l0b.x, w0, acc.z); acc.w = fmaf(l0b.y, w0, acc.w);
            acc.x = fmaf(l1a.x, w1, acc.x); acc.y = fmaf(l1a.y, w1, acc.y);
            acc.z = fmaf(l1b.x, w1, acc.z); acc.w = fmaf(l1b.y, w1, acc.w);
            acc.x = fmaf(l2a.x, w2, acc.x); acc.y = fmaf(l2a.y, w2, acc.y);
            acc.z = fmaf(l2b.x, w2, acc.z); acc.w = fmaf(l2b.y, w2, acc.w);
            acc.x = fmaf(l3a.x, w3, acc.x); acc.y = fmaf(l3a.y, w3, acc.y);
            acc.z = fmaf(l3b.x, w3, acc.z); acc.w = fmaf(l3b.y, w3, acc.w);
        };

        int j = beg;
        int c0, c1, c2, c3;
        bool have = (j + 4 <= end);
        if (have) {
            int s0 = sbuf[j], s1 = sbuf[j + 1], s2 = sbuf[j + 2], s3 = sbuf[j + 3];
            c0 = *(const int*)(xl8 + (size_t)s0 * 256 + lane * 4);
            c1 = *(const int*)(xl8 + (size_t)s1 * 256 + lane * 4);
            c2 = *(const int*)(xl8 + (size_t)s2 * 256 + lane * 4);
            c3 = *(const int*)(xl8 + (size_t)s3 * 256 + lane * 4);
        }
        for (; j + 8 <= end; j += 4) {
            int s0 = sbuf[j + 4], s1 = sbuf[j + 5], s2 = sbuf[j + 6], s3 = sbuf[j + 7];
            int n0 = *(const int*)(xl8 + (size_t)s0 * 256 + lane * 4);
            int n1 = *(const int*)(xl8 + (size_t)s1 * 256 + lane * 4);
            int n2 = *(const int*)(xl8 + (size_t)s2 * 256 + lane * 4);
            int n3 = *(const int*)(xl8 + (size_t)s3 * 256 + lane * 4);
            process4(c0, c1, c2, c3);
            c0 = n0; c1 = n1; c2 = n2; c3 = n3;
        }
        if (have) { process4(c0, c1, c2, c3); j += 4; }
        for (; j < end; ++j) {                   // tail (0..3 edges)
            int u = *(const int*)(xl8 + (size_t)sbuf[j] * 256 + lane * 4);
            f32x2 la = __builtin_amdgcn_cvt_pk_f32_fp8(u, false);
            f32x2 lb = __builtin_amdgcn_cvt_pk_f32_fp8(u, true);
            float vx = la.x + rx; vx = fmaxf(vx, NEG_SLOPE * vx);
            float vy = la.y + ry; vy = fmaxf(vy, NEG_SLOPE * vy);
            float vz = lb.x + rz; vz = fmaxf(vz, NEG_SLOPE * vz);
            float vw = lb.y + rw; vw = fmaxf(vw, NEG_SLOPE * vw);
            float p = halfsum(fmaf(vw, aw, fmaf(vz, az, fmaf(vy, ay, vx * ax))));
            if (__any(p - m > 11.5f)) {
                float mn = fmaxf(m, p);
                float sc = __builtin_amdgcn_exp2f(m - mn);
                z *= sc;
                acc.x *= sc; acc.y *= sc; acc.z *= sc; acc.w *= sc;
                m = mn;
            }
            float w = __builtin_amdgcn_exp2f(p - m);
            z += w;
            acc.x = fmaf(la.x, w, acc.x); acc.y = fmaf(la.y, w, acc.y);
            acc.z = fmaf(lb.x, w, acc.z); acc.w = fmaf(lb.y, w, acc.w);
        }
        float inv = 0.5f / (z + 1e-16f);         // z uniform within each half
        acc.x *= inv; acc.y *= inv; acc.z *= inv; acc.w *= inv;
        // head mean: lane L (<32) += lane L+32 (same channels, head 1)
        acc.x += __shfl_xor(acc.x, 32);
        acc.y += __shfl_xor(acc.y, 32);
        acc.z += __shfl_xor(acc.z, 32);
        acc.w += __shfl_xor(acc.w, 32);
        if (lane < 32) {
            float4* o = (float4*)(out + (size_t)t * DCH + lane * 4);
            float4 cur = *o;
            cur.x += acc.x; cur.y += acc.y; cur.z += acc.z; cur.w += acc.w;
            *o = cur;
        }
    }
}

// --------------------------------------------------------------------- launch
extern "C" void kernel_launch(void* const* d_in, const int* in_sizes, int n_in,
                              void* d_out, int out_size, void* d_ws, size_t ws_size,
                              hipStream_t stream) {
    const float* x     = (const float*)d_in[0];
    const int*   ei    = (const int*)d_in[1];
    const float* gamma = (const float*)d_in[2];
    const float* beta  = (const float*)d_in[3];
    const float* Wl    = (const float*)d_in[4];
    const float* bl    = (const float*)d_in[5];
    const float* Wr    = (const float*)d_in[6];
    const float* br    = (const float*)d_in[7];
    const float* att   = (const float*)d_in[8];
    const float* resW  = (const float*)d_in[9];
    const float* bias  = (const float*)d_in[10];
    float* out = (float*)d_out;

    int n = in_sizes[0] / DCH;
    int E = in_sizes[1] / 2;
    const int* src = ei;
    const int* dstIdx = ei + E;

    char* ws = (char*)d_ws;
    size_t off = 0;
    auto alloc = [&](size_t bytes) -> void* {
        void* p = ws + off;
        off = (off + bytes + 255) & ~(size_t)255;
        return p;
    };

    int nb = (n + 255) / 256;

    unsigned char*  xl8 = (unsigned char*)alloc((size_t)n * 256);       // 25.6 MB
    unsigned short* xr  = (unsigned short*)alloc((size_t)n * 256 * 2);  // 51.2 MB
    unsigned short* wfrag = (unsigned short*)alloc(160 * 64 * 8 * 2);   // 160 KB
    int* cnt   = (int*)alloc((size_t)n * 4);
    int* offs  = (int*)alloc((size_t)(n + 1) * 4);
    int* bsum  = (int*)alloc((size_t)nb * 4);
    int* fillc = (int*)alloc((size_t)n * 4);
    int* sbuf  = (int*)alloc((size_t)E * 4);                            // 6.4 MB

    prep_and_zero<<<40 + nb, 256, 0, stream>>>(Wl, Wr, resW, wfrag, cnt, n);
    int ethr = (E / 4 + 255) / 256 + 1;
    hist_dst<<<ethr, 256, 0, stream>>>(dstIdx, cnt, E);
    scan_block<<<nb, 256, 0, stream>>>(cnt, offs, bsum, n);
    scan_bsum_par<<<1, 512, 0, stream>>>(bsum, nb);
    scan_add<<<nb, 256, 0, stream>>>(offs, fillc, bsum, n, E);

    int nrb = (n + 127) / 128;
    gemm_fill<<<nrb + ethr, 256, 0, stream>>>(x, gamma, beta, wfrag, bl, br, bias,
                                              xl8, xr, out, n,
                                              src, dstIdx, fillc, sbuf, E, nrb);
    gat_aggregate<<<2048, 256, 0, stream>>>(offs, sbuf, xl8, xr, att, out, n);
}